// Round 5
// baseline (1925.159 us; speedup 1.0000x reference)
//
#include <hip/hip_runtime.h>
#include <cstddef>
#include <cstdint>

#define LEAKY_ATT 0.2f
#define LEAKY_ACT 0.01f
#define BN_EPS 1e-5f

static __device__ __forceinline__ unsigned enc_f(float f){
  unsigned u = __float_as_uint(f);
  return (u & 0x80000000u) ? ~u : (u | 0x80000000u);
}
static __device__ __forceinline__ float dec_f(unsigned k){
  return (k & 0x80000000u) ? __uint_as_float(k & 0x7fffffffu) : __uint_as_float(~k);
}
// round-to-nearest-even f32 -> bf16
static __device__ __forceinline__ unsigned short f2bf(float f){
  unsigned u = __float_as_uint(f);
  unsigned r = u + 0x7fffu + ((u >> 16) & 1u);
  return (unsigned short)(r >> 16);
}
static __device__ __forceinline__ float bf_lo(unsigned u){ return __uint_as_float(u << 16); }
static __device__ __forceinline__ float bf_hi(unsigned u){ return __uint_as_float(u & 0xffff0000u); }

// ---------------- argmax + embedding lookup: h[n] = emb[argmax(x[n])] --------
__global__ void k_embed(const float* __restrict__ x, const float* __restrict__ emb,
                        float* __restrict__ h, int N){
  int n = blockIdx.x; if (n >= N) return;
  int t = threadIdx.x;            // 64 threads = 1 wave
  float v = x[(size_t)n*64 + t];
  int idx = t;
  #pragma unroll
  for (int off = 32; off; off >>= 1){
    float ov = __shfl_down(v, off);
    int   oi = __shfl_down(idx, off);
    if (ov > v || (ov == v && oi < idx)) { v = ov; idx = oi; }  // first max wins
  }
  idx = __shfl(idx, 0);
  h[(size_t)n*128 + t]      = emb[(size_t)idx*128 + t];
  h[(size_t)n*128 + 64 + t] = emb[(size_t)idx*128 + 64 + t];
}

// ---------------- degree per dst --------------------------------------------
__global__ void k_deg(const int* __restrict__ dst, int* __restrict__ deg, int E){
  int e = blockIdx.x*blockDim.x + threadIdx.x;
  if (e >= E) return;
  atomicAdd(&deg[dst[e]], 1);
}

// ---------------- single-block exclusive scan of (deg[i]+1) -----------------
__global__ void k_scan(const int* __restrict__ deg, int* __restrict__ rowptr, int N){
  __shared__ int sd[256];
  __shared__ int sbase;
  if (threadIdx.x == 0) sbase = 0;
  __syncthreads();
  for (int base = 0; base < N; base += 256){
    int i = base + threadIdx.x;
    int v = (i < N) ? (deg[i] + 1) : 0;
    sd[threadIdx.x] = v;
    __syncthreads();
    for (int off = 1; off < 256; off <<= 1){
      int t = (threadIdx.x >= off) ? sd[threadIdx.x - off] : 0;
      __syncthreads();
      sd[threadIdx.x] += t;
      __syncthreads();
    }
    if (i < N) rowptr[i] = sbase + sd[threadIdx.x] - v;   // exclusive
    int tot = sd[255];
    __syncthreads();
    if (threadIdx.x == 0) sbase += tot;
    __syncthreads();
  }
  if (threadIdx.x == 0) rowptr[N] = sbase;
}

// ---------------- CSR fill (edges then self-loops) --------------------------
__global__ void k_csrfill(const int* __restrict__ dst, const int* __restrict__ rowptr,
                          int* __restrict__ cur, int* __restrict__ csr, int E, int N){
  int i = blockIdx.x*blockDim.x + threadIdx.x;
  if (i >= E + N) return;
  int d = (i < E) ? dst[i] : (i - E);
  int pos = atomicAdd(&cur[d], 1);
  csr[rowptr[d] + pos] = i;
}

// ---------------- per-dst mean of edge_attr (CSR-based, no atomics) ---------
__global__ void k_eamean(const int* __restrict__ rowptr, const int* __restrict__ csr,
                         const float* __restrict__ ea, float* __restrict__ eam,
                         int E, int N){
  int wid = threadIdx.x >> 6, lane = threadIdx.x & 63;
  int n = blockIdx.x*4 + wid;
  if (n >= N) return;
  int start = rowptr[n], end = rowptr[n+1];
  int j = lane >> 4, k = lane & 15;   // 4 edges x 16 features per pass
  float s = 0.f;
  for (int i = start + j; i < end; i += 4){
    int e = csr[i];
    if (e < E) s += ea[(size_t)e*16 + k];
  }
  s += __shfl_xor(s, 16);
  s += __shfl_xor(s, 32);
  if (lane < 16){
    int deg = end - start - 1;       // real in-degree (one self-loop per node)
    eam[(size_t)n*16 + k] = s / (float)max(deg, 1);
  }
}

// ---------------- dual GEMM: [xl|xr] = A[N,K] @ [Wl|Wr] + [bl|br] -----------
// blockIdx.y < C/64 -> xl half, written as packed bf16; else xr half, f32.
#define GBM 64
#define GBN 64
#define GBK 32
__global__ __launch_bounds__(256) void k_gemm_dual(const float* __restrict__ A,
                       const float* __restrict__ Wl, const float* __restrict__ bl,
                       const float* __restrict__ Wr, const float* __restrict__ br,
                       unsigned short* __restrict__ xlb, float* __restrict__ xr,
                       int N, int K, int C){
  __shared__ float As[GBM*33];
  __shared__ float Ws[GBK*GBN];
  int tid = threadIdx.x;
  int tx = tid & 15, ty = tid >> 4;
  int m0 = blockIdx.x*GBM;
  int n0g = blockIdx.y*GBN;
  bool isL = (n0g < C);
  int n0 = isL ? n0g : n0g - C;
  const float* W    = isL ? Wl : Wr;
  const float* bias = isL ? bl : br;
  float acc[4][4] = {};
  for (int k0 = 0; k0 < K; k0 += GBK){
    for (int i = tid; i < (GBM*GBK)/4; i += 256){
      int flat = i*4; int r = flat >> 5; int c = flat & 31;
      float4 v = make_float4(0.f,0.f,0.f,0.f);
      if (m0 + r < N) v = *reinterpret_cast<const float4*>(&A[(size_t)(m0+r)*K + k0 + c]);
      As[r*33 + c]   = v.x; As[r*33 + c+1] = v.y;
      As[r*33 + c+2] = v.z; As[r*33 + c+3] = v.w;
    }
    for (int i = tid; i < (GBK*GBN)/4; i += 256){
      int flat = i*4; int r = flat >> 6; int c = flat & 63;
      *reinterpret_cast<float4*>(&Ws[r*GBN + c]) =
        *reinterpret_cast<const float4*>(&W[(size_t)(k0+r)*C + n0 + c]);
    }
    __syncthreads();
    #pragma unroll
    for (int kk = 0; kk < GBK; ++kk){
      float a[4];
      #pragma unroll
      for (int i = 0; i < 4; ++i) a[i] = As[(ty*4+i)*33 + kk];
      float4 wv = *reinterpret_cast<const float4*>(&Ws[kk*GBN + tx*4]);
      float w[4] = {wv.x, wv.y, wv.z, wv.w};
      #pragma unroll
      for (int i = 0; i < 4; ++i)
        #pragma unroll
        for (int j = 0; j < 4; ++j) acc[i][j] += a[i]*w[j];
    }
    __syncthreads();
  }
  int cb = n0 + tx*4;
  float b0 = bias[cb], b1 = bias[cb+1], b2 = bias[cb+2], b3 = bias[cb+3];
  #pragma unroll
  for (int i = 0; i < 4; ++i){
    int r = m0 + ty*4 + i;
    if (r >= N) continue;
    float v0 = acc[i][0]+b0, v1 = acc[i][1]+b1, v2 = acc[i][2]+b2, v3 = acc[i][3]+b3;
    if (isL){
      unsigned p0 = (unsigned)f2bf(v0) | ((unsigned)f2bf(v1) << 16);
      unsigned p1 = (unsigned)f2bf(v2) | ((unsigned)f2bf(v3) << 16);
      *reinterpret_cast<uint2*>(&xlb[(size_t)r*C + cb]) = make_uint2(p0, p1);
    } else {
      *reinterpret_cast<float4*>(&xr[(size_t)r*C + cb]) = make_float4(v0, v1, v2, v3);
    }
  }
}

// ---------------- fused GATv2: logits + softmax + aggregation ---------------
// One wave per dst node; UNR edges in flight. xl table is bf16 (halved gather
// bytes); accumulation f32. No max-subtraction (logits O(1) by construction,
// softmax shift-invariant) -> edges independent. Tail edges guarded by
// wave-uniform branches (no duplicate gathers).
template<int C, int UNR>
__global__ __launch_bounds__(256, 4) void k_gat_fused(
    const int* __restrict__ rowptr, const int* __restrict__ csr,
    const int* __restrict__ srcv, const float* __restrict__ edge_attr,
    const float* __restrict__ eam, const unsigned short* __restrict__ xlb,
    const float* __restrict__ xr, const float* __restrict__ We,
    const float* __restrict__ att, const float* __restrict__ bias,
    float* __restrict__ out, int E, int N)
{
  constexpr int CPL = C/64;
  int wid = threadIdx.x >> 6, lane = threadIdx.x & 63;
  int n = blockIdx.x*4 + wid;
  if (n >= N) return;
  const int c0 = lane*CPL;

  // hoist We column-slice + att + xr row into registers (loop-invariant)
  float wreg[16][CPL];
  #pragma unroll
  for (int k = 0; k < 16; ++k)
    #pragma unroll
    for (int q = 0; q < CPL; ++q)
      wreg[k][q] = We[k*C + c0 + q];
  float attv[CPL], xrv[CPL];
  #pragma unroll
  for (int q = 0; q < CPL; ++q){
    attv[q] = att[c0 + q];
    xrv[q]  = xr[(size_t)n*C + c0 + q];
  }

  int start = __builtin_amdgcn_readfirstlane(rowptr[n]);
  int end   = __builtin_amdgcn_readfirstlane(rowptr[n+1]);

  float denom = 0.f;
  float acc[CPL] = {};

  for (int i = start; i < end; i += UNR){
    // phase 1: resolve edge/src ids (scalar, wave-uniform)
    int sids[UNR]; const float* eaps[UNR];
    #pragma unroll
    for (int u = 0; u < UNR; ++u){
      if (i + u < end){
        int e = __builtin_amdgcn_readfirstlane(csr[i + u]);
        if (e < E){ sids[u] = __builtin_amdgcn_readfirstlane(srcv[e]);
                    eaps[u] = edge_attr + (size_t)e*16; }
        else      { sids[u] = e - E;
                    eaps[u] = eam + (size_t)(e-E)*16; }
      } else { sids[u] = 0; eaps[u] = eam; }
    }
    // phase 2: issue all row gathers (bf16 -> f32)
    float xls[UNR][CPL];
    #pragma unroll
    for (int u = 0; u < UNR; ++u){
      if (i + u < end){
        const unsigned short* prow = xlb + (size_t)sids[u]*C + c0;
        if constexpr (CPL == 4){
          uint2 v = *reinterpret_cast<const uint2*>(prow);
          xls[u][0]=bf_lo(v.x); xls[u][1]=bf_hi(v.x);
          xls[u][2]=bf_lo(v.y); xls[u][3]=bf_hi(v.y);
        } else {
          unsigned v = *reinterpret_cast<const unsigned*>(prow);
          xls[u][0]=bf_lo(v); xls[u][1]=bf_hi(v);
        }
      } else {
        #pragma unroll
        for (int q = 0; q < CPL; ++q) xls[u][q] = 0.f;
      }
    }
    // phase 3: logits + exp (independent per edge)
    float pe[UNR];
    #pragma unroll
    for (int u = 0; u < UNR; ++u){
      if (i + u < end){
        float w[CPL] = {};
        #pragma unroll
        for (int k = 0; k < 16; ++k){
          float a = eaps[u][k];            // wave-uniform scalar load
          #pragma unroll
          for (int q = 0; q < CPL; ++q) w[q] += a * wreg[k][q];
        }
        float p = 0.f;
        #pragma unroll
        for (int q = 0; q < CPL; ++q){
          float v = xls[u][q] + xrv[q] + w[q];
          v = (v >= 0.f) ? v : LEAKY_ATT*v;
          p += attv[q]*v;
        }
        #pragma unroll
        for (int off = 32; off; off >>= 1) p += __shfl_xor(p, off);
        pe[u] = __expf(p);
      } else pe[u] = 0.f;
    }
    // phase 4: accumulate (plain FMA chains)
    #pragma unroll
    for (int u = 0; u < UNR; ++u) denom += pe[u];
    #pragma unroll
    for (int q = 0; q < CPL; ++q){
      float a = acc[q];
      #pragma unroll
      for (int u = 0; u < UNR; ++u) a += pe[u]*xls[u][q];
      acc[q] = a;
    }
  }
  float inv = 1.0f / denom;     // self-loop guarantees denom > 0
  #pragma unroll
  for (int q = 0; q < CPL; ++q)
    out[(size_t)n*C + c0 + q] = acc[q]*inv + bias[c0 + q];
}

// ---------------- batchnorm -------------------------------------------------
__global__ void k_bnstats(const float* __restrict__ x, float* __restrict__ sums,
                          int N, int C){
  int c = threadIdx.x;           // blockDim = C
  float s = 0.f, s2 = 0.f;
  for (int r = blockIdx.x; r < N; r += gridDim.x){
    float v = x[(size_t)r*C + c];
    s += v; s2 += v*v;
  }
  atomicAdd(&sums[c], s);
  atomicAdd(&sums[C + c], s2);
}

__global__ void k_bnapply(float* __restrict__ xio, const float* __restrict__ sums,
                          const float* __restrict__ gam, const float* __restrict__ bet,
                          int N, int C){
  size_t i = (size_t)blockIdx.x*blockDim.x + threadIdx.x;
  if (i >= (size_t)N*C) return;
  int c = (int)(i % C);
  float invN = 1.0f / (float)N;
  float mu  = sums[c] * invN;
  float var = sums[C + c] * invN - mu*mu;
  float v = (xio[i] - mu) * rsqrtf(var + BN_EPS) * gam[c] + bet[c];
  xio[i] = (v >= 0.f) ? v : LEAKY_ACT*v;
}

// -------- fused BN-apply + leaky + gate dot (layer 2, C=256, wave/row) ------
__global__ __launch_bounds__(256) void k_bnapply_gate(
    float* __restrict__ d2, const float* __restrict__ sums,
    const float* __restrict__ gam, const float* __restrict__ bet,
    const float* __restrict__ Wg, const float* __restrict__ bg,
    const int* __restrict__ batch, float* __restrict__ gate,
    unsigned* __restrict__ gm, int N){
  int wid = threadIdx.x >> 6, lane = threadIdx.x & 63;
  int n = blockIdx.x*4 + wid;
  if (n >= N) return;
  int c0 = lane*4;
  float invN = 1.0f / (float)N;
  float4 sv  = *reinterpret_cast<const float4*>(&sums[c0]);
  float4 s2v = *reinterpret_cast<const float4*>(&sums[256 + c0]);
  float4 gv  = *reinterpret_cast<const float4*>(&gam[c0]);
  float4 bv  = *reinterpret_cast<const float4*>(&bet[c0]);
  float4 wgv = *reinterpret_cast<const float4*>(&Wg[c0]);
  float4 x   = *reinterpret_cast<const float4*>(&d2[(size_t)n*256 + c0]);
  float mu0 = sv.x*invN, mu1 = sv.y*invN, mu2 = sv.z*invN, mu3 = sv.w*invN;
  float r0 = rsqrtf(s2v.x*invN - mu0*mu0 + BN_EPS);
  float r1 = rsqrtf(s2v.y*invN - mu1*mu1 + BN_EPS);
  float r2 = rsqrtf(s2v.z*invN - mu2*mu2 + BN_EPS);
  float r3 = rsqrtf(s2v.w*invN - mu3*mu3 + BN_EPS);
  float v0 = (x.x - mu0)*r0*gv.x + bv.x;  v0 = (v0 >= 0.f) ? v0 : LEAKY_ACT*v0;
  float v1 = (x.y - mu1)*r1*gv.y + bv.y;  v1 = (v1 >= 0.f) ? v1 : LEAKY_ACT*v1;
  float v2 = (x.z - mu2)*r2*gv.z + bv.z;  v2 = (v2 >= 0.f) ? v2 : LEAKY_ACT*v2;
  float v3 = (x.w - mu3)*r3*gv.w + bv.w;  v3 = (v3 >= 0.f) ? v3 : LEAKY_ACT*v3;
  *reinterpret_cast<float4*>(&d2[(size_t)n*256 + c0]) = make_float4(v0,v1,v2,v3);
  float s = v0*wgv.x + v1*wgv.y + v2*wgv.z + v3*wgv.w;
  #pragma unroll
  for (int off = 32; off; off >>= 1) s += __shfl_xor(s, off);
  if (lane == 0){
    float g = s + bg[0];
    gate[n] = g;
    atomicMax(&gm[batch[n]], enc_f(g));
  }
}

// ---------------- graph softmax + pooled output -----------------------------
__global__ void k_gexp(float* __restrict__ gate, const int* __restrict__ batch,
                       const unsigned* __restrict__ gm, float* __restrict__ gden, int N){
  int n = blockIdx.x*blockDim.x + threadIdx.x;
  if (n >= N) return;
  int b = batch[n];
  float ex = __expf(gate[n] - dec_f(gm[b]));
  atomicAdd(&gden[b], ex);
  gate[n] = ex;
}

__global__ void k_gptr(const int* __restrict__ batch, int* __restrict__ gptr, int N, int G){
  int n = blockIdx.x*blockDim.x + threadIdx.x;
  if (n > N) return;
  if (n == N){
    int last = batch[N-1];
    for (int g = last+1; g <= G; ++g) gptr[g] = N;
    return;
  }
  int bc = batch[n];
  int bp = (n == 0) ? -1 : batch[n-1];
  for (int g = bp+1; g <= bc; ++g) gptr[g] = n;
}

__global__ void k_final(const float* __restrict__ d2, const float* __restrict__ w,
                        const float* __restrict__ gden, const int* __restrict__ gptr,
                        float* __restrict__ out){
  int g = blockIdx.x;
  int c = threadIdx.x;           // 256
  int s = gptr[g], e = gptr[g+1];
  float den = gden[g];
  if (den == 0.f) den = 1.f;
  float acc = 0.f;
  for (int n = s; n < e; ++n)
    acc += d2[(size_t)n*256 + c] * w[n];
  out[(size_t)g*256 + c] = acc / den;
}

// ============================================================================
extern "C" void kernel_launch(void* const* d_in, const int* in_sizes, int n_in,
                              void* d_out, int out_size, void* d_ws, size_t ws_size,
                              hipStream_t stream){
  const float* x         = (const float*)d_in[0];
  const int*   edge_idx  = (const int*)  d_in[1];
  const float* edge_attr = (const float*)d_in[2];
  const int*   batch     = (const int*)  d_in[3];
  const float* emb       = (const float*)d_in[4];
  const float* Wl1 = (const float*)d_in[5];  const float* bl1 = (const float*)d_in[6];
  const float* Wr1 = (const float*)d_in[7];  const float* br1 = (const float*)d_in[8];
  const float* We1 = (const float*)d_in[9];  const float* att1= (const float*)d_in[10];
  const float* bias1=(const float*)d_in[11]; const float* g1  = (const float*)d_in[12];
  const float* be1 = (const float*)d_in[13];
  const float* Wl2 = (const float*)d_in[14]; const float* bl2 = (const float*)d_in[15];
  const float* Wr2 = (const float*)d_in[16]; const float* br2 = (const float*)d_in[17];
  const float* We2 = (const float*)d_in[18]; const float* att2= (const float*)d_in[19];
  const float* bias2=(const float*)d_in[20]; const float* g2  = (const float*)d_in[21];
  const float* be2 = (const float*)d_in[22];
  const float* Wg  = (const float*)d_in[23]; const float* bg  = (const float*)d_in[24];
  float* out = (float*)d_out;

  const int N = in_sizes[0] / 64;        // 50000
  const int E = in_sizes[1] / 2;         // 800000
  const int EP = E + N;                  // with self-loops
  const int G = 256;
  const int* srcv = edge_idx;
  const int* dstv = edge_idx + E;

  // ---- workspace layout (element offsets, 64-elem aligned) ----
  float* ws = (float*)d_ws;
  size_t o = 0;
  auto alloc = [&](size_t elems){ size_t r = o; o += (elems + 63) & ~(size_t)63; return r; };
  size_t o_big1  = alloc((size_t)N*128);  // h (f32), later xlb2 (bf16, N*256*2B)
  size_t o_union = alloc((size_t)N*256);  // [xr1 | d1] f32, later d2 f32
  size_t o_xlb1  = alloc((size_t)N*64);   // xlb1 (bf16, N*128*2B)
  size_t o_xr2   = alloc((size_t)N*256);
  size_t o_ea    = alloc((size_t)N*16);
  size_t o_gate  = alloc((size_t)N);
  size_t o_bn1   = alloc(2*128);
  size_t o_bn2   = alloc(2*256);
  size_t o_deg   = alloc((size_t)N);
  size_t o_rp    = alloc((size_t)N+1);
  size_t o_cur   = alloc((size_t)N);
  size_t o_csr   = alloc((size_t)EP);
  size_t o_gm    = alloc(G);
  size_t o_gden  = alloc(G);
  size_t o_gptr  = alloc(G+1);

  float* h    = ws + o_big1;
  unsigned short* xlb2 = (unsigned short*)(ws + o_big1);   // after h is dead
  float* xr1  = ws + o_union;                // first N*128
  float* d1   = ws + o_union + (size_t)N*128;
  float* d2   = ws + o_union;                // full N*256, after xr1/d1 dead
  unsigned short* xlb1 = (unsigned short*)(ws + o_xlb1);
  float* xr2  = ws + o_xr2;
  float* eam  = ws + o_ea;
  float* gate = ws + o_gate;
  float* bn1  = ws + o_bn1;
  float* bn2  = ws + o_bn2;
  int*   deg  = (int*)(ws + o_deg);
  int*   rp   = (int*)(ws + o_rp);
  int*   cur  = (int*)(ws + o_cur);
  int*   csr  = (int*)(ws + o_csr);
  unsigned* gm = (unsigned*)(ws + o_gm);
  float* gden = ws + o_gden;
  int*   gptr = (int*)(ws + o_gptr);

  // ---- zero accumulators (every call: graph replays must be deterministic) ----
  hipMemsetAsync(deg,  0, (size_t)N*4, stream);
  hipMemsetAsync(cur,  0, (size_t)N*4, stream);
  hipMemsetAsync(bn1,  0, 2*128*4, stream);
  hipMemsetAsync(bn2,  0, 2*256*4, stream);
  hipMemsetAsync(gm,   0, G*4, stream);          // 0 == encoded minimum
  hipMemsetAsync(gden, 0, G*4, stream);

  auto nblk = [](long long n, int b){ return (int)((n + b - 1) / b); };

  // ---- graph prep ----
  k_embed<<<N, 64, 0, stream>>>(x, emb, h, N);
  k_deg<<<nblk(E,256), 256, 0, stream>>>(dstv, deg, E);
  k_scan<<<1, 256, 0, stream>>>(deg, rp, N);
  k_csrfill<<<nblk(EP,256), 256, 0, stream>>>(dstv, rp, cur, csr, E, N);
  k_eamean<<<nblk(N,4), 256, 0, stream>>>(rp, csr, edge_attr, eam, E, N);

  // ---- layer 1 (C=128) ----
  {
    dim3 grid(nblk(N,GBM), 2*128/GBN);   // y: 2 xl tiles + 2 xr tiles
    k_gemm_dual<<<grid, 256, 0, stream>>>(h, Wl1, bl1, Wr1, br1, xlb1, xr1, N, 128, 128);
  }
  k_gat_fused<128,8><<<nblk(N,4), 256, 0, stream>>>(rp, csr, srcv, edge_attr, eam,
      xlb1, xr1, We1, att1, bias1, d1, E, N);
  k_bnstats<<<512, 128, 0, stream>>>(d1, bn1, N, 128);
  k_bnapply<<<nblk((long long)N*128,256), 256, 0, stream>>>(d1, bn1, g1, be1, N, 128);

  // ---- layer 2 (C=256) ----
  {
    dim3 grid(nblk(N,GBM), 2*256/GBN);   // y: 4 xl tiles + 4 xr tiles
    k_gemm_dual<<<grid, 256, 0, stream>>>(d1, Wl2, bl2, Wr2, br2, xlb2, xr2, N, 128, 256);
  }
  k_gat_fused<256,8><<<nblk(N,4), 256, 0, stream>>>(rp, csr, srcv, edge_attr, eam,
      xlb2, xr2, We2, att2, bias2, d2, E, N);
  k_bnstats<<<512, 256, 0, stream>>>(d2, bn2, N, 256);
  k_bnapply_gate<<<nblk(N,4), 256, 0, stream>>>(d2, bn2, g2, be2, Wg, bg, batch,
      gate, gm, N);

  // ---- attentional aggregation ----
  k_gexp<<<nblk(N,256), 256, 0, stream>>>(gate, batch, gm, gden, N);
  k_gptr<<<nblk((long long)N+1,256), 256, 0, stream>>>(batch, gptr, N, G);
  k_final<<<G, 256, 0, stream>>>(d2, gate, gden, gptr, out);
}

// Round 6
// 1835.170 us; speedup vs baseline: 1.0490x; 1.0490x over previous
//
#include <hip/hip_runtime.h>
#include <cstddef>
#include <cstdint>

#define LEAKY_ATT 0.2f
#define LEAKY_ACT 0.01f
#define BN_EPS 1e-5f

static __device__ __forceinline__ unsigned enc_f(float f){
  unsigned u = __float_as_uint(f);
  return (u & 0x80000000u) ? ~u : (u | 0x80000000u);
}
static __device__ __forceinline__ float dec_f(unsigned k){
  return (k & 0x80000000u) ? __uint_as_float(k & 0x7fffffffu) : __uint_as_float(~k);
}
// round-to-nearest-even f32 -> bf16
static __device__ __forceinline__ unsigned short f2bf(float f){
  unsigned u = __float_as_uint(f);
  unsigned r = u + 0x7fffu + ((u >> 16) & 1u);
  return (unsigned short)(r >> 16);
}
static __device__ __forceinline__ float bf_lo(unsigned u){ return __uint_as_float(u << 16); }
static __device__ __forceinline__ float bf_hi(unsigned u){ return __uint_as_float(u & 0xffff0000u); }

// ---------------- argmax + embedding lookup: h[n] = emb[argmax(x[n])] --------
__global__ void k_embed(const float* __restrict__ x, const float* __restrict__ emb,
                        float* __restrict__ h, int N){
  int n = blockIdx.x; if (n >= N) return;
  int t = threadIdx.x;            // 64 threads = 1 wave
  float v = x[(size_t)n*64 + t];
  int idx = t;
  #pragma unroll
  for (int off = 32; off; off >>= 1){
    float ov = __shfl_down(v, off);
    int   oi = __shfl_down(idx, off);
    if (ov > v || (ov == v && oi < idx)) { v = ov; idx = oi; }  // first max wins
  }
  idx = __shfl(idx, 0);
  h[(size_t)n*128 + t]      = emb[(size_t)idx*128 + t];
  h[(size_t)n*128 + 64 + t] = emb[(size_t)idx*128 + 64 + t];
}

// ---------------- degree per dst --------------------------------------------
__global__ void k_deg(const int* __restrict__ dst, int* __restrict__ deg, int E){
  int e = blockIdx.x*blockDim.x + threadIdx.x;
  if (e >= E) return;
  atomicAdd(&deg[dst[e]], 1);
}

// ---------------- single-block exclusive scan of (deg[i]+1) -----------------
__global__ void k_scan(const int* __restrict__ deg, int* __restrict__ rowptr, int N){
  __shared__ int sd[256];
  __shared__ int sbase;
  if (threadIdx.x == 0) sbase = 0;
  __syncthreads();
  for (int base = 0; base < N; base += 256){
    int i = base + threadIdx.x;
    int v = (i < N) ? (deg[i] + 1) : 0;
    sd[threadIdx.x] = v;
    __syncthreads();
    for (int off = 1; off < 256; off <<= 1){
      int t = (threadIdx.x >= off) ? sd[threadIdx.x - off] : 0;
      __syncthreads();
      sd[threadIdx.x] += t;
      __syncthreads();
    }
    if (i < N) rowptr[i] = sbase + sd[threadIdx.x] - v;   // exclusive
    int tot = sd[255];
    __syncthreads();
    if (threadIdx.x == 0) sbase += tot;
    __syncthreads();
  }
  if (threadIdx.x == 0) rowptr[N] = sbase;
}

// ---------------- CSR fill (edges then self-loops) --------------------------
__global__ void k_csrfill(const int* __restrict__ dst, const int* __restrict__ rowptr,
                          int* __restrict__ cur, int* __restrict__ csr, int E, int N){
  int i = blockIdx.x*blockDim.x + threadIdx.x;
  if (i >= E + N) return;
  int d = (i < E) ? dst[i] : (i - E);
  int pos = atomicAdd(&cur[d], 1);
  csr[rowptr[d] + pos] = i;
}

// ---------------- per-dst mean of edge_attr (CSR-based, no atomics) ---------
__global__ void k_eamean(const int* __restrict__ rowptr, const int* __restrict__ csr,
                         const float* __restrict__ ea, float* __restrict__ eam,
                         int E, int N){
  int wid = threadIdx.x >> 6, lane = threadIdx.x & 63;
  int n = blockIdx.x*4 + wid;
  if (n >= N) return;
  int start = rowptr[n], end = rowptr[n+1];
  int j = lane >> 4, k = lane & 15;   // 4 edges x 16 features per pass
  float s = 0.f;
  for (int i = start + j; i < end; i += 4){
    int e = csr[i];
    if (e < E) s += ea[(size_t)e*16 + k];
  }
  s += __shfl_xor(s, 16);
  s += __shfl_xor(s, 32);
  if (lane < 16){
    int deg = end - start - 1;       // real in-degree (one self-loop per node)
    eam[(size_t)n*16 + k] = s / (float)max(deg, 1);
  }
}

// ---------------- dual GEMM: [xl|xr] = A[N,K] @ [Wl|Wr] + [bl|br] -----------
// blockIdx.y < C/64 -> xl half, written as packed bf16; else xr half, f32.
#define GBM 64
#define GBN 64
#define GBK 32
__global__ __launch_bounds__(256) void k_gemm_dual(const float* __restrict__ A,
                       const float* __restrict__ Wl, const float* __restrict__ bl,
                       const float* __restrict__ Wr, const float* __restrict__ br,
                       unsigned short* __restrict__ xlb, float* __restrict__ xr,
                       int N, int K, int C){
  __shared__ float As[GBM*33];
  __shared__ float Ws[GBK*GBN];
  int tid = threadIdx.x;
  int tx = tid & 15, ty = tid >> 4;
  int m0 = blockIdx.x*GBM;
  int n0g = blockIdx.y*GBN;
  bool isL = (n0g < C);
  int n0 = isL ? n0g : n0g - C;
  const float* W    = isL ? Wl : Wr;
  const float* bias = isL ? bl : br;
  float acc[4][4] = {};
  for (int k0 = 0; k0 < K; k0 += GBK){
    for (int i = tid; i < (GBM*GBK)/4; i += 256){
      int flat = i*4; int r = flat >> 5; int c = flat & 31;
      float4 v = make_float4(0.f,0.f,0.f,0.f);
      if (m0 + r < N) v = *reinterpret_cast<const float4*>(&A[(size_t)(m0+r)*K + k0 + c]);
      As[r*33 + c]   = v.x; As[r*33 + c+1] = v.y;
      As[r*33 + c+2] = v.z; As[r*33 + c+3] = v.w;
    }
    for (int i = tid; i < (GBK*GBN)/4; i += 256){
      int flat = i*4; int r = flat >> 6; int c = flat & 63;
      *reinterpret_cast<float4*>(&Ws[r*GBN + c]) =
        *reinterpret_cast<const float4*>(&W[(size_t)(k0+r)*C + n0 + c]);
    }
    __syncthreads();
    #pragma unroll
    for (int kk = 0; kk < GBK; ++kk){
      float a[4];
      #pragma unroll
      for (int i = 0; i < 4; ++i) a[i] = As[(ty*4+i)*33 + kk];
      float4 wv = *reinterpret_cast<const float4*>(&Ws[kk*GBN + tx*4]);
      float w[4] = {wv.x, wv.y, wv.z, wv.w};
      #pragma unroll
      for (int i = 0; i < 4; ++i)
        #pragma unroll
        for (int j = 0; j < 4; ++j) acc[i][j] += a[i]*w[j];
    }
    __syncthreads();
  }
  int cb = n0 + tx*4;
  float b0 = bias[cb], b1 = bias[cb+1], b2 = bias[cb+2], b3 = bias[cb+3];
  #pragma unroll
  for (int i = 0; i < 4; ++i){
    int r = m0 + ty*4 + i;
    if (r >= N) continue;
    float v0 = acc[i][0]+b0, v1 = acc[i][1]+b1, v2 = acc[i][2]+b2, v3 = acc[i][3]+b3;
    if (isL){
      unsigned p0 = (unsigned)f2bf(v0) | ((unsigned)f2bf(v1) << 16);
      unsigned p1 = (unsigned)f2bf(v2) | ((unsigned)f2bf(v3) << 16);
      *reinterpret_cast<uint2*>(&xlb[(size_t)r*C + cb]) = make_uint2(p0, p1);
    } else {
      *reinterpret_cast<float4*>(&xr[(size_t)r*C + cb]) = make_float4(v0, v1, v2, v3);
    }
  }
}

// ---------------- fused GATv2: logits + softmax + aggregation ---------------
// One wave per dst node; UNR edges in flight. xl table bf16; accum f32.
// No max-subtraction (logits O(1) by construction, softmax shift-invariant).
// launch_bounds (256,2): <=256 VGPRs so wreg/xls stay IN REGISTERS — the
// (256,4) variant capped at 64 VGPRs and spilled wreg to scratch, generating
// >1.5 GB of HBM scratch traffic per dispatch (R3-R5 counters).
template<int C, int UNR>
__global__ __launch_bounds__(256, 2) void k_gat_fused(
    const int* __restrict__ rowptr, const int* __restrict__ csr,
    const int* __restrict__ srcv, const float* __restrict__ edge_attr,
    const float* __restrict__ eam, const unsigned short* __restrict__ xlb,
    const float* __restrict__ xr, const float* __restrict__ We,
    const float* __restrict__ att, const float* __restrict__ bias,
    float* __restrict__ out, int E, int N)
{
  constexpr int CPL = C/64;
  int wid = threadIdx.x >> 6, lane = threadIdx.x & 63;
  int n = blockIdx.x*4 + wid;
  if (n >= N) return;
  const int c0 = lane*CPL;

  // hoist We column-slice + att + xr row into registers (loop-invariant)
  float wreg[16][CPL];
  #pragma unroll
  for (int k = 0; k < 16; ++k)
    #pragma unroll
    for (int q = 0; q < CPL; ++q)
      wreg[k][q] = We[k*C + c0 + q];
  float attv[CPL], xrv[CPL];
  #pragma unroll
  for (int q = 0; q < CPL; ++q){
    attv[q] = att[c0 + q];
    xrv[q]  = xr[(size_t)n*C + c0 + q];
  }

  int start = __builtin_amdgcn_readfirstlane(rowptr[n]);
  int end   = __builtin_amdgcn_readfirstlane(rowptr[n+1]);

  float denom = 0.f;
  float acc[CPL] = {};

  for (int i = start; i < end; i += UNR){
    // phase 1: resolve edge/src ids (scalar, wave-uniform)
    int sids[UNR]; const float* eaps[UNR];
    #pragma unroll
    for (int u = 0; u < UNR; ++u){
      if (i + u < end){
        int e = __builtin_amdgcn_readfirstlane(csr[i + u]);
        if (e < E){ sids[u] = __builtin_amdgcn_readfirstlane(srcv[e]);
                    eaps[u] = edge_attr + (size_t)e*16; }
        else      { sids[u] = e - E;
                    eaps[u] = eam + (size_t)(e-E)*16; }
      } else { sids[u] = 0; eaps[u] = eam; }
    }
    // phase 2: issue all row gathers (bf16 -> f32)
    float xls[UNR][CPL];
    #pragma unroll
    for (int u = 0; u < UNR; ++u){
      if (i + u < end){
        const unsigned short* prow = xlb + (size_t)sids[u]*C + c0;
        if constexpr (CPL == 4){
          uint2 v = *reinterpret_cast<const uint2*>(prow);
          xls[u][0]=bf_lo(v.x); xls[u][1]=bf_hi(v.x);
          xls[u][2]=bf_lo(v.y); xls[u][3]=bf_hi(v.y);
        } else {
          unsigned v = *reinterpret_cast<const unsigned*>(prow);
          xls[u][0]=bf_lo(v); xls[u][1]=bf_hi(v);
        }
      } else {
        #pragma unroll
        for (int q = 0; q < CPL; ++q) xls[u][q] = 0.f;
      }
    }
    // phase 3: logits + exp (independent per edge)
    float pe[UNR];
    #pragma unroll
    for (int u = 0; u < UNR; ++u){
      if (i + u < end){
        float w[CPL] = {};
        #pragma unroll
        for (int k = 0; k < 16; ++k){
          float a = eaps[u][k];            // wave-uniform scalar load
          #pragma unroll
          for (int q = 0; q < CPL; ++q) w[q] += a * wreg[k][q];
        }
        float p = 0.f;
        #pragma unroll
        for (int q = 0; q < CPL; ++q){
          float v = xls[u][q] + xrv[q] + w[q];
          v = (v >= 0.f) ? v : LEAKY_ATT*v;
          p += attv[q]*v;
        }
        #pragma unroll
        for (int off = 32; off; off >>= 1) p += __shfl_xor(p, off);
        pe[u] = __expf(p);
      } else pe[u] = 0.f;
    }
    // phase 4: accumulate (plain FMA chains)
    #pragma unroll
    for (int u = 0; u < UNR; ++u) denom += pe[u];
    #pragma unroll
    for (int q = 0; q < CPL; ++q){
      float a = acc[q];
      #pragma unroll
      for (int u = 0; u < UNR; ++u) a += pe[u]*xls[u][q];
      acc[q] = a;
    }
  }
  float inv = 1.0f / denom;     // self-loop guarantees denom > 0
  #pragma unroll
  for (int q = 0; q < CPL; ++q)
    out[(size_t)n*C + c0 + q] = acc[q]*inv + bias[c0 + q];
}

// ---------------- batchnorm -------------------------------------------------
__global__ void k_bnstats(const float* __restrict__ x, float* __restrict__ sums,
                          int N, int C){
  int c = threadIdx.x;           // blockDim = C
  float s = 0.f, s2 = 0.f;
  for (int r = blockIdx.x; r < N; r += gridDim.x){
    float v = x[(size_t)r*C + c];
    s += v; s2 += v*v;
  }
  atomicAdd(&sums[c], s);
  atomicAdd(&sums[C + c], s2);
}

__global__ void k_bnapply(float* __restrict__ xio, const float* __restrict__ sums,
                          const float* __restrict__ gam, const float* __restrict__ bet,
                          int N, int C){
  size_t i = (size_t)blockIdx.x*blockDim.x + threadIdx.x;
  if (i >= (size_t)N*C) return;
  int c = (int)(i % C);
  float invN = 1.0f / (float)N;
  float mu  = sums[c] * invN;
  float var = sums[C + c] * invN - mu*mu;
  float v = (xio[i] - mu) * rsqrtf(var + BN_EPS) * gam[c] + bet[c];
  xio[i] = (v >= 0.f) ? v : LEAKY_ACT*v;
}

// -------- fused BN-apply + leaky + gate dot (layer 2, C=256, wave/row) ------
__global__ __launch_bounds__(256) void k_bnapply_gate(
    float* __restrict__ d2, const float* __restrict__ sums,
    const float* __restrict__ gam, const float* __restrict__ bet,
    const float* __restrict__ Wg, const float* __restrict__ bg,
    const int* __restrict__ batch, float* __restrict__ gate,
    unsigned* __restrict__ gm, int N){
  int wid = threadIdx.x >> 6, lane = threadIdx.x & 63;
  int n = blockIdx.x*4 + wid;
  if (n >= N) return;
  int c0 = lane*4;
  float invN = 1.0f / (float)N;
  float4 sv  = *reinterpret_cast<const float4*>(&sums[c0]);
  float4 s2v = *reinterpret_cast<const float4*>(&sums[256 + c0]);
  float4 gv  = *reinterpret_cast<const float4*>(&gam[c0]);
  float4 bv  = *reinterpret_cast<const float4*>(&bet[c0]);
  float4 wgv = *reinterpret_cast<const float4*>(&Wg[c0]);
  float4 x   = *reinterpret_cast<const float4*>(&d2[(size_t)n*256 + c0]);
  float mu0 = sv.x*invN, mu1 = sv.y*invN, mu2 = sv.z*invN, mu3 = sv.w*invN;
  float r0 = rsqrtf(s2v.x*invN - mu0*mu0 + BN_EPS);
  float r1 = rsqrtf(s2v.y*invN - mu1*mu1 + BN_EPS);
  float r2 = rsqrtf(s2v.z*invN - mu2*mu2 + BN_EPS);
  float r3 = rsqrtf(s2v.w*invN - mu3*mu3 + BN_EPS);
  float v0 = (x.x - mu0)*r0*gv.x + bv.x;  v0 = (v0 >= 0.f) ? v0 : LEAKY_ACT*v0;
  float v1 = (x.y - mu1)*r1*gv.y + bv.y;  v1 = (v1 >= 0.f) ? v1 : LEAKY_ACT*v1;
  float v2 = (x.z - mu2)*r2*gv.z + bv.z;  v2 = (v2 >= 0.f) ? v2 : LEAKY_ACT*v2;
  float v3 = (x.w - mu3)*r3*gv.w + bv.w;  v3 = (v3 >= 0.f) ? v3 : LEAKY_ACT*v3;
  *reinterpret_cast<float4*>(&d2[(size_t)n*256 + c0]) = make_float4(v0,v1,v2,v3);
  float s = v0*wgv.x + v1*wgv.y + v2*wgv.z + v3*wgv.w;
  #pragma unroll
  for (int off = 32; off; off >>= 1) s += __shfl_xor(s, off);
  if (lane == 0){
    float g = s + bg[0];
    gate[n] = g;
    atomicMax(&gm[batch[n]], enc_f(g));
  }
}

// ---------------- graph softmax + pooled output -----------------------------
__global__ void k_gexp(float* __restrict__ gate, const int* __restrict__ batch,
                       const unsigned* __restrict__ gm, float* __restrict__ gden, int N){
  int n = blockIdx.x*blockDim.x + threadIdx.x;
  if (n >= N) return;
  int b = batch[n];
  float ex = __expf(gate[n] - dec_f(gm[b]));
  atomicAdd(&gden[b], ex);
  gate[n] = ex;
}

__global__ void k_gptr(const int* __restrict__ batch, int* __restrict__ gptr, int N, int G){
  int n = blockIdx.x*blockDim.x + threadIdx.x;
  if (n > N) return;
  if (n == N){
    int last = batch[N-1];
    for (int g = last+1; g <= G; ++g) gptr[g] = N;
    return;
  }
  int bc = batch[n];
  int bp = (n == 0) ? -1 : batch[n-1];
  for (int g = bp+1; g <= bc; ++g) gptr[g] = n;
}

__global__ void k_final(const float* __restrict__ d2, const float* __restrict__ w,
                        const float* __restrict__ gden, const int* __restrict__ gptr,
                        float* __restrict__ out){
  int g = blockIdx.x;
  int c = threadIdx.x;           // 256
  int s = gptr[g], e = gptr[g+1];
  float den = gden[g];
  if (den == 0.f) den = 1.f;
  float acc = 0.f;
  for (int n = s; n < e; ++n)
    acc += d2[(size_t)n*256 + c] * w[n];
  out[(size_t)g*256 + c] = acc / den;
}

// ============================================================================
extern "C" void kernel_launch(void* const* d_in, const int* in_sizes, int n_in,
                              void* d_out, int out_size, void* d_ws, size_t ws_size,
                              hipStream_t stream){
  const float* x         = (const float*)d_in[0];
  const int*   edge_idx  = (const int*)  d_in[1];
  const float* edge_attr = (const float*)d_in[2];
  const int*   batch     = (const int*)  d_in[3];
  const float* emb       = (const float*)d_in[4];
  const float* Wl1 = (const float*)d_in[5];  const float* bl1 = (const float*)d_in[6];
  const float* Wr1 = (const float*)d_in[7];  const float* br1 = (const float*)d_in[8];
  const float* We1 = (const float*)d_in[9];  const float* att1= (const float*)d_in[10];
  const float* bias1=(const float*)d_in[11]; const float* g1  = (const float*)d_in[12];
  const float* be1 = (const float*)d_in[13];
  const float* Wl2 = (const float*)d_in[14]; const float* bl2 = (const float*)d_in[15];
  const float* Wr2 = (const float*)d_in[16]; const float* br2 = (const float*)d_in[17];
  const float* We2 = (const float*)d_in[18]; const float* att2= (const float*)d_in[19];
  const float* bias2=(const float*)d_in[20]; const float* g2  = (const float*)d_in[21];
  const float* be2 = (const float*)d_in[22];
  const float* Wg  = (const float*)d_in[23]; const float* bg  = (const float*)d_in[24];
  float* out = (float*)d_out;

  const int N = in_sizes[0] / 64;        // 50000
  const int E = in_sizes[1] / 2;         // 800000
  const int EP = E + N;                  // with self-loops
  const int G = 256;
  const int* srcv = edge_idx;
  const int* dstv = edge_idx + E;

  // ---- workspace layout (element offsets, 64-elem aligned) ----
  float* ws = (float*)d_ws;
  size_t o = 0;
  auto alloc = [&](size_t elems){ size_t r = o; o += (elems + 63) & ~(size_t)63; return r; };
  size_t o_big1  = alloc((size_t)N*128);  // h (f32), later xlb2 (bf16, N*256*2B)
  size_t o_union = alloc((size_t)N*256);  // [xr1 | d1] f32, later d2 f32
  size_t o_xlb1  = alloc((size_t)N*64);   // xlb1 (bf16, N*128*2B)
  size_t o_xr2   = alloc((size_t)N*256);
  size_t o_ea    = alloc((size_t)N*16);
  size_t o_gate  = alloc((size_t)N);
  size_t o_bn1   = alloc(2*128);
  size_t o_bn2   = alloc(2*256);
  size_t o_deg   = alloc((size_t)N);
  size_t o_rp    = alloc((size_t)N+1);
  size_t o_cur   = alloc((size_t)N);
  size_t o_csr   = alloc((size_t)EP);
  size_t o_gm    = alloc(G);
  size_t o_gden  = alloc(G);
  size_t o_gptr  = alloc(G+1);

  float* h    = ws + o_big1;
  unsigned short* xlb2 = (unsigned short*)(ws + o_big1);   // after h is dead
  float* xr1  = ws + o_union;                // first N*128
  float* d1   = ws + o_union + (size_t)N*128;
  float* d2   = ws + o_union;                // full N*256, after xr1/d1 dead
  unsigned short* xlb1 = (unsigned short*)(ws + o_xlb1);
  float* xr2  = ws + o_xr2;
  float* eam  = ws + o_ea;
  float* gate = ws + o_gate;
  float* bn1  = ws + o_bn1;
  float* bn2  = ws + o_bn2;
  int*   deg  = (int*)(ws + o_deg);
  int*   rp   = (int*)(ws + o_rp);
  int*   cur  = (int*)(ws + o_cur);
  int*   csr  = (int*)(ws + o_csr);
  unsigned* gm = (unsigned*)(ws + o_gm);
  float* gden = ws + o_gden;
  int*   gptr = (int*)(ws + o_gptr);

  // ---- zero accumulators (every call: graph replays must be deterministic) ----
  hipMemsetAsync(deg,  0, (size_t)N*4, stream);
  hipMemsetAsync(cur,  0, (size_t)N*4, stream);
  hipMemsetAsync(bn1,  0, 2*128*4, stream);
  hipMemsetAsync(bn2,  0, 2*256*4, stream);
  hipMemsetAsync(gm,   0, G*4, stream);          // 0 == encoded minimum
  hipMemsetAsync(gden, 0, G*4, stream);

  auto nblk = [](long long n, int b){ return (int)((n + b - 1) / b); };

  // ---- graph prep ----
  k_embed<<<N, 64, 0, stream>>>(x, emb, h, N);
  k_deg<<<nblk(E,256), 256, 0, stream>>>(dstv, deg, E);
  k_scan<<<1, 256, 0, stream>>>(deg, rp, N);
  k_csrfill<<<nblk(EP,256), 256, 0, stream>>>(dstv, rp, cur, csr, E, N);
  k_eamean<<<nblk(N,4), 256, 0, stream>>>(rp, csr, edge_attr, eam, E, N);

  // ---- layer 1 (C=128) ----
  {
    dim3 grid(nblk(N,GBM), 2*128/GBN);   // y: 2 xl tiles + 2 xr tiles
    k_gemm_dual<<<grid, 256, 0, stream>>>(h, Wl1, bl1, Wr1, br1, xlb1, xr1, N, 128, 128);
  }
  k_gat_fused<128,8><<<nblk(N,4), 256, 0, stream>>>(rp, csr, srcv, edge_attr, eam,
      xlb1, xr1, We1, att1, bias1, d1, E, N);
  k_bnstats<<<512, 128, 0, stream>>>(d1, bn1, N, 128);
  k_bnapply<<<nblk((long long)N*128,256), 256, 0, stream>>>(d1, bn1, g1, be1, N, 128);

  // ---- layer 2 (C=256) ----
  {
    dim3 grid(nblk(N,GBM), 2*256/GBN);   // y: 4 xl tiles + 4 xr tiles
    k_gemm_dual<<<grid, 256, 0, stream>>>(d1, Wl2, bl2, Wr2, br2, xlb2, xr2, N, 128, 256);
  }
  k_gat_fused<256,4><<<nblk(N,4), 256, 0, stream>>>(rp, csr, srcv, edge_attr, eam,
      xlb2, xr2, We2, att2, bias2, d2, E, N);
  k_bnstats<<<512, 256, 0, stream>>>(d2, bn2, N, 256);
  k_bnapply_gate<<<nblk(N,4), 256, 0, stream>>>(d2, bn2, g2, be2, Wg, bg, batch,
      gate, gm, N);

  // ---- attentional aggregation ----
  k_gexp<<<nblk(N,256), 256, 0, stream>>>(gate, batch, gm, gden, N);
  k_gptr<<<nblk((long long)N+1,256), 256, 0, stream>>>(batch, gptr, N, G);
  k_final<<<G, 256, 0, stream>>>(d2, gate, gden, gptr, out);
}

// Round 7
// 1459.240 us; speedup vs baseline: 1.3193x; 1.2576x over previous
//
#include <hip/hip_runtime.h>
#include <cstddef>
#include <cstdint>

#define LEAKY_ATT 0.2f
#define LEAKY_ACT 0.01f
#define BN_EPS 1e-5f

static __device__ __forceinline__ unsigned enc_f(float f){
  unsigned u = __float_as_uint(f);
  return (u & 0x80000000u) ? ~u : (u | 0x80000000u);
}
static __device__ __forceinline__ float dec_f(unsigned k){
  return (k & 0x80000000u) ? __uint_as_float(k & 0x7fffffffu) : __uint_as_float(~k);
}
// round-to-nearest-even f32 -> bf16
static __device__ __forceinline__ unsigned short f2bf(float f){
  unsigned u = __float_as_uint(f);
  unsigned r = u + 0x7fffu + ((u >> 16) & 1u);
  return (unsigned short)(r >> 16);
}
static __device__ __forceinline__ float bf_lo(unsigned u){ return __uint_as_float(u << 16); }
static __device__ __forceinline__ float bf_hi(unsigned u){ return __uint_as_float(u & 0xffff0000u); }

// ---------------- argmax + embedding lookup: h[n] = emb[argmax(x[n])] --------
__global__ void k_embed(const float* __restrict__ x, const float* __restrict__ emb,
                        float* __restrict__ h, int N){
  int n = blockIdx.x; if (n >= N) return;
  int t = threadIdx.x;            // 64 threads = 1 wave
  float v = x[(size_t)n*64 + t];
  int idx = t;
  #pragma unroll
  for (int off = 32; off; off >>= 1){
    float ov = __shfl_down(v, off);
    int   oi = __shfl_down(idx, off);
    if (ov > v || (ov == v && oi < idx)) { v = ov; idx = oi; }  // first max wins
  }
  idx = __shfl(idx, 0);
  h[(size_t)n*128 + t]      = emb[(size_t)idx*128 + t];
  h[(size_t)n*128 + 64 + t] = emb[(size_t)idx*128 + 64 + t];
}

// ---------------- degree per dst --------------------------------------------
__global__ void k_deg(const int* __restrict__ dst, int* __restrict__ deg, int E){
  int e = blockIdx.x*blockDim.x + threadIdx.x;
  if (e >= E) return;
  atomicAdd(&deg[dst[e]], 1);
}

// ---------------- single-block exclusive scan of (deg[i]+1) -----------------
__global__ void k_scan(const int* __restrict__ deg, int* __restrict__ rowptr, int N){
  __shared__ int sd[256];
  __shared__ int sbase;
  if (threadIdx.x == 0) sbase = 0;
  __syncthreads();
  for (int base = 0; base < N; base += 256){
    int i = base + threadIdx.x;
    int v = (i < N) ? (deg[i] + 1) : 0;
    sd[threadIdx.x] = v;
    __syncthreads();
    for (int off = 1; off < 256; off <<= 1){
      int t = (threadIdx.x >= off) ? sd[threadIdx.x - off] : 0;
      __syncthreads();
      sd[threadIdx.x] += t;
      __syncthreads();
    }
    if (i < N) rowptr[i] = sbase + sd[threadIdx.x] - v;   // exclusive
    int tot = sd[255];
    __syncthreads();
    if (threadIdx.x == 0) sbase += tot;
    __syncthreads();
  }
  if (threadIdx.x == 0) rowptr[N] = sbase;
}

// ---------------- CSR fill: store {src, edge_id} per slot -------------------
// (fuses the csr->srcv dependent-load chain out of the hot GAT loop)
__global__ void k_csrfill(const int* __restrict__ src, const int* __restrict__ dst,
                          const int* __restrict__ rowptr,
                          int* __restrict__ cur, int2* __restrict__ csr2, int E, int N){
  int i = blockIdx.x*blockDim.x + threadIdx.x;
  if (i >= E + N) return;
  int d, s;
  if (i < E){ d = dst[i]; s = src[i]; }
  else      { d = i - E;  s = i - E;  }
  int pos = atomicAdd(&cur[d], 1);
  csr2[rowptr[d] + pos] = make_int2(s, i);
}

// ---------------- per-dst mean of edge_attr (CSR-based, no atomics) ---------
__global__ void k_eamean(const int* __restrict__ rowptr, const int2* __restrict__ csr2,
                         const float* __restrict__ ea, float* __restrict__ eam,
                         int E, int N){
  int wid = threadIdx.x >> 6, lane = threadIdx.x & 63;
  int n = blockIdx.x*4 + wid;
  if (n >= N) return;
  int start = rowptr[n], end = rowptr[n+1];
  int j = lane >> 4, k = lane & 15;   // 4 edges x 16 features per pass
  float s = 0.f;
  for (int i = start + j; i < end; i += 4){
    int e = csr2[i].y;
    if (e < E) s += ea[(size_t)e*16 + k];
  }
  s += __shfl_xor(s, 16);
  s += __shfl_xor(s, 32);
  if (lane < 16){
    int deg = end - start - 1;       // real in-degree (one self-loop per node)
    eam[(size_t)n*16 + k] = s / (float)max(deg, 1);
  }
}

// ---------------- dual GEMM: [xl|xr] = A[N,K] @ [Wl|Wr] + [bl|br] -----------
// blockIdx.y < C/64 -> xl half, written as packed bf16; else xr half, f32.
#define GBM 64
#define GBN 64
#define GBK 32
__global__ __launch_bounds__(256) void k_gemm_dual(const float* __restrict__ A,
                       const float* __restrict__ Wl, const float* __restrict__ bl,
                       const float* __restrict__ Wr, const float* __restrict__ br,
                       unsigned short* __restrict__ xlb, float* __restrict__ xr,
                       int N, int K, int C){
  __shared__ float As[GBM*33];
  __shared__ float Ws[GBK*GBN];
  int tid = threadIdx.x;
  int tx = tid & 15, ty = tid >> 4;
  int m0 = blockIdx.x*GBM;
  int n0g = blockIdx.y*GBN;
  bool isL = (n0g < C);
  int n0 = isL ? n0g : n0g - C;
  const float* W    = isL ? Wl : Wr;
  const float* bias = isL ? bl : br;
  float acc[4][4] = {};
  for (int k0 = 0; k0 < K; k0 += GBK){
    for (int i = tid; i < (GBM*GBK)/4; i += 256){
      int flat = i*4; int r = flat >> 5; int c = flat & 31;
      float4 v = make_float4(0.f,0.f,0.f,0.f);
      if (m0 + r < N) v = *reinterpret_cast<const float4*>(&A[(size_t)(m0+r)*K + k0 + c]);
      As[r*33 + c]   = v.x; As[r*33 + c+1] = v.y;
      As[r*33 + c+2] = v.z; As[r*33 + c+3] = v.w;
    }
    for (int i = tid; i < (GBK*GBN)/4; i += 256){
      int flat = i*4; int r = flat >> 6; int c = flat & 63;
      *reinterpret_cast<float4*>(&Ws[r*GBN + c]) =
        *reinterpret_cast<const float4*>(&W[(size_t)(k0+r)*C + n0 + c]);
    }
    __syncthreads();
    #pragma unroll
    for (int kk = 0; kk < GBK; ++kk){
      float a[4];
      #pragma unroll
      for (int i = 0; i < 4; ++i) a[i] = As[(ty*4+i)*33 + kk];
      float4 wv = *reinterpret_cast<const float4*>(&Ws[kk*GBN + tx*4]);
      float w[4] = {wv.x, wv.y, wv.z, wv.w};
      #pragma unroll
      for (int i = 0; i < 4; ++i)
        #pragma unroll
        for (int j = 0; j < 4; ++j) acc[i][j] += a[i]*w[j];
    }
    __syncthreads();
  }
  int cb = n0 + tx*4;
  float b0 = bias[cb], b1 = bias[cb+1], b2 = bias[cb+2], b3 = bias[cb+3];
  #pragma unroll
  for (int i = 0; i < 4; ++i){
    int r = m0 + ty*4 + i;
    if (r >= N) continue;
    float v0 = acc[i][0]+b0, v1 = acc[i][1]+b1, v2 = acc[i][2]+b2, v3 = acc[i][3]+b3;
    if (isL){
      unsigned p0 = (unsigned)f2bf(v0) | ((unsigned)f2bf(v1) << 16);
      unsigned p1 = (unsigned)f2bf(v2) | ((unsigned)f2bf(v3) << 16);
      *reinterpret_cast<uint2*>(&xlb[(size_t)r*C + cb]) = make_uint2(p0, p1);
    } else {
      *reinterpret_cast<float4*>(&xr[(size_t)r*C + cb]) = make_float4(v0, v1, v2, v3);
    }
  }
}

// ---------------- fused GATv2: logits + softmax + aggregation ---------------
// PERSISTENT grid-stride waves: each wave handles ~N/4096 nodes, so the
// We/att register setup is paid once per wave (not per node) and waves stay
// resident (no block churn). csr2 holds {src, edge} -> ONE scalar load per
// edge (no dependent csr->srcv chain). UNR edges in flight; xl rows kept as
// PACKED bf16 (uint) regs and unpacked at use to stay under 128 VGPR
// (16 waves/CU). No max-subtraction: logits are O(1) by construction, so
// softmax is computed unshifted and every edge is independent.
template<int C, int UNR>
__global__ __launch_bounds__(256) void k_gat_fused(
    const int* __restrict__ rowptr, const int2* __restrict__ csr2,
    const float* __restrict__ edge_attr, const float* __restrict__ eam,
    const unsigned short* __restrict__ xlb, const float* __restrict__ xr,
    const float* __restrict__ We, const float* __restrict__ att,
    const float* __restrict__ bias, float* __restrict__ out, int E, int N)
{
  constexpr int CPL = C/64;          // 2 or 4 columns per lane
  constexpr int PK  = CPL/2;         // packed uints per edge per lane
  int wid = threadIdx.x >> 6, lane = threadIdx.x & 63;
  int gw  = blockIdx.x*4 + wid;      // global wave id
  int nw  = gridDim.x*4;             // total waves
  const int c0 = lane*CPL;

  // once per wave: We column-slice + att (loop-invariant across nodes)
  float wreg[16][CPL];
  #pragma unroll
  for (int k = 0; k < 16; ++k)
    #pragma unroll
    for (int q = 0; q < CPL; ++q)
      wreg[k][q] = We[k*C + c0 + q];
  float attv[CPL];
  #pragma unroll
  for (int q = 0; q < CPL; ++q) attv[q] = att[c0 + q];

  for (int n = gw; n < N; n += nw){
    float xrv[CPL];
    #pragma unroll
    for (int q = 0; q < CPL; ++q) xrv[q] = xr[(size_t)n*C + c0 + q];
    int start = __builtin_amdgcn_readfirstlane(rowptr[n]);
    int end   = __builtin_amdgcn_readfirstlane(rowptr[n+1]);

    float denom = 0.f;
    float acc[CPL] = {};

    for (int i = start; i < end; i += UNR){
      // phase 1: one scalar load per edge -> {src, edge}
      int sids[UNR]; const float* eaps[UNR];
      #pragma unroll
      for (int u = 0; u < UNR; ++u){
        if (i + u < end){
          int2 v = csr2[i + u];
          sids[u] = __builtin_amdgcn_readfirstlane(v.x);
          int e   = __builtin_amdgcn_readfirstlane(v.y);
          eaps[u] = (e < E) ? edge_attr + (size_t)e*16
                            : eam + (size_t)(e - E)*16;
        } else { sids[u] = 0; eaps[u] = eam; }
      }
      // phase 2: issue all row gathers (packed bf16 kept packed)
      unsigned xp[UNR][PK];
      #pragma unroll
      for (int u = 0; u < UNR; ++u){
        if (i + u < end){
          const unsigned short* prow = xlb + (size_t)sids[u]*C + c0;
          if constexpr (PK == 2){
            uint2 v = *reinterpret_cast<const uint2*>(prow);
            xp[u][0] = v.x; xp[u][1] = v.y;
          } else {
            xp[u][0] = *reinterpret_cast<const unsigned*>(prow);
          }
        } else {
          #pragma unroll
          for (int p = 0; p < PK; ++p) xp[u][p] = 0;
        }
      }
      // phase 3: logits + exp (independent per edge)
      float pe[UNR];
      #pragma unroll
      for (int u = 0; u < UNR; ++u){
        if (i + u < end){
          float w[CPL] = {};
          #pragma unroll
          for (int k = 0; k < 16; ++k){
            float a = eaps[u][k];            // wave-uniform scalar load
            #pragma unroll
            for (int q = 0; q < CPL; ++q) w[q] += a * wreg[k][q];
          }
          float p = 0.f;
          #pragma unroll
          for (int p2 = 0; p2 < PK; ++p2){
            float x0 = bf_lo(xp[u][p2]), x1 = bf_hi(xp[u][p2]);
            float v0 = x0 + xrv[2*p2]   + w[2*p2];
            float v1 = x1 + xrv[2*p2+1] + w[2*p2+1];
            v0 = (v0 >= 0.f) ? v0 : LEAKY_ATT*v0;
            v1 = (v1 >= 0.f) ? v1 : LEAKY_ATT*v1;
            p += attv[2*p2]*v0 + attv[2*p2+1]*v1;
          }
          #pragma unroll
          for (int off = 32; off; off >>= 1) p += __shfl_xor(p, off);
          pe[u] = __expf(p);
        } else pe[u] = 0.f;
      }
      // phase 4: accumulate (unpack packed rows again; pe=0 rows are zeroed)
      #pragma unroll
      for (int u = 0; u < UNR; ++u) denom += pe[u];
      #pragma unroll
      for (int u = 0; u < UNR; ++u){
        #pragma unroll
        for (int p2 = 0; p2 < PK; ++p2){
          acc[2*p2]   += pe[u]*bf_lo(xp[u][p2]);
          acc[2*p2+1] += pe[u]*bf_hi(xp[u][p2]);
        }
      }
    }
    float inv = 1.0f / denom;     // self-loop guarantees denom > 0
    #pragma unroll
    for (int q = 0; q < CPL; ++q)
      out[(size_t)n*C + c0 + q] = acc[q]*inv + bias[c0 + q];
  }
}

// ---------------- batchnorm -------------------------------------------------
__global__ void k_bnstats(const float* __restrict__ x, float* __restrict__ sums,
                          int N, int C){
  int c = threadIdx.x;           // blockDim = C
  float s = 0.f, s2 = 0.f;
  for (int r = blockIdx.x; r < N; r += gridDim.x){
    float v = x[(size_t)r*C + c];
    s += v; s2 += v*v;
  }
  atomicAdd(&sums[c], s);
  atomicAdd(&sums[C + c], s2);
}

__global__ void k_bnapply(float* __restrict__ xio, const float* __restrict__ sums,
                          const float* __restrict__ gam, const float* __restrict__ bet,
                          int N, int C){
  size_t i = (size_t)blockIdx.x*blockDim.x + threadIdx.x;
  if (i >= (size_t)N*C) return;
  int c = (int)(i % C);
  float invN = 1.0f / (float)N;
  float mu  = sums[c] * invN;
  float var = sums[C + c] * invN - mu*mu;
  float v = (xio[i] - mu) * rsqrtf(var + BN_EPS) * gam[c] + bet[c];
  xio[i] = (v >= 0.f) ? v : LEAKY_ACT*v;
}

// -------- fused BN-apply + leaky + gate dot (layer 2, C=256, wave/row) ------
__global__ __launch_bounds__(256) void k_bnapply_gate(
    float* __restrict__ d2, const float* __restrict__ sums,
    const float* __restrict__ gam, const float* __restrict__ bet,
    const float* __restrict__ Wg, const float* __restrict__ bg,
    const int* __restrict__ batch, float* __restrict__ gate,
    unsigned* __restrict__ gm, int N){
  int wid = threadIdx.x >> 6, lane = threadIdx.x & 63;
  int n = blockIdx.x*4 + wid;
  if (n >= N) return;
  int c0 = lane*4;
  float invN = 1.0f / (float)N;
  float4 sv  = *reinterpret_cast<const float4*>(&sums[c0]);
  float4 s2v = *reinterpret_cast<const float4*>(&sums[256 + c0]);
  float4 gv  = *reinterpret_cast<const float4*>(&gam[c0]);
  float4 bv  = *reinterpret_cast<const float4*>(&bet[c0]);
  float4 wgv = *reinterpret_cast<const float4*>(&Wg[c0]);
  float4 x   = *reinterpret_cast<const float4*>(&d2[(size_t)n*256 + c0]);
  float mu0 = sv.x*invN, mu1 = sv.y*invN, mu2 = sv.z*invN, mu3 = sv.w*invN;
  float r0 = rsqrtf(s2v.x*invN - mu0*mu0 + BN_EPS);
  float r1 = rsqrtf(s2v.y*invN - mu1*mu1 + BN_EPS);
  float r2 = rsqrtf(s2v.z*invN - mu2*mu2 + BN_EPS);
  float r3 = rsqrtf(s2v.w*invN - mu3*mu3 + BN_EPS);
  float v0 = (x.x - mu0)*r0*gv.x + bv.x;  v0 = (v0 >= 0.f) ? v0 : LEAKY_ACT*v0;
  float v1 = (x.y - mu1)*r1*gv.y + bv.y;  v1 = (v1 >= 0.f) ? v1 : LEAKY_ACT*v1;
  float v2 = (x.z - mu2)*r2*gv.z + bv.z;  v2 = (v2 >= 0.f) ? v2 : LEAKY_ACT*v2;
  float v3 = (x.w - mu3)*r3*gv.w + bv.w;  v3 = (v3 >= 0.f) ? v3 : LEAKY_ACT*v3;
  *reinterpret_cast<float4*>(&d2[(size_t)n*256 + c0]) = make_float4(v0,v1,v2,v3);
  float s = v0*wgv.x + v1*wgv.y + v2*wgv.z + v3*wgv.w;
  #pragma unroll
  for (int off = 32; off; off >>= 1) s += __shfl_xor(s, off);
  if (lane == 0){
    float g = s + bg[0];
    gate[n] = g;
    atomicMax(&gm[batch[n]], enc_f(g));
  }
}

// ---------------- graph softmax + pooled output -----------------------------
__global__ void k_gexp(float* __restrict__ gate, const int* __restrict__ batch,
                       const unsigned* __restrict__ gm, float* __restrict__ gden, int N){
  int n = blockIdx.x*blockDim.x + threadIdx.x;
  if (n >= N) return;
  int b = batch[n];
  float ex = __expf(gate[n] - dec_f(gm[b]));
  atomicAdd(&gden[b], ex);
  gate[n] = ex;
}

__global__ void k_gptr(const int* __restrict__ batch, int* __restrict__ gptr, int N, int G){
  int n = blockIdx.x*blockDim.x + threadIdx.x;
  if (n > N) return;
  if (n == N){
    int last = batch[N-1];
    for (int g = last+1; g <= G; ++g) gptr[g] = N;
    return;
  }
  int bc = batch[n];
  int bp = (n == 0) ? -1 : batch[n-1];
  for (int g = bp+1; g <= bc; ++g) gptr[g] = n;
}

__global__ void k_final(const float* __restrict__ d2, const float* __restrict__ w,
                        const float* __restrict__ gden, const int* __restrict__ gptr,
                        float* __restrict__ out){
  int g = blockIdx.x;
  int c = threadIdx.x;           // 256
  int s = gptr[g], e = gptr[g+1];
  float den = gden[g];
  if (den == 0.f) den = 1.f;
  float acc = 0.f;
  for (int n = s; n < e; ++n)
    acc += d2[(size_t)n*256 + c] * w[n];
  out[(size_t)g*256 + c] = acc / den;
}

// ============================================================================
extern "C" void kernel_launch(void* const* d_in, const int* in_sizes, int n_in,
                              void* d_out, int out_size, void* d_ws, size_t ws_size,
                              hipStream_t stream){
  const float* x         = (const float*)d_in[0];
  const int*   edge_idx  = (const int*)  d_in[1];
  const float* edge_attr = (const float*)d_in[2];
  const int*   batch     = (const int*)  d_in[3];
  const float* emb       = (const float*)d_in[4];
  const float* Wl1 = (const float*)d_in[5];  const float* bl1 = (const float*)d_in[6];
  const float* Wr1 = (const float*)d_in[7];  const float* br1 = (const float*)d_in[8];
  const float* We1 = (const float*)d_in[9];  const float* att1= (const float*)d_in[10];
  const float* bias1=(const float*)d_in[11]; const float* g1  = (const float*)d_in[12];
  const float* be1 = (const float*)d_in[13];
  const float* Wl2 = (const float*)d_in[14]; const float* bl2 = (const float*)d_in[15];
  const float* Wr2 = (const float*)d_in[16]; const float* br2 = (const float*)d_in[17];
  const float* We2 = (const float*)d_in[18]; const float* att2= (const float*)d_in[19];
  const float* bias2=(const float*)d_in[20]; const float* g2  = (const float*)d_in[21];
  const float* be2 = (const float*)d_in[22];
  const float* Wg  = (const float*)d_in[23]; const float* bg  = (const float*)d_in[24];
  float* out = (float*)d_out;

  const int N = in_sizes[0] / 64;        // 50000
  const int E = in_sizes[1] / 2;         // 800000
  const int EP = E + N;                  // with self-loops
  const int G = 256;
  const int* srcv = edge_idx;
  const int* dstv = edge_idx + E;

  // ---- workspace layout (element offsets, 64-elem aligned) ----
  float* ws = (float*)d_ws;
  size_t o = 0;
  auto alloc = [&](size_t elems){ size_t r = o; o += (elems + 63) & ~(size_t)63; return r; };
  size_t o_big1  = alloc((size_t)N*128);  // h (f32), later xlb2 (bf16, N*256*2B)
  size_t o_union = alloc((size_t)N*256);  // [xr1 | d1] f32, later d2 f32
  size_t o_xlb1  = alloc((size_t)N*64);   // xlb1 (bf16, N*128*2B)
  size_t o_xr2   = alloc((size_t)N*256);
  size_t o_ea    = alloc((size_t)N*16);
  size_t o_gate  = alloc((size_t)N);
  size_t o_bn1   = alloc(2*128);
  size_t o_bn2   = alloc(2*256);
  size_t o_deg   = alloc((size_t)N);
  size_t o_rp    = alloc((size_t)N+1);
  size_t o_cur   = alloc((size_t)N);
  size_t o_csr   = alloc((size_t)EP*2);   // int2 per CSR slot
  size_t o_gm    = alloc(G);
  size_t o_gden  = alloc(G);
  size_t o_gptr  = alloc(G+1);

  float* h    = ws + o_big1;
  unsigned short* xlb2 = (unsigned short*)(ws + o_big1);   // after h is dead
  float* xr1  = ws + o_union;                // first N*128
  float* d1   = ws + o_union + (size_t)N*128;
  float* d2   = ws + o_union;                // full N*256, after xr1/d1 dead
  unsigned short* xlb1 = (unsigned short*)(ws + o_xlb1);
  float* xr2  = ws + o_xr2;
  float* eam  = ws + o_ea;
  float* gate = ws + o_gate;
  float* bn1  = ws + o_bn1;
  float* bn2  = ws + o_bn2;
  int*   deg  = (int*)(ws + o_deg);
  int*   rp   = (int*)(ws + o_rp);
  int*   cur  = (int*)(ws + o_cur);
  int2*  csr2 = (int2*)(ws + o_csr);
  unsigned* gm = (unsigned*)(ws + o_gm);
  float* gden = ws + o_gden;
  int*   gptr = (int*)(ws + o_gptr);

  // ---- zero accumulators (every call: graph replays must be deterministic) ----
  hipMemsetAsync(deg,  0, (size_t)N*4, stream);
  hipMemsetAsync(cur,  0, (size_t)N*4, stream);
  hipMemsetAsync(bn1,  0, 2*128*4, stream);
  hipMemsetAsync(bn2,  0, 2*256*4, stream);
  hipMemsetAsync(gm,   0, G*4, stream);          // 0 == encoded minimum
  hipMemsetAsync(gden, 0, G*4, stream);

  auto nblk = [](long long n, int b){ return (int)((n + b - 1) / b); };

  // ---- graph prep ----
  k_embed<<<N, 64, 0, stream>>>(x, emb, h, N);
  k_deg<<<nblk(E,256), 256, 0, stream>>>(dstv, deg, E);
  k_scan<<<1, 256, 0, stream>>>(deg, rp, N);
  k_csrfill<<<nblk(EP,256), 256, 0, stream>>>(srcv, dstv, rp, cur, csr2, E, N);
  k_eamean<<<nblk(N,4), 256, 0, stream>>>(rp, csr2, edge_attr, eam, E, N);

  const int FGRID = 1024;   // persistent waves: 4096 waves, ~12 nodes each

  // ---- layer 1 (C=128) ----
  {
    dim3 grid(nblk(N,GBM), 2*128/GBN);   // y: 2 xl tiles + 2 xr tiles
    k_gemm_dual<<<grid, 256, 0, stream>>>(h, Wl1, bl1, Wr1, br1, xlb1, xr1, N, 128, 128);
  }
  k_gat_fused<128,8><<<FGRID, 256, 0, stream>>>(rp, csr2, edge_attr, eam,
      xlb1, xr1, We1, att1, bias1, d1, E, N);
  k_bnstats<<<512, 128, 0, stream>>>(d1, bn1, N, 128);
  k_bnapply<<<nblk((long long)N*128,256), 256, 0, stream>>>(d1, bn1, g1, be1, N, 128);

  // ---- layer 2 (C=256) ----
  {
    dim3 grid(nblk(N,GBM), 2*256/GBN);   // y: 4 xl tiles + 4 xr tiles
    k_gemm_dual<<<grid, 256, 0, stream>>>(d1, Wl2, bl2, Wr2, br2, xlb2, xr2, N, 128, 256);
  }
  k_gat_fused<256,8><<<FGRID, 256, 0, stream>>>(rp, csr2, edge_attr, eam,
      xlb2, xr2, We2, att2, bias2, d2, E, N);
  k_bnstats<<<512, 256, 0, stream>>>(d2, bn2, N, 256);
  k_bnapply_gate<<<nblk(N,4), 256, 0, stream>>>(d2, bn2, g2, be2, Wg, bg, batch,
      gate, gm, N);

  // ---- attentional aggregation ----
  k_gexp<<<nblk(N,256), 256, 0, stream>>>(gate, batch, gm, gden, N);
  k_gptr<<<nblk((long long)N+1,256), 256, 0, stream>>>(batch, gptr, N, G);
  k_final<<<G, 256, 0, stream>>>(d2, gate, gden, gptr, out);
}

// Round 8
// 1447.537 us; speedup vs baseline: 1.3300x; 1.0081x over previous
//
#include <hip/hip_runtime.h>
#include <cstddef>
#include <cstdint>

#define LEAKY_ATT 0.2f
#define LEAKY_ACT 0.01f
#define BN_EPS 1e-5f

static __device__ __forceinline__ unsigned enc_f(float f){
  unsigned u = __float_as_uint(f);
  return (u & 0x80000000u) ? ~u : (u | 0x80000000u);
}
static __device__ __forceinline__ float dec_f(unsigned k){
  return (k & 0x80000000u) ? __uint_as_float(k & 0x7fffffffu) : __uint_as_float(~k);
}
// round-to-nearest-even f32 -> bf16
static __device__ __forceinline__ unsigned short f2bf(float f){
  unsigned u = __float_as_uint(f);
  unsigned r = u + 0x7fffu + ((u >> 16) & 1u);
  return (unsigned short)(r >> 16);
}
static __device__ __forceinline__ float bf_lo(unsigned u){ return __uint_as_float(u << 16); }
static __device__ __forceinline__ float bf_hi(unsigned u){ return __uint_as_float(u & 0xffff0000u); }

// ---------------- argmax + embedding lookup: h[n] = emb[argmax(x[n])] --------
__global__ void k_embed(const float* __restrict__ x, const float* __restrict__ emb,
                        float* __restrict__ h, int N){
  int n = blockIdx.x; if (n >= N) return;
  int t = threadIdx.x;            // 64 threads = 1 wave
  float v = x[(size_t)n*64 + t];
  int idx = t;
  #pragma unroll
  for (int off = 32; off; off >>= 1){
    float ov = __shfl_down(v, off);
    int   oi = __shfl_down(idx, off);
    if (ov > v || (ov == v && oi < idx)) { v = ov; idx = oi; }  // first max wins
  }
  idx = __shfl(idx, 0);
  h[(size_t)n*128 + t]      = emb[(size_t)idx*128 + t];
  h[(size_t)n*128 + 64 + t] = emb[(size_t)idx*128 + 64 + t];
}

// ---------------- degree per dst --------------------------------------------
__global__ void k_deg(const int* __restrict__ dst, int* __restrict__ deg, int E){
  int e = blockIdx.x*blockDim.x + threadIdx.x;
  if (e >= E) return;
  atomicAdd(&deg[dst[e]], 1);
}

// ---------------- hierarchical exclusive scan of (deg[i]+1) -----------------
// scan1: per-1024-element block partial scan; scan2: scan of block sums
// (single wave, in-place); scan3: add block offsets + write rowptr[N].
__global__ __launch_bounds__(256) void k_scan1(const int* __restrict__ deg,
                        int* __restrict__ rowptr, int* __restrict__ bsum, int N){
  __shared__ int sd[256];
  int tid = threadIdx.x;
  int base = blockIdx.x*1024 + tid*4;
  int v0=0,v1=0,v2=0,v3=0;
  if (base+0 < N) v0 = deg[base+0]+1;
  if (base+1 < N) v1 = deg[base+1]+1;
  if (base+2 < N) v2 = deg[base+2]+1;
  if (base+3 < N) v3 = deg[base+3]+1;
  int t = v0+v1+v2+v3;
  sd[tid] = t;
  __syncthreads();
  for (int off = 1; off < 256; off <<= 1){
    int x = (tid >= off) ? sd[tid-off] : 0;
    __syncthreads();
    sd[tid] += x;
    __syncthreads();
  }
  int excl = sd[tid] - t;
  if (tid == 255) bsum[blockIdx.x] = sd[255];
  if (base+0 < N) rowptr[base+0] = excl;
  if (base+1 < N) rowptr[base+1] = excl + v0;
  if (base+2 < N) rowptr[base+2] = excl + v0 + v1;
  if (base+3 < N) rowptr[base+3] = excl + v0 + v1 + v2;
}
__global__ void k_scan2(int* __restrict__ bsum, int nb){
  int lane = threadIdx.x & 63;
  int carry = 0;
  for (int base = 0; base < nb; base += 64){
    int idx = base + lane;
    int v = (idx < nb) ? bsum[idx] : 0;
    int orig = v;
    #pragma unroll
    for (int off = 1; off < 64; off <<= 1){
      int x = __shfl_up(v, off);
      if (lane >= off) v += x;
    }
    if (idx < nb) bsum[idx] = carry + v - orig;   // exclusive
    carry += __shfl(v, 63);
  }
}
__global__ void k_scan3(int* __restrict__ rowptr, const int* __restrict__ bsum,
                        int N, int EP){
  int i = blockIdx.x*blockDim.x + threadIdx.x;
  if (i < N) rowptr[i] += bsum[i >> 10];
  if (i == N) rowptr[N] = EP;
}

// ---------------- CSR fill: store {src, edge_id} per slot -------------------
__global__ void k_csrfill(const int* __restrict__ src, const int* __restrict__ dst,
                          const int* __restrict__ rowptr,
                          int* __restrict__ cur, int2* __restrict__ csr2, int E, int N){
  int i = blockIdx.x*blockDim.x + threadIdx.x;
  if (i >= E + N) return;
  int d, s;
  if (i < E){ d = dst[i]; s = src[i]; }
  else      { d = i - E;  s = i - E;  }
  int pos = atomicAdd(&cur[d], 1);
  csr2[rowptr[d] + pos] = make_int2(s, i);
}

// ---------------- per-dst mean of edge_attr (CSR-based, no atomics) ---------
__global__ void k_eamean(const int* __restrict__ rowptr, const int2* __restrict__ csr2,
                         const float* __restrict__ ea, float* __restrict__ eam,
                         int E, int N){
  int wid = threadIdx.x >> 6, lane = threadIdx.x & 63;
  int n = blockIdx.x*4 + wid;
  if (n >= N) return;
  int start = rowptr[n], end = rowptr[n+1];
  int j = lane >> 4, k = lane & 15;   // 4 edges x 16 features per pass
  float s = 0.f;
  for (int i = start + j; i < end; i += 4){
    int e = csr2[i].y;
    if (e < E) s += ea[(size_t)e*16 + k];
  }
  s += __shfl_xor(s, 16);
  s += __shfl_xor(s, 32);
  if (lane < 16){
    int deg = end - start - 1;       // real in-degree (one self-loop per node)
    eam[(size_t)n*16 + k] = s / (float)max(deg, 1);
  }
}

// ---------------- dual GEMM: [xl|xr] = A[N,K] @ [Wl|Wr] + [bl|br] -----------
// blockIdx.y < C/64 -> xl half, written packed bf16; else xr half, f32.
// APPLY_BN: A is pre-BN d1; apply per-K-channel affine + leaky on stage
// (fuses layer-1 bnapply into this GEMM, saving a full d1 pass).
#define GBM 64
#define GBN 64
#define GBK 32
template<bool APPLY_BN>
__global__ __launch_bounds__(256) void k_gemm_dual(const float* __restrict__ A,
                       const float* __restrict__ Wl, const float* __restrict__ bl,
                       const float* __restrict__ Wr, const float* __restrict__ br,
                       unsigned short* __restrict__ xlb, float* __restrict__ xr,
                       const float* __restrict__ bnsc, const float* __restrict__ bnsh,
                       int N, int K, int C){
  __shared__ float As[GBM*33];
  __shared__ float Ws[GBK*GBN];
  int tid = threadIdx.x;
  int tx = tid & 15, ty = tid >> 4;
  int m0 = blockIdx.x*GBM;
  int n0g = blockIdx.y*GBN;
  bool isL = (n0g < C);
  int n0 = isL ? n0g : n0g - C;
  const float* W    = isL ? Wl : Wr;
  const float* bias = isL ? bl : br;
  float acc[4][4] = {};
  for (int k0 = 0; k0 < K; k0 += GBK){
    for (int i = tid; i < (GBM*GBK)/4; i += 256){
      int flat = i*4; int r = flat >> 5; int c = flat & 31;
      float4 v = make_float4(0.f,0.f,0.f,0.f);
      if (m0 + r < N){
        v = *reinterpret_cast<const float4*>(&A[(size_t)(m0+r)*K + k0 + c]);
        if constexpr (APPLY_BN){
          float4 sc4 = *reinterpret_cast<const float4*>(&bnsc[k0 + c]);
          float4 sh4 = *reinterpret_cast<const float4*>(&bnsh[k0 + c]);
          v.x = v.x*sc4.x + sh4.x;  v.x = (v.x >= 0.f) ? v.x : LEAKY_ACT*v.x;
          v.y = v.y*sc4.y + sh4.y;  v.y = (v.y >= 0.f) ? v.y : LEAKY_ACT*v.y;
          v.z = v.z*sc4.z + sh4.z;  v.z = (v.z >= 0.f) ? v.z : LEAKY_ACT*v.z;
          v.w = v.w*sc4.w + sh4.w;  v.w = (v.w >= 0.f) ? v.w : LEAKY_ACT*v.w;
        }
      }
      As[r*33 + c]   = v.x; As[r*33 + c+1] = v.y;
      As[r*33 + c+2] = v.z; As[r*33 + c+3] = v.w;
    }
    for (int i = tid; i < (GBK*GBN)/4; i += 256){
      int flat = i*4; int r = flat >> 6; int c = flat & 63;
      *reinterpret_cast<float4*>(&Ws[r*GBN + c]) =
        *reinterpret_cast<const float4*>(&W[(size_t)(k0+r)*C + n0 + c]);
    }
    __syncthreads();
    #pragma unroll
    for (int kk = 0; kk < GBK; ++kk){
      float a[4];
      #pragma unroll
      for (int i = 0; i < 4; ++i) a[i] = As[(ty*4+i)*33 + kk];
      float4 wv = *reinterpret_cast<const float4*>(&Ws[kk*GBN + tx*4]);
      float w[4] = {wv.x, wv.y, wv.z, wv.w};
      #pragma unroll
      for (int i = 0; i < 4; ++i)
        #pragma unroll
        for (int j = 0; j < 4; ++j) acc[i][j] += a[i]*w[j];
    }
    __syncthreads();
  }
  int cb = n0 + tx*4;
  float b0 = bias[cb], b1 = bias[cb+1], b2 = bias[cb+2], b3 = bias[cb+3];
  #pragma unroll
  for (int i = 0; i < 4; ++i){
    int r = m0 + ty*4 + i;
    if (r >= N) continue;
    float v0 = acc[i][0]+b0, v1 = acc[i][1]+b1, v2 = acc[i][2]+b2, v3 = acc[i][3]+b3;
    if (isL){
      unsigned p0 = (unsigned)f2bf(v0) | ((unsigned)f2bf(v1) << 16);
      unsigned p1 = (unsigned)f2bf(v2) | ((unsigned)f2bf(v3) << 16);
      *reinterpret_cast<uint2*>(&xlb[(size_t)r*C + cb]) = make_uint2(p0, p1);
    } else {
      *reinterpret_cast<float4*>(&xr[(size_t)r*C + cb]) = make_float4(v0, v1, v2, v3);
    }
  }
}

// ---------------- fused GATv2: logits + softmax + aggregation ---------------
// 1 wave per block (64 thr), persistent grid-stride over nodes. Edge batches
// are double-buffered: stage(batch i+1) — csr2 scalar loads + bf16 row
// gathers — issues BEFORE compute(batch i), so gather latency hides under the
// ~100 VALU ops of the previous batch. No max-subtraction (logits O(1) by
// construction -> exp can't overflow; softmax shift-invariant).
template<int C, int UNR>
__global__ __launch_bounds__(64) void k_gat_fused(
    const int* __restrict__ rowptr, const int2* __restrict__ csr2,
    const float* __restrict__ edge_attr, const float* __restrict__ eam,
    const unsigned short* __restrict__ xlb, const float* __restrict__ xr,
    const float* __restrict__ We, const float* __restrict__ att,
    const float* __restrict__ bias, float* __restrict__ out, int E, int N)
{
  constexpr int CPL = C/64;          // 2 or 4 columns per lane
  constexpr int PK  = CPL/2;         // packed uints per edge per lane
  const int lane = threadIdx.x;
  const int c0 = lane*CPL;

  // once per wave: We column-slice + att + bias (loop-invariant across nodes)
  float wreg[16][CPL];
  #pragma unroll
  for (int k = 0; k < 16; ++k)
    #pragma unroll
    for (int q = 0; q < CPL; ++q)
      wreg[k][q] = We[k*C + c0 + q];
  float attv[CPL], biasv[CPL];
  #pragma unroll
  for (int q = 0; q < CPL; ++q){ attv[q] = att[c0 + q]; biasv[q] = bias[c0 + q]; }

  for (int n = blockIdx.x; n < N; n += gridDim.x){
    float xrv[CPL];
    #pragma unroll
    for (int q = 0; q < CPL; ++q) xrv[q] = xr[(size_t)n*C + c0 + q];
    int start = __builtin_amdgcn_readfirstlane(rowptr[n]);
    int end   = __builtin_amdgcn_readfirstlane(rowptr[n+1]);

    float denom = 0.f;
    float acc[CPL] = {};

    const float* eA[UNR]; unsigned xA[UNR][PK];
    const float* eB[UNR]; unsigned xB[UNR][PK];

    auto stage = [&](int base, const float** eaps, unsigned (*xp)[PK]){
      #pragma unroll
      for (int u = 0; u < UNR; ++u){
        if (base + u < end){
          int2 v = csr2[base + u];
          int s = __builtin_amdgcn_readfirstlane(v.x);
          int e = __builtin_amdgcn_readfirstlane(v.y);
          eaps[u] = (e < E) ? edge_attr + (size_t)e*16
                            : eam + (size_t)(e - E)*16;
          const unsigned short* prow = xlb + (size_t)s*C + c0;
          if constexpr (PK == 2){
            uint2 w = *reinterpret_cast<const uint2*>(prow);
            xp[u][0] = w.x; xp[u][1] = w.y;
          } else {
            xp[u][0] = *reinterpret_cast<const unsigned*>(prow);
          }
        } else {
          eaps[u] = eam;
          #pragma unroll
          for (int p = 0; p < PK; ++p) xp[u][p] = 0;
        }
      }
    };
    auto compute = [&](int base, const float* const* eaps, const unsigned (*xp)[PK]){
      float pe[UNR];
      #pragma unroll
      for (int u = 0; u < UNR; ++u){
        if (base + u < end){
          float w[CPL] = {};
          #pragma unroll
          for (int k = 0; k < 16; ++k){
            float a = eaps[u][k];            // wave-uniform scalar load
            #pragma unroll
            for (int q = 0; q < CPL; ++q) w[q] += a * wreg[k][q];
          }
          float p = 0.f;
          #pragma unroll
          for (int p2 = 0; p2 < PK; ++p2){
            float x0 = bf_lo(xp[u][p2]), x1 = bf_hi(xp[u][p2]);
            float v0 = x0 + xrv[2*p2]   + w[2*p2];
            float v1 = x1 + xrv[2*p2+1] + w[2*p2+1];
            v0 = (v0 >= 0.f) ? v0 : LEAKY_ATT*v0;
            v1 = (v1 >= 0.f) ? v1 : LEAKY_ATT*v1;
            p += attv[2*p2]*v0 + attv[2*p2+1]*v1;
          }
          #pragma unroll
          for (int off = 32; off; off >>= 1) p += __shfl_xor(p, off);
          pe[u] = __expf(p);
        } else pe[u] = 0.f;
      }
      #pragma unroll
      for (int u = 0; u < UNR; ++u) denom += pe[u];
      #pragma unroll
      for (int u = 0; u < UNR; ++u)
        #pragma unroll
        for (int p2 = 0; p2 < PK; ++p2){
          acc[2*p2]   += pe[u]*bf_lo(xp[u][p2]);
          acc[2*p2+1] += pe[u]*bf_hi(xp[u][p2]);
        }
    };

    int i = start;
    stage(i, eA, xA);
    for (;;){
      int j = i + UNR;
      if (j < end) stage(j, eB, xB);       // prefetch next batch
      compute(i, eA, xA);
      i = j;
      if (i >= end) break;
      j = i + UNR;
      if (j < end) stage(j, eA, xA);
      compute(i, eB, xB);
      i = j;
      if (i >= end) break;
    }

    float inv = 1.0f / denom;     // self-loop guarantees denom > 0
    if constexpr (CPL == 4){
      float4 o = make_float4(acc[0]*inv + biasv[0], acc[1]*inv + biasv[1],
                             acc[2]*inv + biasv[2], acc[3]*inv + biasv[3]);
      *reinterpret_cast<float4*>(&out[(size_t)n*C + c0]) = o;
    } else {
      float2 o = make_float2(acc[0]*inv + biasv[0], acc[1]*inv + biasv[1]);
      *reinterpret_cast<float2*>(&out[(size_t)n*C + c0]) = o;
    }
  }
}

// ---------------- batchnorm -------------------------------------------------
__global__ void k_bnstats(const float* __restrict__ x, float* __restrict__ sums,
                          int N, int C){
  int c = threadIdx.x;           // blockDim = C
  float s = 0.f, s2 = 0.f;
  for (int r = blockIdx.x; r < N; r += gridDim.x){
    float v = x[(size_t)r*C + c];
    s += v; s2 += v*v;
  }
  atomicAdd(&sums[c], s);
  atomicAdd(&sums[C + c], s2);
}

// sums -> per-channel affine (scale, shift) for fused BN+leaky application
__global__ void k_bnfin(const float* __restrict__ sums, const float* __restrict__ gam,
                        const float* __restrict__ bet, float* __restrict__ sc,
                        float* __restrict__ sh, int N, int C){
  int c = threadIdx.x; if (c >= C) return;
  float invN = 1.0f / (float)N;
  float mu  = sums[c] * invN;
  float var = sums[C + c] * invN - mu*mu;
  float r = rsqrtf(var + BN_EPS) * gam[c];
  sc[c] = r;
  sh[c] = bet[c] - mu*r;
}

// -------- fused BN-apply + leaky + gate dot (layer 2, C=256, wave/row) ------
__global__ __launch_bounds__(256) void k_bnapply_gate(
    float* __restrict__ d2, const float* __restrict__ sums,
    const float* __restrict__ gam, const float* __restrict__ bet,
    const float* __restrict__ Wg, const float* __restrict__ bg,
    const int* __restrict__ batch, float* __restrict__ gate,
    unsigned* __restrict__ gm, int N){
  int wid = threadIdx.x >> 6, lane = threadIdx.x & 63;
  int n = blockIdx.x*4 + wid;
  if (n >= N) return;
  int c0 = lane*4;
  float invN = 1.0f / (float)N;
  float4 sv  = *reinterpret_cast<const float4*>(&sums[c0]);
  float4 s2v = *reinterpret_cast<const float4*>(&sums[256 + c0]);
  float4 gv  = *reinterpret_cast<const float4*>(&gam[c0]);
  float4 bv  = *reinterpret_cast<const float4*>(&bet[c0]);
  float4 wgv = *reinterpret_cast<const float4*>(&Wg[c0]);
  float4 x   = *reinterpret_cast<const float4*>(&d2[(size_t)n*256 + c0]);
  float mu0 = sv.x*invN, mu1 = sv.y*invN, mu2 = sv.z*invN, mu3 = sv.w*invN;
  float r0 = rsqrtf(s2v.x*invN - mu0*mu0 + BN_EPS);
  float r1 = rsqrtf(s2v.y*invN - mu1*mu1 + BN_EPS);
  float r2 = rsqrtf(s2v.z*invN - mu2*mu2 + BN_EPS);
  float r3 = rsqrtf(s2v.w*invN - mu3*mu3 + BN_EPS);
  float v0 = (x.x - mu0)*r0*gv.x + bv.x;  v0 = (v0 >= 0.f) ? v0 : LEAKY_ACT*v0;
  float v1 = (x.y - mu1)*r1*gv.y + bv.y;  v1 = (v1 >= 0.f) ? v1 : LEAKY_ACT*v1;
  float v2 = (x.z - mu2)*r2*gv.z + bv.z;  v2 = (v2 >= 0.f) ? v2 : LEAKY_ACT*v2;
  float v3 = (x.w - mu3)*r3*gv.w + bv.w;  v3 = (v3 >= 0.f) ? v3 : LEAKY_ACT*v3;
  *reinterpret_cast<float4*>(&d2[(size_t)n*256 + c0]) = make_float4(v0,v1,v2,v3);
  float s = v0*wgv.x + v1*wgv.y + v2*wgv.z + v3*wgv.w;
  #pragma unroll
  for (int off = 32; off; off >>= 1) s += __shfl_xor(s, off);
  if (lane == 0){
    float g = s + bg[0];
    gate[n] = g;
    atomicMax(&gm[batch[n]], enc_f(g));
  }
}

// ---------------- graph softmax + pooled output -----------------------------
__global__ void k_gexp(float* __restrict__ gate, const int* __restrict__ batch,
                       const unsigned* __restrict__ gm, float* __restrict__ gden, int N){
  int n = blockIdx.x*blockDim.x + threadIdx.x;
  if (n >= N) return;
  int b = batch[n];
  float ex = __expf(gate[n] - dec_f(gm[b]));
  atomicAdd(&gden[b], ex);
  gate[n] = ex;
}

__global__ void k_gptr(const int* __restrict__ batch, int* __restrict__ gptr, int N, int G){
  int n = blockIdx.x*blockDim.x + threadIdx.x;
  if (n > N) return;
  if (n == N){
    int last = batch[N-1];
    for (int g = last+1; g <= G; ++g) gptr[g] = N;
    return;
  }
  int bc = batch[n];
  int bp = (n == 0) ? -1 : batch[n-1];
  for (int g = bp+1; g <= bc; ++g) gptr[g] = n;
}

__global__ void k_final(const float* __restrict__ d2, const float* __restrict__ w,
                        const float* __restrict__ gden, const int* __restrict__ gptr,
                        float* __restrict__ out){
  int g = blockIdx.x;
  int c = threadIdx.x;           // 256
  int s = gptr[g], e = gptr[g+1];
  float den = gden[g];
  if (den == 0.f) den = 1.f;
  float acc = 0.f;
  for (int n = s; n < e; ++n)
    acc += d2[(size_t)n*256 + c] * w[n];
  out[(size_t)g*256 + c] = acc / den;
}

// ============================================================================
extern "C" void kernel_launch(void* const* d_in, const int* in_sizes, int n_in,
                              void* d_out, int out_size, void* d_ws, size_t ws_size,
                              hipStream_t stream){
  const float* x         = (const float*)d_in[0];
  const int*   edge_idx  = (const int*)  d_in[1];
  const float* edge_attr = (const float*)d_in[2];
  const int*   batch     = (const int*)  d_in[3];
  const float* emb       = (const float*)d_in[4];
  const float* Wl1 = (const float*)d_in[5];  const float* bl1 = (const float*)d_in[6];
  const float* Wr1 = (const float*)d_in[7];  const float* br1 = (const float*)d_in[8];
  const float* We1 = (const float*)d_in[9];  const float* att1= (const float*)d_in[10];
  const float* bias1=(const float*)d_in[11]; const float* g1  = (const float*)d_in[12];
  const float* be1 = (const float*)d_in[13];
  const float* Wl2 = (const float*)d_in[14]; const float* bl2 = (const float*)d_in[15];
  const float* Wr2 = (const float*)d_in[16]; const float* br2 = (const float*)d_in[17];
  const float* We2 = (const float*)d_in[18]; const float* att2= (const float*)d_in[19];
  const float* bias2=(const float*)d_in[20]; const float* g2  = (const float*)d_in[21];
  const float* be2 = (const float*)d_in[22];
  const float* Wg  = (const float*)d_in[23]; const float* bg  = (const float*)d_in[24];
  float* out = (float*)d_out;

  const int N = in_sizes[0] / 64;        // 50000
  const int E = in_sizes[1] / 2;         // 800000
  const int EP = E + N;                  // with self-loops
  const int G = 256;
  const int* srcv = edge_idx;
  const int* dstv = edge_idx + E;

  // ---- workspace layout (element offsets, 64-elem aligned) ----
  float* ws = (float*)d_ws;
  size_t o = 0;
  auto alloc = [&](size_t elems){ size_t r = o; o += (elems + 63) & ~(size_t)63; return r; };
  size_t o_big1  = alloc((size_t)N*128);  // h (f32), later xlb2 (bf16, N*256*2B)
  size_t o_union = alloc((size_t)N*256);  // [xr1 | d1] f32, later d2 f32
  size_t o_xlb1  = alloc((size_t)N*64);   // xlb1 (bf16, N*128*2B)
  size_t o_xr2   = alloc((size_t)N*256);
  size_t o_ea    = alloc((size_t)N*16);
  size_t o_gate  = alloc((size_t)N);
  size_t o_bn1   = alloc(2*128);          // bn1+bn2 contiguous -> one memset
  size_t o_bn2   = alloc(2*256);
  size_t o_sc1   = alloc(128);
  size_t o_sh1   = alloc(128);
  size_t o_deg   = alloc((size_t)N);      // deg+cur contiguous -> one memset
  size_t o_cur   = alloc((size_t)N);
  size_t o_rp    = alloc((size_t)N+1);
  size_t o_bsum  = alloc(64);
  size_t o_csr   = alloc((size_t)EP*2);   // int2 per CSR slot
  size_t o_gm    = alloc(G);              // gm+gden contiguous -> one memset
  size_t o_gden  = alloc(G);
  size_t o_gptr  = alloc(G+1);

  float* h    = ws + o_big1;
  unsigned short* xlb2 = (unsigned short*)(ws + o_big1);   // after h is dead
  float* xr1  = ws + o_union;                // first N*128
  float* d1   = ws + o_union + (size_t)N*128;
  float* d2   = ws + o_union;                // full N*256, after xr1/d1 dead
  unsigned short* xlb1 = (unsigned short*)(ws + o_xlb1);
  float* xr2  = ws + o_xr2;
  float* eam  = ws + o_ea;
  float* gate = ws + o_gate;
  float* bn1  = ws + o_bn1;
  float* bn2  = ws + o_bn2;
  float* sc1  = ws + o_sc1;
  float* sh1  = ws + o_sh1;
  int*   deg  = (int*)(ws + o_deg);
  int*   cur  = (int*)(ws + o_cur);
  int*   rp   = (int*)(ws + o_rp);
  int*   bsum = (int*)(ws + o_bsum);
  int2*  csr2 = (int2*)(ws + o_csr);
  unsigned* gm = (unsigned*)(ws + o_gm);
  float* gden = ws + o_gden;
  int*   gptr = (int*)(ws + o_gptr);

  // ---- zero accumulators (every call: graph replays must be deterministic) ----
  hipMemsetAsync(deg, 0, (o_cur - o_deg + (size_t)N)*4, stream);       // deg+cur
  hipMemsetAsync(bn1, 0, (o_bn2 - o_bn1 + 2*256)*4, stream);           // bn1+bn2
  hipMemsetAsync(gm,  0, (o_gden - o_gm + (size_t)G)*4, stream);       // gm+gden

  auto nblk = [](long long n, int b){ return (int)((n + b - 1) / b); };

  // ---- graph prep ----
  k_embed<<<N, 64, 0, stream>>>(x, emb, h, N);
  k_deg<<<nblk(E,256), 256, 0, stream>>>(dstv, deg, E);
  int nbs = nblk(N, 1024);
  k_scan1<<<nbs, 256, 0, stream>>>(deg, rp, bsum, N);
  k_scan2<<<1, 64, 0, stream>>>(bsum, nbs);
  k_scan3<<<nblk((long long)N+1,256), 256, 0, stream>>>(rp, bsum, N, EP);
  k_csrfill<<<nblk(EP,256), 256, 0, stream>>>(srcv, dstv, rp, cur, csr2, E, N);
  k_eamean<<<nblk(N,4), 256, 0, stream>>>(rp, csr2, edge_attr, eam, E, N);

  const int FGRID = 4096;   // persistent 1-wave blocks, ~12 nodes each

  // ---- layer 1 (C=128) ----
  {
    dim3 grid(nblk(N,GBM), 2*128/GBN);   // y: 2 xl tiles + 2 xr tiles
    k_gemm_dual<false><<<grid, 256, 0, stream>>>(h, Wl1, bl1, Wr1, br1,
        xlb1, xr1, nullptr, nullptr, N, 128, 128);
  }
  k_gat_fused<128,8><<<FGRID, 64, 0, stream>>>(rp, csr2, edge_attr, eam,
      xlb1, xr1, We1, att1, bias1, d1, E, N);
  k_bnstats<<<512, 128, 0, stream>>>(d1, bn1, N, 128);
  k_bnfin<<<1, 128, 0, stream>>>(bn1, g1, be1, sc1, sh1, N, 128);

  // ---- layer 2 (C=256); BN+leaky of d1 fused into the A-staging ----
  {
    dim3 grid(nblk(N,GBM), 2*256/GBN);   // y: 4 xl tiles + 4 xr tiles
    k_gemm_dual<true><<<grid, 256, 0, stream>>>(d1, Wl2, bl2, Wr2, br2,
        xlb2, xr2, sc1, sh1, N, 128, 256);
  }
  k_gat_fused<256,6><<<FGRID, 64, 0, stream>>>(rp, csr2, edge_attr, eam,
      xlb2, xr2, We2, att2, bias2, d2, E, N);
  k_bnstats<<<512, 256, 0, stream>>>(d2, bn2, N, 256);
  k_bnapply_gate<<<nblk(N,4), 256, 0, stream>>>(d2, bn2, g2, be2, Wg, bg, batch,
      gate, gm, N);

  // ---- attentional aggregation ----
  k_gexp<<<nblk(N,256), 256, 0, stream>>>(gate, batch, gm, gden, N);
  k_gptr<<<nblk((long long)N+1,256), 256, 0, stream>>>(batch, gptr, N, G);
  k_final<<<G, 256, 0, stream>>>(d2, gate, gden, gptr, out);
}

// Round 9
// 1320.205 us; speedup vs baseline: 1.4582x; 1.0964x over previous
//
#include <hip/hip_runtime.h>
#include <cstddef>
#include <cstdint>

#define LEAKY_ATT 0.2f
#define LEAKY_ACT 0.01f
#define BN_EPS 1e-5f

typedef __attribute__((ext_vector_type(8))) short bf16x8;
typedef __attribute__((ext_vector_type(4))) float f32x4;

static __device__ __forceinline__ unsigned enc_f(float f){
  unsigned u = __float_as_uint(f);
  return (u & 0x80000000u) ? ~u : (u | 0x80000000u);
}
static __device__ __forceinline__ float dec_f(unsigned k){
  return (k & 0x80000000u) ? __uint_as_float(k & 0x7fffffffu) : __uint_as_float(~k);
}
// round-to-nearest-even f32 -> bf16
static __device__ __forceinline__ unsigned short f2bf(float f){
  unsigned u = __float_as_uint(f);
  unsigned r = u + 0x7fffu + ((u >> 16) & 1u);
  return (unsigned short)(r >> 16);
}
static __device__ __forceinline__ float bf_lo(unsigned u){ return __uint_as_float(u << 16); }
static __device__ __forceinline__ float bf_hi(unsigned u){ return __uint_as_float(u & 0xffff0000u); }
static __device__ __forceinline__ float bf2f(unsigned short u){ return __uint_as_float((unsigned)u << 16); }

// ---------------- argmax + embedding lookup: hb[n] = bf16(emb[argmax(x[n])]) -
__global__ void k_embed(const float* __restrict__ x, const float* __restrict__ emb,
                        unsigned short* __restrict__ hb, int N){
  int n = blockIdx.x; if (n >= N) return;
  int t = threadIdx.x;            // 64 threads = 1 wave
  float v = x[(size_t)n*64 + t];
  int idx = t;
  #pragma unroll
  for (int off = 32; off; off >>= 1){
    float ov = __shfl_down(v, off);
    int   oi = __shfl_down(idx, off);
    if (ov > v || (ov == v && oi < idx)) { v = ov; idx = oi; }  // first max wins
  }
  idx = __shfl(idx, 0);
  hb[(size_t)n*128 + t]      = f2bf(emb[(size_t)idx*128 + t]);
  hb[(size_t)n*128 + 64 + t] = f2bf(emb[(size_t)idx*128 + 64 + t]);
}

// ---------------- degree per dst --------------------------------------------
__global__ void k_deg(const int* __restrict__ dst, int* __restrict__ deg, int E){
  int e = blockIdx.x*blockDim.x + threadIdx.x;
  if (e >= E) return;
  atomicAdd(&deg[dst[e]], 1);
}

// ---------------- hierarchical exclusive scan of (deg[i]+1) -----------------
__global__ __launch_bounds__(256) void k_scan1(const int* __restrict__ deg,
                        int* __restrict__ rowptr, int* __restrict__ bsum, int N){
  __shared__ int sd[256];
  int tid = threadIdx.x;
  int base = blockIdx.x*1024 + tid*4;
  int v0=0,v1=0,v2=0,v3=0;
  if (base+0 < N) v0 = deg[base+0]+1;
  if (base+1 < N) v1 = deg[base+1]+1;
  if (base+2 < N) v2 = deg[base+2]+1;
  if (base+3 < N) v3 = deg[base+3]+1;
  int t = v0+v1+v2+v3;
  sd[tid] = t;
  __syncthreads();
  for (int off = 1; off < 256; off <<= 1){
    int x = (tid >= off) ? sd[tid-off] : 0;
    __syncthreads();
    sd[tid] += x;
    __syncthreads();
  }
  int excl = sd[tid] - t;
  if (tid == 255) bsum[blockIdx.x] = sd[255];
  if (base+0 < N) rowptr[base+0] = excl;
  if (base+1 < N) rowptr[base+1] = excl + v0;
  if (base+2 < N) rowptr[base+2] = excl + v0 + v1;
  if (base+3 < N) rowptr[base+3] = excl + v0 + v1 + v2;
}
__global__ void k_scan2(int* __restrict__ bsum, int nb){
  int lane = threadIdx.x & 63;
  int carry = 0;
  for (int base = 0; base < nb; base += 64){
    int idx = base + lane;
    int v = (idx < nb) ? bsum[idx] : 0;
    int orig = v;
    #pragma unroll
    for (int off = 1; off < 64; off <<= 1){
      int x = __shfl_up(v, off);
      if (lane >= off) v += x;
    }
    if (idx < nb) bsum[idx] = carry + v - orig;   // exclusive
    carry += __shfl(v, 63);
  }
}
__global__ void k_scan3(int* __restrict__ rowptr, const int* __restrict__ bsum,
                        int N, int EP){
  int i = blockIdx.x*blockDim.x + threadIdx.x;
  if (i < N) rowptr[i] += bsum[i >> 10];
  if (i == N) rowptr[N] = EP;
}

// ---------------- CSR fill: store {src, edge_id} per slot -------------------
__global__ void k_csrfill(const int* __restrict__ src, const int* __restrict__ dst,
                          const int* __restrict__ rowptr,
                          int* __restrict__ cur, int2* __restrict__ csr2, int E, int N){
  int i = blockIdx.x*blockDim.x + threadIdx.x;
  if (i >= E + N) return;
  int d, s;
  if (i < E){ d = dst[i]; s = src[i]; }
  else      { d = i - E;  s = i - E;  }
  int pos = atomicAdd(&cur[d], 1);
  csr2[rowptr[d] + pos] = make_int2(s, i);
}

// ---------------- per-dst mean of edge_attr (CSR-based, no atomics) ---------
__global__ void k_eamean(const int* __restrict__ rowptr, const int2* __restrict__ csr2,
                         const float* __restrict__ ea, float* __restrict__ eam,
                         int E, int N){
  int wid = threadIdx.x >> 6, lane = threadIdx.x & 63;
  int n = blockIdx.x*4 + wid;
  if (n >= N) return;
  int start = rowptr[n], end = rowptr[n+1];
  int j = lane >> 4, k = lane & 15;   // 4 edges x 16 features per pass
  float s = 0.f;
  for (int i = start + j; i < end; i += 4){
    int e = csr2[i].y;
    if (e < E) s += ea[(size_t)e*16 + k];
  }
  s += __shfl_xor(s, 16);
  s += __shfl_xor(s, 32);
  if (lane < 16){
    int deg = end - start - 1;       // real in-degree (one self-loop per node)
    eam[(size_t)n*16 + k] = s / (float)max(deg, 1);
  }
}

// ---------------- weight prep: Wt[n][k] = bf16(W[k][n]) ---------------------
__global__ void k_wprep(const float* __restrict__ W, unsigned short* __restrict__ Wt,
                        int K, int C){
  int i = blockIdx.x*blockDim.x + threadIdx.x;
  if (i >= K*C) return;
  int n = i / K, k = i - n*K;
  Wt[i] = f2bf(W[(size_t)k*C + n]);
}

// ---------------- MFMA GEMM: [xl|xr] = A[N,128]bf16 @ Wt^T + bias -----------
// Block: 256 thr = 4 waves; tile M=64 (16/wave) x N=128 (8 mfma tiles/wave).
// grid.y < half -> xl half (packed bf16 out); else xr half (f32 out).
// APPLY_BN: A is pre-BN bf16 d1; apply per-K-channel affine + leaky during
// LDS staging (fuses layer-1 bnapply).
// MFMA 16x16x32 bf16 layouts (m89/m91-verified): A: row=lane&15,
// k=(lane>>4)*8+j; B: col=lane&15, k=(lane>>4)*8+j; D: col=lane&15,
// row=(lane>>4)*4+reg.
template<bool APPLY_BN>
__global__ __launch_bounds__(256) void k_gemm_mfma(
    const unsigned short* __restrict__ A,
    const unsigned short* __restrict__ Wtl, const float* __restrict__ bl,
    const unsigned short* __restrict__ Wtr, const float* __restrict__ br,
    const float* __restrict__ bnsc, const float* __restrict__ bnsh,
    unsigned short* __restrict__ xlb, float* __restrict__ xr,
    int N, int C)
{
  constexpr int K = 128;
  __shared__ unsigned short As[64][40];    // +8 bf16 pad: bank-conflict-free b128
  int tid = threadIdx.x;
  int wv = tid >> 6, lane = tid & 63;
  int m0 = blockIdx.x*64;
  int half = gridDim.y >> 1;
  bool isL = ((int)blockIdx.y < half);
  int n0 = (isL ? blockIdx.y : blockIdx.y - half) * 128;
  const unsigned short* Wt = isL ? Wtl : Wtr;
  const float* bias = isL ? bl : br;

  f32x4 acc[8];
  #pragma unroll
  for (int t = 0; t < 8; ++t) acc[t] = (f32x4){0.f,0.f,0.f,0.f};

  int srow = tid >> 2;            // 0..63
  int sseg = (tid & 3) * 8;       // k-offset 0,8,16,24
  int grow = m0 + srow;
  int arow = wv*16 + (lane & 15);
  int koff = (lane >> 4) * 8;

  for (int k0 = 0; k0 < K; k0 += 32){
    __syncthreads();
    uint4 raw = make_uint4(0,0,0,0);
    if (grow < N){
      raw = *reinterpret_cast<const uint4*>(&A[(size_t)grow*K + k0 + sseg]);
      if constexpr (APPLY_BN){
        float4 sa = *reinterpret_cast<const float4*>(&bnsc[k0 + sseg]);
        float4 sb = *reinterpret_cast<const float4*>(&bnsc[k0 + sseg + 4]);
        float4 ha = *reinterpret_cast<const float4*>(&bnsh[k0 + sseg]);
        float4 hb = *reinterpret_cast<const float4*>(&bnsh[k0 + sseg + 4]);
        float f0 = bf_lo(raw.x)*sa.x + ha.x; f0 = (f0>=0.f)?f0:LEAKY_ACT*f0;
        float f1 = bf_hi(raw.x)*sa.y + ha.y; f1 = (f1>=0.f)?f1:LEAKY_ACT*f1;
        float f2 = bf_lo(raw.y)*sa.z + ha.z; f2 = (f2>=0.f)?f2:LEAKY_ACT*f2;
        float f3 = bf_hi(raw.y)*sa.w + ha.w; f3 = (f3>=0.f)?f3:LEAKY_ACT*f3;
        float f4 = bf_lo(raw.z)*sb.x + hb.x; f4 = (f4>=0.f)?f4:LEAKY_ACT*f4;
        float f5 = bf_hi(raw.z)*sb.y + hb.y; f5 = (f5>=0.f)?f5:LEAKY_ACT*f5;
        float f6 = bf_lo(raw.w)*sb.z + hb.z; f6 = (f6>=0.f)?f6:LEAKY_ACT*f6;
        float f7 = bf_hi(raw.w)*sb.w + hb.w; f7 = (f7>=0.f)?f7:LEAKY_ACT*f7;
        raw.x = (unsigned)f2bf(f0) | ((unsigned)f2bf(f1) << 16);
        raw.y = (unsigned)f2bf(f2) | ((unsigned)f2bf(f3) << 16);
        raw.z = (unsigned)f2bf(f4) | ((unsigned)f2bf(f5) << 16);
        raw.w = (unsigned)f2bf(f6) | ((unsigned)f2bf(f7) << 16);
      }
    }
    *reinterpret_cast<uint4*>(&As[srow][sseg]) = raw;
    __syncthreads();
    bf16x8 a = *reinterpret_cast<const bf16x8*>(&As[arow][koff]);
    #pragma unroll
    for (int nt = 0; nt < 8; ++nt){
      int ncol = n0 + nt*16 + (lane & 15);
      bf16x8 b = *reinterpret_cast<const bf16x8*>(&Wt[(size_t)ncol*K + k0 + koff]);
      acc[nt] = __builtin_amdgcn_mfma_f32_16x16x32_bf16(a, b, acc[nt], 0, 0, 0);
    }
  }
  int rbase = m0 + wv*16 + (lane >> 4)*4;
  #pragma unroll
  for (int nt = 0; nt < 8; ++nt){
    int col = n0 + nt*16 + (lane & 15);
    float bv = bias[col];
    #pragma unroll
    for (int r = 0; r < 4; ++r){
      int row = rbase + r;
      if (row < N){
        float v = acc[nt][r] + bv;
        if (isL) xlb[(size_t)row*C + col] = f2bf(v);
        else     xr [(size_t)row*C + col] = v;
      }
    }
  }
}

// ---------------- fused GATv2: logits + softmax + aggregation ---------------
// 1 wave/block persistent. Double-buffered edge batches; stage prefetches
// csr2, the bf16 xl row, AND the 16 edge-attr floats (per-lane vector load,
// ea[lane&15]) so compute touches NO memory: ea broadcast via literal-lane
// __shfl (v_readlane -> scalar FMA operand). No max-subtraction (logits O(1)
// by construction, softmax shift-invariant -> edges independent).
template<int C, int UNR, bool OUTBF>
__global__ __launch_bounds__(64) void k_gat_fused(
    const int* __restrict__ rowptr, const int2* __restrict__ csr2,
    const float* __restrict__ edge_attr, const float* __restrict__ eam,
    const unsigned short* __restrict__ xlb, const float* __restrict__ xr,
    const float* __restrict__ We, const float* __restrict__ att,
    const float* __restrict__ bias, float* __restrict__ out_f,
    unsigned short* __restrict__ out_b, int E, int N)
{
  constexpr int CPL = C/64;          // 2 or 4 columns per lane
  constexpr int PK  = CPL/2;         // packed uints per edge per lane
  const int lane = threadIdx.x;
  const int c0 = lane*CPL;

  float wreg[16][CPL];
  #pragma unroll
  for (int k = 0; k < 16; ++k)
    #pragma unroll
    for (int q = 0; q < CPL; ++q)
      wreg[k][q] = We[k*C + c0 + q];
  float attv[CPL], biasv[CPL];
  #pragma unroll
  for (int q = 0; q < CPL; ++q){ attv[q] = att[c0 + q]; biasv[q] = bias[c0 + q]; }

  for (int n = blockIdx.x; n < N; n += gridDim.x){
    float xrv[CPL];
    #pragma unroll
    for (int q = 0; q < CPL; ++q) xrv[q] = xr[(size_t)n*C + c0 + q];
    int start = __builtin_amdgcn_readfirstlane(rowptr[n]);
    int end   = __builtin_amdgcn_readfirstlane(rowptr[n+1]);

    float denom = 0.f;
    float acc[CPL] = {};

    unsigned xA[UNR][PK]; float eaA[UNR];
    unsigned xB[UNR][PK]; float eaB[UNR];

    auto stage = [&](int base, unsigned (&xp)[UNR][PK], float (&eal)[UNR]){
      #pragma unroll
      for (int u = 0; u < UNR; ++u){
        if (base + u < end){
          int2 v = csr2[base + u];
          int s = __builtin_amdgcn_readfirstlane(v.x);
          int e = __builtin_amdgcn_readfirstlane(v.y);
          const float* eap = (e < E) ? edge_attr + (size_t)e*16
                                     : eam + (size_t)(e - E)*16;
          eal[u] = eap[lane & 15];               // prefetched into VGPR
          const unsigned short* prow = xlb + (size_t)s*C + c0;
          if constexpr (PK == 2){
            uint2 w = *reinterpret_cast<const uint2*>(prow);
            xp[u][0] = w.x; xp[u][1] = w.y;
          } else {
            xp[u][0] = *reinterpret_cast<const unsigned*>(prow);
          }
        } else {
          eal[u] = 0.f;
          #pragma unroll
          for (int p = 0; p < PK; ++p) xp[u][p] = 0;
        }
      }
    };
    auto compute = [&](int base, unsigned (&xp)[UNR][PK], float (&eal)[UNR]){
      float pe[UNR];
      #pragma unroll
      for (int u = 0; u < UNR; ++u){
        if (base + u < end){
          float w[CPL] = {};
          #pragma unroll
          for (int k = 0; k < 16; ++k){
            float aa = __shfl(eal[u], k);        // v_readlane (register op)
            #pragma unroll
            for (int q = 0; q < CPL; ++q) w[q] += aa * wreg[k][q];
          }
          float p = 0.f;
          #pragma unroll
          for (int p2 = 0; p2 < PK; ++p2){
            float x0 = bf_lo(xp[u][p2]), x1 = bf_hi(xp[u][p2]);
            float v0 = x0 + xrv[2*p2]   + w[2*p2];
            float v1 = x1 + xrv[2*p2+1] + w[2*p2+1];
            v0 = (v0 >= 0.f) ? v0 : LEAKY_ATT*v0;
            v1 = (v1 >= 0.f) ? v1 : LEAKY_ATT*v1;
            p += attv[2*p2]*v0 + attv[2*p2+1]*v1;
          }
          #pragma unroll
          for (int off = 32; off; off >>= 1) p += __shfl_xor(p, off);
          pe[u] = __expf(p);
        } else pe[u] = 0.f;
      }
      #pragma unroll
      for (int u = 0; u < UNR; ++u) denom += pe[u];
      #pragma unroll
      for (int u = 0; u < UNR; ++u)
        #pragma unroll
        for (int p2 = 0; p2 < PK; ++p2){
          acc[2*p2]   += pe[u]*bf_lo(xp[u][p2]);
          acc[2*p2+1] += pe[u]*bf_hi(xp[u][p2]);
        }
    };

    int i = start;
    stage(i, xA, eaA);
    for (;;){
      int j = i + UNR;
      if (j < end) stage(j, xB, eaB);
      compute(i, xA, eaA);
      i = j;
      if (i >= end) break;
      j = i + UNR;
      if (j < end) stage(j, xA, eaA);
      compute(i, xB, eaB);
      i = j;
      if (i >= end) break;
    }

    float inv = 1.0f / denom;     // self-loop guarantees denom > 0
    if constexpr (OUTBF){
      #pragma unroll
      for (int p2 = 0; p2 < PK; ++p2){
        unsigned po = (unsigned)f2bf(acc[2*p2]*inv + biasv[2*p2])
                    | ((unsigned)f2bf(acc[2*p2+1]*inv + biasv[2*p2+1]) << 16);
        *reinterpret_cast<unsigned*>(&out_b[(size_t)n*C + c0 + 2*p2]) = po;
      }
    } else {
      if constexpr (CPL == 4){
        float4 o = make_float4(acc[0]*inv + biasv[0], acc[1]*inv + biasv[1],
                               acc[2]*inv + biasv[2], acc[3]*inv + biasv[3]);
        *reinterpret_cast<float4*>(&out_f[(size_t)n*C + c0]) = o;
      } else {
        float2 o = make_float2(acc[0]*inv + biasv[0], acc[1]*inv + biasv[1]);
        *reinterpret_cast<float2*>(&out_f[(size_t)n*C + c0]) = o;
      }
    }
  }
}

// ---------------- batchnorm -------------------------------------------------
__global__ void k_bnstats(const float* __restrict__ x, float* __restrict__ sums,
                          int N, int C){
  int c = threadIdx.x;           // blockDim = C
  float s = 0.f, s2 = 0.f;
  for (int r = blockIdx.x; r < N; r += gridDim.x){
    float v = x[(size_t)r*C + c];
    s += v; s2 += v*v;
  }
  atomicAdd(&sums[c], s);
  atomicAdd(&sums[C + c], s2);
}

__global__ void k_bnstats_bf(const unsigned short* __restrict__ x,
                             float* __restrict__ sums, int N, int C){
  int c = threadIdx.x;
  float s = 0.f, s2 = 0.f;
  for (int r = blockIdx.x; r < N; r += gridDim.x){
    float v = bf2f(x[(size_t)r*C + c]);
    s += v; s2 += v*v;
  }
  atomicAdd(&sums[c], s);
  atomicAdd(&sums[C + c], s2);
}

// sums -> per-channel affine (scale, shift)
__global__ void k_bnfin(const float* __restrict__ sums, const float* __restrict__ gam,
                        const float* __restrict__ bet, float* __restrict__ sc,
                        float* __restrict__ sh, int N, int C){
  int c = threadIdx.x; if (c >= C) return;
  float invN = 1.0f / (float)N;
  float mu  = sums[c] * invN;
  float var = sums[C + c] * invN - mu*mu;
  float r = rsqrtf(var + BN_EPS) * gam[c];
  sc[c] = r;
  sh[c] = bet[c] - mu*r;
}

// -------- fused BN-apply + leaky + gate dot (layer 2, C=256, wave/row) ------
__global__ __launch_bounds__(256) void k_bnapply_gate(
    float* __restrict__ d2, const float* __restrict__ sums,
    const float* __restrict__ gam, const float* __restrict__ bet,
    const float* __restrict__ Wg, const float* __restrict__ bg,
    const int* __restrict__ batch, float* __restrict__ gate,
    unsigned* __restrict__ gm, int N){
  int wid = threadIdx.x >> 6, lane = threadIdx.x & 63;
  int n = blockIdx.x*4 + wid;
  if (n >= N) return;
  int c0 = lane*4;
  float invN = 1.0f / (float)N;
  float4 sv  = *reinterpret_cast<const float4*>(&sums[c0]);
  float4 s2v = *reinterpret_cast<const float4*>(&sums[256 + c0]);
  float4 gv  = *reinterpret_cast<const float4*>(&gam[c0]);
  float4 bv  = *reinterpret_cast<const float4*>(&bet[c0]);
  float4 wgv = *reinterpret_cast<const float4*>(&Wg[c0]);
  float4 x   = *reinterpret_cast<const float4*>(&d2[(size_t)n*256 + c0]);
  float mu0 = sv.x*invN, mu1 = sv.y*invN, mu2 = sv.z*invN, mu3 = sv.w*invN;
  float r0 = rsqrtf(s2v.x*invN - mu0*mu0 + BN_EPS);
  float r1 = rsqrtf(s2v.y*invN - mu1*mu1 + BN_EPS);
  float r2 = rsqrtf(s2v.z*invN - mu2*mu2 + BN_EPS);
  float r3 = rsqrtf(s2v.w*invN - mu3*mu3 + BN_EPS);
  float v0 = (x.x - mu0)*r0*gv.x + bv.x;  v0 = (v0 >= 0.f) ? v0 : LEAKY_ACT*v0;
  float v1 = (x.y - mu1)*r1*gv.y + bv.y;  v1 = (v1 >= 0.f) ? v1 : LEAKY_ACT*v1;
  float v2 = (x.z - mu2)*r2*gv.z + bv.z;  v2 = (v2 >= 0.f) ? v2 : LEAKY_ACT*v2;
  float v3 = (x.w - mu3)*r3*gv.w + bv.w;  v3 = (v3 >= 0.f) ? v3 : LEAKY_ACT*v3;
  *reinterpret_cast<float4*>(&d2[(size_t)n*256 + c0]) = make_float4(v0,v1,v2,v3);
  float s = v0*wgv.x + v1*wgv.y + v2*wgv.z + v3*wgv.w;
  #pragma unroll
  for (int off = 32; off; off >>= 1) s += __shfl_xor(s, off);
  if (lane == 0){
    float g = s + bg[0];
    gate[n] = g;
    atomicMax(&gm[batch[n]], enc_f(g));
  }
}

// ---------------- graph softmax + pooled output -----------------------------
__global__ void k_gexp(float* __restrict__ gate, const int* __restrict__ batch,
                       const unsigned* __restrict__ gm, float* __restrict__ gden, int N){
  int n = blockIdx.x*blockDim.x + threadIdx.x;
  if (n >= N) return;
  int b = batch[n];
  float ex = __expf(gate[n] - dec_f(gm[b]));
  atomicAdd(&gden[b], ex);
  gate[n] = ex;
}

__global__ void k_gptr(const int* __restrict__ batch, int* __restrict__ gptr, int N, int G){
  int n = blockIdx.x*blockDim.x + threadIdx.x;
  if (n > N) return;
  if (n == N){
    int last = batch[N-1];
    for (int g = last+1; g <= G; ++g) gptr[g] = N;
    return;
  }
  int bc = batch[n];
  int bp = (n == 0) ? -1 : batch[n-1];
  for (int g = bp+1; g <= bc; ++g) gptr[g] = n;
}

__global__ void k_final(const float* __restrict__ d2, const float* __restrict__ w,
                        const float* __restrict__ gden, const int* __restrict__ gptr,
                        float* __restrict__ out){
  int g = blockIdx.x;
  int c = threadIdx.x;           // 256
  int s = gptr[g], e = gptr[g+1];
  float den = gden[g];
  if (den == 0.f) den = 1.f;
  float acc = 0.f;
  for (int n = s; n < e; ++n)
    acc += d2[(size_t)n*256 + c] * w[n];
  out[(size_t)g*256 + c] = acc / den;
}

// ============================================================================
extern "C" void kernel_launch(void* const* d_in, const int* in_sizes, int n_in,
                              void* d_out, int out_size, void* d_ws, size_t ws_size,
                              hipStream_t stream){
  const float* x         = (const float*)d_in[0];
  const int*   edge_idx  = (const int*)  d_in[1];
  const float* edge_attr = (const float*)d_in[2];
  const int*   batch     = (const int*)  d_in[3];
  const float* emb       = (const float*)d_in[4];
  const float* Wl1 = (const float*)d_in[5];  const float* bl1 = (const float*)d_in[6];
  const float* Wr1 = (const float*)d_in[7];  const float* br1 = (const float*)d_in[8];
  const float* We1 = (const float*)d_in[9];  const float* att1= (const float*)d_in[10];
  const float* bias1=(const float*)d_in[11]; const float* g1  = (const float*)d_in[12];
  const float* be1 = (const float*)d_in[13];
  const float* Wl2 = (const float*)d_in[14]; const float* bl2 = (const float*)d_in[15];
  const float* Wr2 = (const float*)d_in[16]; const float* br2 = (const float*)d_in[17];
  const float* We2 = (const float*)d_in[18]; const float* att2= (const float*)d_in[19];
  const float* bias2=(const float*)d_in[20]; const float* g2  = (const float*)d_in[21];
  const float* be2 = (const float*)d_in[22];
  const float* Wg  = (const float*)d_in[23]; const float* bg  = (const float*)d_in[24];
  float* out = (float*)d_out;

  const int N = in_sizes[0] / 64;        // 50000
  const int E = in_sizes[1] / 2;         // 800000
  const int EP = E + N;                  // with self-loops
  const int G = 256;
  const int* srcv = edge_idx;
  const int* dstv = edge_idx + E;

  // ---- workspace layout (element offsets, 64-elem aligned) ----
  float* ws = (float*)d_ws;
  size_t o = 0;
  auto alloc = [&](size_t elems){ size_t r = o; o += (elems + 63) & ~(size_t)63; return r; };
  size_t o_big1  = alloc((size_t)N*128);  // hb (bf16 N*128), later xlb2 (bf16 N*256)
  size_t o_union = alloc((size_t)N*256);  // [xr1 f32 | d1b bf16] , later d2 f32
  size_t o_xlb1  = alloc((size_t)N*64);   // xlb1 (bf16, N*128)
  size_t o_xr2   = alloc((size_t)N*256);
  size_t o_ea    = alloc((size_t)N*16);
  size_t o_gate  = alloc((size_t)N);
  size_t o_bn1   = alloc(2*128);          // bn1+bn2 contiguous -> one memset
  size_t o_bn2   = alloc(2*256);
  size_t o_sc1   = alloc(128);
  size_t o_sh1   = alloc(128);
  size_t o_deg   = alloc((size_t)N);      // deg+cur contiguous -> one memset
  size_t o_cur   = alloc((size_t)N);
  size_t o_rp    = alloc((size_t)N+1);
  size_t o_bsum  = alloc(64);
  size_t o_csr   = alloc((size_t)EP*2);   // int2 per CSR slot
  size_t o_wt1l  = alloc(128*128/2);      // bf16 128x128
  size_t o_wt1r  = alloc(128*128/2);
  size_t o_wt2l  = alloc(256*128/2);      // bf16 256x128
  size_t o_wt2r  = alloc(256*128/2);
  size_t o_gm    = alloc(G);              // gm+gden contiguous -> one memset
  size_t o_gden  = alloc(G);
  size_t o_gptr  = alloc(G+1);

  unsigned short* hb   = (unsigned short*)(ws + o_big1);
  unsigned short* xlb2 = (unsigned short*)(ws + o_big1);   // after hb is dead
  float* xr1  = ws + o_union;                              // N*128 f32
  unsigned short* d1b = (unsigned short*)(ws + o_union + (size_t)N*128);
  float* d2   = ws + o_union;                              // after xr1/d1b dead
  unsigned short* xlb1 = (unsigned short*)(ws + o_xlb1);
  float* xr2  = ws + o_xr2;
  float* eam  = ws + o_ea;
  float* gate = ws + o_gate;
  float* bn1  = ws + o_bn1;
  float* bn2  = ws + o_bn2;
  float* sc1  = ws + o_sc1;
  float* sh1  = ws + o_sh1;
  int*   deg  = (int*)(ws + o_deg);
  int*   cur  = (int*)(ws + o_cur);
  int*   rp   = (int*)(ws + o_rp);
  int*   bsum = (int*)(ws + o_bsum);
  int2*  csr2 = (int2*)(ws + o_csr);
  unsigned short* wt1l = (unsigned short*)(ws + o_wt1l);
  unsigned short* wt1r = (unsigned short*)(ws + o_wt1r);
  unsigned short* wt2l = (unsigned short*)(ws + o_wt2l);
  unsigned short* wt2r = (unsigned short*)(ws + o_wt2r);
  unsigned* gm = (unsigned*)(ws + o_gm);
  float* gden = ws + o_gden;
  int*   gptr = (int*)(ws + o_gptr);

  // ---- zero accumulators (graph replays must be deterministic) ----
  hipMemsetAsync(deg, 0, (o_cur - o_deg + (size_t)N)*4, stream);       // deg+cur
  hipMemsetAsync(bn1, 0, (o_bn2 - o_bn1 + 2*256)*4, stream);           // bn1+bn2
  hipMemsetAsync(gm,  0, (o_gden - o_gm + (size_t)G)*4, stream);       // gm+gden

  auto nblk = [](long long n, int b){ return (int)((n + b - 1) / b); };

  // ---- graph prep + weight prep ----
  k_embed<<<N, 64, 0, stream>>>(x, emb, hb, N);
  k_deg<<<nblk(E,256), 256, 0, stream>>>(dstv, deg, E);
  int nbs = nblk(N, 1024);
  k_scan1<<<nbs, 256, 0, stream>>>(deg, rp, bsum, N);
  k_scan2<<<1, 64, 0, stream>>>(bsum, nbs);
  k_scan3<<<nblk((long long)N+1,256), 256, 0, stream>>>(rp, bsum, N, EP);
  k_csrfill<<<nblk(EP,256), 256, 0, stream>>>(srcv, dstv, rp, cur, csr2, E, N);
  k_eamean<<<nblk(N,4), 256, 0, stream>>>(rp, csr2, edge_attr, eam, E, N);
  k_wprep<<<nblk(128*128,256), 256, 0, stream>>>(Wl1, wt1l, 128, 128);
  k_wprep<<<nblk(128*128,256), 256, 0, stream>>>(Wr1, wt1r, 128, 128);
  k_wprep<<<nblk(128*256,256), 256, 0, stream>>>(Wl2, wt2l, 128, 256);
  k_wprep<<<nblk(128*256,256), 256, 0, stream>>>(Wr2, wt2r, 128, 256);

  const int FGRID = 8192;   // persistent 1-wave blocks

  // ---- layer 1 (C=128) ----
  {
    dim3 grid(nblk(N,64), 2);            // y=0: xl, y=1: xr
    k_gemm_mfma<false><<<grid, 256, 0, stream>>>(hb, wt1l, bl1, wt1r, br1,
        nullptr, nullptr, xlb1, xr1, N, 128);
  }
  k_gat_fused<128,8,true><<<FGRID, 64, 0, stream>>>(rp, csr2, edge_attr, eam,
      xlb1, xr1, We1, att1, bias1, nullptr, d1b, E, N);
  k_bnstats_bf<<<512, 128, 0, stream>>>(d1b, bn1, N, 128);
  k_bnfin<<<1, 128, 0, stream>>>(bn1, g1, be1, sc1, sh1, N, 128);

  // ---- layer 2 (C=256); layer-1 BN+leaky fused into A-staging ----
  {
    dim3 grid(nblk(N,64), 4);            // y=0,1: xl halves; y=2,3: xr halves
    k_gemm_mfma<true><<<grid, 256, 0, stream>>>(d1b, wt2l, bl2, wt2r, br2,
        sc1, sh1, xlb2, xr2, N, 256);
  }
  k_gat_fused<256,4,false><<<FGRID, 64, 0, stream>>>(rp, csr2, edge_attr, eam,
      xlb2, xr2, We2, att2, bias2, d2, nullptr, E, N);
  k_bnstats<<<512, 256, 0, stream>>>(d2, bn2, N, 256);
  k_bnapply_gate<<<nblk(N,4), 256, 0, stream>>>(d2, bn2, g2, be2, Wg, bg, batch,
      gate, gm, N);

  // ---- attentional aggregation ----
  k_gexp<<<nblk(N,256), 256, 0, stream>>>(gate, batch, gm, gden, N);
  k_gptr<<<nblk((long long)N+1,256), 256, 0, stream>>>(batch, gptr, N, G);
  k_final<<<G, 256, 0, stream>>>(d2, gate, gden, gptr, out);
}

// Round 10
// 1075.050 us; speedup vs baseline: 1.7908x; 1.2280x over previous
//
#include <hip/hip_runtime.h>
#include <cstddef>
#include <cstdint>

#define LEAKY_ATT 0.2f
#define LEAKY_ACT 0.01f
#define BN_EPS 1e-5f

typedef __attribute__((ext_vector_type(8))) short bf16x8;
typedef __attribute__((ext_vector_type(4))) float f32x4;

static __device__ __forceinline__ unsigned enc_f(float f){
  unsigned u = __float_as_uint(f);
  return (u & 0x80000000u) ? ~u : (u | 0x80000000u);
}
static __device__ __forceinline__ float dec_f(unsigned k){
  return (k & 0x80000000u) ? __uint_as_float(k & 0x7fffffffu) : __uint_as_float(~k);
}
// round-to-nearest-even f32 -> bf16
static __device__ __forceinline__ unsigned short f2bf(float f){
  unsigned u = __float_as_uint(f);
  unsigned r = u + 0x7fffu + ((u >> 16) & 1u);
  return (unsigned short)(r >> 16);
}
static __device__ __forceinline__ float bf_lo(unsigned u){ return __uint_as_float(u << 16); }
static __device__ __forceinline__ float bf_hi(unsigned u){ return __uint_as_float(u & 0xffff0000u); }
static __device__ __forceinline__ float bf2f(unsigned short u){ return __uint_as_float((unsigned)u << 16); }

// full-wave (64-lane) f32 sum via DPP row ops — VALU pipe only, no LDS.
// row_shr:1/2/4/8 then row_bcast:15/31; total lands in lane 63; readlane
// broadcasts to an SGPR. ~6 VALU pairs vs 6 dependent ds_bpermute.
static __device__ __forceinline__ float wave_sum64(float x){
  float t;
  t = __int_as_float(__builtin_amdgcn_update_dpp(0, __float_as_int(x), 0x111, 0xf, 0xf, true)); x += t;
  t = __int_as_float(__builtin_amdgcn_update_dpp(0, __float_as_int(x), 0x112, 0xf, 0xf, true)); x += t;
  t = __int_as_float(__builtin_amdgcn_update_dpp(0, __float_as_int(x), 0x114, 0xf, 0xf, true)); x += t;
  t = __int_as_float(__builtin_amdgcn_update_dpp(0, __float_as_int(x), 0x118, 0xf, 0xf, true)); x += t;
  t = __int_as_float(__builtin_amdgcn_update_dpp(0, __float_as_int(x), 0x142, 0xf, 0xf, true)); x += t; // row_bcast:15
  t = __int_as_float(__builtin_amdgcn_update_dpp(0, __float_as_int(x), 0x143, 0xf, 0xf, true)); x += t; // row_bcast:31
  return __int_as_float(__builtin_amdgcn_readlane(__float_as_int(x), 63));
}

// ---------------- argmax + embedding lookup: hb[n] = bf16(emb[argmax(x[n])]) -
__global__ void k_embed(const float* __restrict__ x, const float* __restrict__ emb,
                        unsigned short* __restrict__ hb, int N){
  int n = blockIdx.x; if (n >= N) return;
  int t = threadIdx.x;            // 64 threads = 1 wave
  float v = x[(size_t)n*64 + t];
  int idx = t;
  #pragma unroll
  for (int off = 32; off; off >>= 1){
    float ov = __shfl_down(v, off);
    int   oi = __shfl_down(idx, off);
    if (ov > v || (ov == v && oi < idx)) { v = ov; idx = oi; }  // first max wins
  }
  idx = __shfl(idx, 0);
  hb[(size_t)n*128 + t]      = f2bf(emb[(size_t)idx*128 + t]);
  hb[(size_t)n*128 + 64 + t] = f2bf(emb[(size_t)idx*128 + 64 + t]);
}

// ---------------- degree per dst --------------------------------------------
__global__ void k_deg(const int* __restrict__ dst, int* __restrict__ deg, int E){
  int e = blockIdx.x*blockDim.x + threadIdx.x;
  if (e >= E) return;
  atomicAdd(&deg[dst[e]], 1);
}

// ---------------- hierarchical exclusive scan of (deg[i]+1) -----------------
__global__ __launch_bounds__(256) void k_scan1(const int* __restrict__ deg,
                        int* __restrict__ rowptr, int* __restrict__ bsum, int N){
  __shared__ int sd[256];
  int tid = threadIdx.x;
  int base = blockIdx.x*1024 + tid*4;
  int v0=0,v1=0,v2=0,v3=0;
  if (base+0 < N) v0 = deg[base+0]+1;
  if (base+1 < N) v1 = deg[base+1]+1;
  if (base+2 < N) v2 = deg[base+2]+1;
  if (base+3 < N) v3 = deg[base+3]+1;
  int t = v0+v1+v2+v3;
  sd[tid] = t;
  __syncthreads();
  for (int off = 1; off < 256; off <<= 1){
    int x = (tid >= off) ? sd[tid-off] : 0;
    __syncthreads();
    sd[tid] += x;
    __syncthreads();
  }
  int excl = sd[tid] - t;
  if (tid == 255) bsum[blockIdx.x] = sd[255];
  if (base+0 < N) rowptr[base+0] = excl;
  if (base+1 < N) rowptr[base+1] = excl + v0;
  if (base+2 < N) rowptr[base+2] = excl + v0 + v1;
  if (base+3 < N) rowptr[base+3] = excl + v0 + v1 + v2;
}
__global__ void k_scan2(int* __restrict__ bsum, int nb){
  int lane = threadIdx.x & 63;
  int carry = 0;
  for (int base = 0; base < nb; base += 64){
    int idx = base + lane;
    int v = (idx < nb) ? bsum[idx] : 0;
    int orig = v;
    #pragma unroll
    for (int off = 1; off < 64; off <<= 1){
      int x = __shfl_up(v, off);
      if (lane >= off) v += x;
    }
    if (idx < nb) bsum[idx] = carry + v - orig;   // exclusive
    carry += __shfl(v, 63);
  }
}
__global__ void k_scan3(int* __restrict__ rowptr, const int* __restrict__ bsum,
                        int N, int EP){
  int i = blockIdx.x*blockDim.x + threadIdx.x;
  if (i < N) rowptr[i] += bsum[i >> 10];
  if (i == N) rowptr[N] = EP;
}

// ---------------- CSR fill: store {src, edge_id} per slot -------------------
__global__ void k_csrfill(const int* __restrict__ src, const int* __restrict__ dst,
                          const int* __restrict__ rowptr,
                          int* __restrict__ cur, int2* __restrict__ csr2, int E, int N){
  int i = blockIdx.x*blockDim.x + threadIdx.x;
  if (i >= E + N) return;
  int d, s;
  if (i < E){ d = dst[i]; s = src[i]; }
  else      { d = i - E;  s = i - E;  }
  int pos = atomicAdd(&cur[d], 1);
  csr2[rowptr[d] + pos] = make_int2(s, i);
}

// ---------------- per-dst mean of edge_attr (CSR-based, no atomics) ---------
__global__ void k_eamean(const int* __restrict__ rowptr, const int2* __restrict__ csr2,
                         const float* __restrict__ ea, float* __restrict__ eam,
                         int E, int N){
  int wid = threadIdx.x >> 6, lane = threadIdx.x & 63;
  int n = blockIdx.x*4 + wid;
  if (n >= N) return;
  int start = rowptr[n], end = rowptr[n+1];
  int j = lane >> 4, k = lane & 15;   // 4 edges x 16 features per pass
  float s = 0.f;
  for (int i = start + j; i < end; i += 4){
    int e = csr2[i].y;
    if (e < E) s += ea[(size_t)e*16 + k];
  }
  s += __shfl_xor(s, 16);
  s += __shfl_xor(s, 32);
  if (lane < 16){
    int deg = end - start - 1;       // real in-degree (one self-loop per node)
    eam[(size_t)n*16 + k] = s / (float)max(deg, 1);
  }
}

// ---------------- weight prep: Wt[n][k] = bf16(W[k][n]) ---------------------
__global__ void k_wprep(const float* __restrict__ W, unsigned short* __restrict__ Wt,
                        int K, int C){
  int i = blockIdx.x*blockDim.x + threadIdx.x;
  if (i >= K*C) return;
  int n = i / K, k = i - n*K;
  Wt[i] = f2bf(W[(size_t)k*C + n]);
}

// ---------------- MFMA GEMM: [xl|xr] = A[N,128]bf16 @ Wt^T + bias -----------
template<bool APPLY_BN>
__global__ __launch_bounds__(256) void k_gemm_mfma(
    const unsigned short* __restrict__ A,
    const unsigned short* __restrict__ Wtl, const float* __restrict__ bl,
    const unsigned short* __restrict__ Wtr, const float* __restrict__ br,
    const float* __restrict__ bnsc, const float* __restrict__ bnsh,
    unsigned short* __restrict__ xlb, float* __restrict__ xr,
    int N, int C)
{
  constexpr int K = 128;
  __shared__ unsigned short As[64][40];    // +8 bf16 pad: bank-conflict-free b128
  int tid = threadIdx.x;
  int wv = tid >> 6, lane = tid & 63;
  int m0 = blockIdx.x*64;
  int half = gridDim.y >> 1;
  bool isL = ((int)blockIdx.y < half);
  int n0 = (isL ? blockIdx.y : blockIdx.y - half) * 128;
  const unsigned short* Wt = isL ? Wtl : Wtr;
  const float* bias = isL ? bl : br;

  f32x4 acc[8];
  #pragma unroll
  for (int t = 0; t < 8; ++t) acc[t] = (f32x4){0.f,0.f,0.f,0.f};

  int srow = tid >> 2;            // 0..63
  int sseg = (tid & 3) * 8;       // k-offset 0,8,16,24
  int grow = m0 + srow;
  int arow = wv*16 + (lane & 15);
  int koff = (lane >> 4) * 8;

  for (int k0 = 0; k0 < K; k0 += 32){
    __syncthreads();
    uint4 raw = make_uint4(0,0,0,0);
    if (grow < N){
      raw = *reinterpret_cast<const uint4*>(&A[(size_t)grow*K + k0 + sseg]);
      if constexpr (APPLY_BN){
        float4 sa = *reinterpret_cast<const float4*>(&bnsc[k0 + sseg]);
        float4 sb = *reinterpret_cast<const float4*>(&bnsc[k0 + sseg + 4]);
        float4 ha = *reinterpret_cast<const float4*>(&bnsh[k0 + sseg]);
        float4 hb = *reinterpret_cast<const float4*>(&bnsh[k0 + sseg + 4]);
        float f0 = bf_lo(raw.x)*sa.x + ha.x; f0 = (f0>=0.f)?f0:LEAKY_ACT*f0;
        float f1 = bf_hi(raw.x)*sa.y + ha.y; f1 = (f1>=0.f)?f1:LEAKY_ACT*f1;
        float f2 = bf_lo(raw.y)*sa.z + ha.z; f2 = (f2>=0.f)?f2:LEAKY_ACT*f2;
        float f3 = bf_hi(raw.y)*sa.w + ha.w; f3 = (f3>=0.f)?f3:LEAKY_ACT*f3;
        float f4 = bf_lo(raw.z)*sb.x + hb.x; f4 = (f4>=0.f)?f4:LEAKY_ACT*f4;
        float f5 = bf_hi(raw.z)*sb.y + hb.y; f5 = (f5>=0.f)?f5:LEAKY_ACT*f5;
        float f6 = bf_lo(raw.w)*sb.z + hb.z; f6 = (f6>=0.f)?f6:LEAKY_ACT*f6;
        float f7 = bf_hi(raw.w)*sb.w + hb.w; f7 = (f7>=0.f)?f7:LEAKY_ACT*f7;
        raw.x = (unsigned)f2bf(f0) | ((unsigned)f2bf(f1) << 16);
        raw.y = (unsigned)f2bf(f2) | ((unsigned)f2bf(f3) << 16);
        raw.z = (unsigned)f2bf(f4) | ((unsigned)f2bf(f5) << 16);
        raw.w = (unsigned)f2bf(f6) | ((unsigned)f2bf(f7) << 16);
      }
    }
    *reinterpret_cast<uint4*>(&As[srow][sseg]) = raw;
    __syncthreads();
    bf16x8 a = *reinterpret_cast<const bf16x8*>(&As[arow][koff]);
    #pragma unroll
    for (int nt = 0; nt < 8; ++nt){
      int ncol = n0 + nt*16 + (lane & 15);
      bf16x8 b = *reinterpret_cast<const bf16x8*>(&Wt[(size_t)ncol*K + k0 + koff]);
      acc[nt] = __builtin_amdgcn_mfma_f32_16x16x32_bf16(a, b, acc[nt], 0, 0, 0);
    }
  }
  int rbase = m0 + wv*16 + (lane >> 4)*4;
  #pragma unroll
  for (int nt = 0; nt < 8; ++nt){
    int col = n0 + nt*16 + (lane & 15);
    float bv = bias[col];
    #pragma unroll
    for (int r = 0; r < 4; ++r){
      int row = rbase + r;
      if (row < N){
        float v = acc[nt][r] + bv;
        if (isL) xlb[(size_t)row*C + col] = f2bf(v);
        else     xr [(size_t)row*C + col] = v;
      }
    }
  }
}

// ---------------- fused GATv2: logits + softmax + aggregation ---------------
// 1 wave/block persistent; double-buffered edge batches (csr2 + bf16 xl row +
// edge-attr all prefetched). Logit reduce via DPP (wave_sum64) — VALU pipe
// only, replaces 6 dependent ds_bpermute ops that were the per-edge latency
// floor. No max-subtraction (logits O(1) by construction, softmax
// shift-invariant -> edges independent).
template<int C, int UNR, bool OUTBF>
__global__ __launch_bounds__(64) void k_gat_fused(
    const int* __restrict__ rowptr, const int2* __restrict__ csr2,
    const float* __restrict__ edge_attr, const float* __restrict__ eam,
    const unsigned short* __restrict__ xlb, const float* __restrict__ xr,
    const float* __restrict__ We, const float* __restrict__ att,
    const float* __restrict__ bias, float* __restrict__ out_f,
    unsigned short* __restrict__ out_b, int E, int N)
{
  constexpr int CPL = C/64;          // 2 or 4 columns per lane
  constexpr int PK  = CPL/2;         // packed uints per edge per lane
  const int lane = threadIdx.x;
  const int c0 = lane*CPL;

  float wreg[16][CPL];
  #pragma unroll
  for (int k = 0; k < 16; ++k)
    #pragma unroll
    for (int q = 0; q < CPL; ++q)
      wreg[k][q] = We[k*C + c0 + q];
  float attv[CPL], biasv[CPL];
  #pragma unroll
  for (int q = 0; q < CPL; ++q){ attv[q] = att[c0 + q]; biasv[q] = bias[c0 + q]; }

  for (int n = blockIdx.x; n < N; n += gridDim.x){
    float xrv[CPL];
    #pragma unroll
    for (int q = 0; q < CPL; ++q) xrv[q] = xr[(size_t)n*C + c0 + q];
    int start = __builtin_amdgcn_readfirstlane(rowptr[n]);
    int end   = __builtin_amdgcn_readfirstlane(rowptr[n+1]);

    float denom = 0.f;
    float acc[CPL] = {};

    unsigned xA[UNR][PK]; float eaA[UNR];
    unsigned xB[UNR][PK]; float eaB[UNR];

    auto stage = [&](int base, unsigned (&xp)[UNR][PK], float (&eal)[UNR]){
      #pragma unroll
      for (int u = 0; u < UNR; ++u){
        if (base + u < end){
          int2 v = csr2[base + u];
          int s = __builtin_amdgcn_readfirstlane(v.x);
          int e = __builtin_amdgcn_readfirstlane(v.y);
          const float* eap = (e < E) ? edge_attr + (size_t)e*16
                                     : eam + (size_t)(e - E)*16;
          eal[u] = eap[lane & 15];               // prefetched into VGPR
          const unsigned short* prow = xlb + (size_t)s*C + c0;
          if constexpr (PK == 2){
            uint2 w = *reinterpret_cast<const uint2*>(prow);
            xp[u][0] = w.x; xp[u][1] = w.y;
          } else {
            xp[u][0] = *reinterpret_cast<const unsigned*>(prow);
          }
        } else {
          eal[u] = 0.f;
          #pragma unroll
          for (int p = 0; p < PK; ++p) xp[u][p] = 0;
        }
      }
    };
    auto compute = [&](int base, unsigned (&xp)[UNR][PK], float (&eal)[UNR]){
      float pe[UNR];
      #pragma unroll
      for (int u = 0; u < UNR; ++u){
        if (base + u < end){
          float w[CPL] = {};
          #pragma unroll
          for (int k = 0; k < 16; ++k){
            float aa = __shfl(eal[u], k);        // v_readlane (register op)
            #pragma unroll
            for (int q = 0; q < CPL; ++q) w[q] += aa * wreg[k][q];
          }
          float p = 0.f;
          #pragma unroll
          for (int p2 = 0; p2 < PK; ++p2){
            float x0 = bf_lo(xp[u][p2]), x1 = bf_hi(xp[u][p2]);
            float v0 = x0 + xrv[2*p2]   + w[2*p2];
            float v1 = x1 + xrv[2*p2+1] + w[2*p2+1];
            v0 = (v0 >= 0.f) ? v0 : LEAKY_ATT*v0;
            v1 = (v1 >= 0.f) ? v1 : LEAKY_ATT*v1;
            p += attv[2*p2]*v0 + attv[2*p2+1]*v1;
          }
          p = wave_sum64(p);                     // DPP reduce (VALU only)
          pe[u] = __expf(p);
        } else pe[u] = 0.f;
      }
      #pragma unroll
      for (int u = 0; u < UNR; ++u) denom += pe[u];
      #pragma unroll
      for (int u = 0; u < UNR; ++u)
        #pragma unroll
        for (int p2 = 0; p2 < PK; ++p2){
          acc[2*p2]   += pe[u]*bf_lo(xp[u][p2]);
          acc[2*p2+1] += pe[u]*bf_hi(xp[u][p2]);
        }
    };

    int i = start;
    stage(i, xA, eaA);
    for (;;){
      int j = i + UNR;
      if (j < end) stage(j, xB, eaB);
      compute(i, xA, eaA);
      i = j;
      if (i >= end) break;
      j = i + UNR;
      if (j < end) stage(j, xA, eaA);
      compute(i, xB, eaB);
      i = j;
      if (i >= end) break;
    }

    float inv = 1.0f / denom;     // self-loop guarantees denom > 0
    if constexpr (OUTBF){
      #pragma unroll
      for (int p2 = 0; p2 < PK; ++p2){
        unsigned po = (unsigned)f2bf(acc[2*p2]*inv + biasv[2*p2])
                    | ((unsigned)f2bf(acc[2*p2+1]*inv + biasv[2*p2+1]) << 16);
        *reinterpret_cast<unsigned*>(&out_b[(size_t)n*C + c0 + 2*p2]) = po;
      }
    } else {
      if constexpr (CPL == 4){
        float4 o = make_float4(acc[0]*inv + biasv[0], acc[1]*inv + biasv[1],
                               acc[2]*inv + biasv[2], acc[3]*inv + biasv[3]);
        *reinterpret_cast<float4*>(&out_f[(size_t)n*C + c0]) = o;
      } else {
        float2 o = make_float2(acc[0]*inv + biasv[0], acc[1]*inv + biasv[1]);
        *reinterpret_cast<float2*>(&out_f[(size_t)n*C + c0]) = o;
      }
    }
  }
}

// ---------------- batchnorm -------------------------------------------------
__global__ void k_bnstats(const float* __restrict__ x, float* __restrict__ sums,
                          int N, int C){
  int c = threadIdx.x;           // blockDim = C
  float s = 0.f, s2 = 0.f;
  for (int r = blockIdx.x; r < N; r += gridDim.x){
    float v = x[(size_t)r*C + c];
    s += v; s2 += v*v;
  }
  atomicAdd(&sums[c], s);
  atomicAdd(&sums[C + c], s2);
}

__global__ void k_bnstats_bf(const unsigned short* __restrict__ x,
                             float* __restrict__ sums, int N, int C){
  int c = threadIdx.x;
  float s = 0.f, s2 = 0.f;
  for (int r = blockIdx.x; r < N; r += gridDim.x){
    float v = bf2f(x[(size_t)r*C + c]);
    s += v; s2 += v*v;
  }
  atomicAdd(&sums[c], s);
  atomicAdd(&sums[C + c], s2);
}

// sums -> per-channel affine (scale, shift)
__global__ void k_bnfin(const float* __restrict__ sums, const float* __restrict__ gam,
                        const float* __restrict__ bet, float* __restrict__ sc,
                        float* __restrict__ sh, int N, int C){
  int c = threadIdx.x; if (c >= C) return;
  float invN = 1.0f / (float)N;
  float mu  = sums[c] * invN;
  float var = sums[C + c] * invN - mu*mu;
  float r = rsqrtf(var + BN_EPS) * gam[c];
  sc[c] = r;
  sh[c] = bet[c] - mu*r;
}

// -------- fused BN-apply + leaky + gate dot (layer 2, C=256, wave/row) ------
__global__ __launch_bounds__(256) void k_bnapply_gate(
    float* __restrict__ d2, const float* __restrict__ sums,
    const float* __restrict__ gam, const float* __restrict__ bet,
    const float* __restrict__ Wg, const float* __restrict__ bg,
    const int* __restrict__ batch, float* __restrict__ gate,
    unsigned* __restrict__ gm, int N){
  int wid = threadIdx.x >> 6, lane = threadIdx.x & 63;
  int n = blockIdx.x*4 + wid;
  if (n >= N) return;
  int c0 = lane*4;
  float invN = 1.0f / (float)N;
  float4 sv  = *reinterpret_cast<const float4*>(&sums[c0]);
  float4 s2v = *reinterpret_cast<const float4*>(&sums[256 + c0]);
  float4 gv  = *reinterpret_cast<const float4*>(&gam[c0]);
  float4 bv  = *reinterpret_cast<const float4*>(&bet[c0]);
  float4 wgv = *reinterpret_cast<const float4*>(&Wg[c0]);
  float4 x   = *reinterpret_cast<const float4*>(&d2[(size_t)n*256 + c0]);
  float mu0 = sv.x*invN, mu1 = sv.y*invN, mu2 = sv.z*invN, mu3 = sv.w*invN;
  float r0 = rsqrtf(s2v.x*invN - mu0*mu0 + BN_EPS);
  float r1 = rsqrtf(s2v.y*invN - mu1*mu1 + BN_EPS);
  float r2 = rsqrtf(s2v.z*invN - mu2*mu2 + BN_EPS);
  float r3 = rsqrtf(s2v.w*invN - mu3*mu3 + BN_EPS);
  float v0 = (x.x - mu0)*r0*gv.x + bv.x;  v0 = (v0 >= 0.f) ? v0 : LEAKY_ACT*v0;
  float v1 = (x.y - mu1)*r1*gv.y + bv.y;  v1 = (v1 >= 0.f) ? v1 : LEAKY_ACT*v1;
  float v2 = (x.z - mu2)*r2*gv.z + bv.z;  v2 = (v2 >= 0.f) ? v2 : LEAKY_ACT*v2;
  float v3 = (x.w - mu3)*r3*gv.w + bv.w;  v3 = (v3 >= 0.f) ? v3 : LEAKY_ACT*v3;
  *reinterpret_cast<float4*>(&d2[(size_t)n*256 + c0]) = make_float4(v0,v1,v2,v3);
  float s = v0*wgv.x + v1*wgv.y + v2*wgv.z + v3*wgv.w;
  #pragma unroll
  for (int off = 32; off; off >>= 1) s += __shfl_xor(s, off);
  if (lane == 0){
    float g = s + bg[0];
    gate[n] = g;
    atomicMax(&gm[batch[n]], enc_f(g));
  }
}

// ---------------- graph softmax + pooled output -----------------------------
__global__ void k_gexp(float* __restrict__ gate, const int* __restrict__ batch,
                       const unsigned* __restrict__ gm, float* __restrict__ gden, int N){
  int n = blockIdx.x*blockDim.x + threadIdx.x;
  if (n >= N) return;
  int b = batch[n];
  float ex = __expf(gate[n] - dec_f(gm[b]));
  atomicAdd(&gden[b], ex);
  gate[n] = ex;
}

__global__ void k_gptr(const int* __restrict__ batch, int* __restrict__ gptr, int N, int G){
  int n = blockIdx.x*blockDim.x + threadIdx.x;
  if (n > N) return;
  if (n == N){
    int last = batch[N-1];
    for (int g = last+1; g <= G; ++g) gptr[g] = N;
    return;
  }
  int bc = batch[n];
  int bp = (n == 0) ? -1 : batch[n-1];
  for (int g = bp+1; g <= bc; ++g) gptr[g] = n;
}

__global__ void k_final(const float* __restrict__ d2, const float* __restrict__ w,
                        const float* __restrict__ gden, const int* __restrict__ gptr,
                        float* __restrict__ out){
  int g = blockIdx.x;
  int c = threadIdx.x;           // 256
  int s = gptr[g], e = gptr[g+1];
  float den = gden[g];
  if (den == 0.f) den = 1.f;
  float acc = 0.f;
  for (int n = s; n < e; ++n)
    acc += d2[(size_t)n*256 + c] * w[n];
  out[(size_t)g*256 + c] = acc / den;
}

// ============================================================================
extern "C" void kernel_launch(void* const* d_in, const int* in_sizes, int n_in,
                              void* d_out, int out_size, void* d_ws, size_t ws_size,
                              hipStream_t stream){
  const float* x         = (const float*)d_in[0];
  const int*   edge_idx  = (const int*)  d_in[1];
  const float* edge_attr = (const float*)d_in[2];
  const int*   batch     = (const int*)  d_in[3];
  const float* emb       = (const float*)d_in[4];
  const float* Wl1 = (const float*)d_in[5];  const float* bl1 = (const float*)d_in[6];
  const float* Wr1 = (const float*)d_in[7];  const float* br1 = (const float*)d_in[8];
  const float* We1 = (const float*)d_in[9];  const float* att1= (const float*)d_in[10];
  const float* bias1=(const float*)d_in[11]; const float* g1  = (const float*)d_in[12];
  const float* be1 = (const float*)d_in[13];
  const float* Wl2 = (const float*)d_in[14]; const float* bl2 = (const float*)d_in[15];
  const float* Wr2 = (const float*)d_in[16]; const float* br2 = (const float*)d_in[17];
  const float* We2 = (const float*)d_in[18]; const float* att2= (const float*)d_in[19];
  const float* bias2=(const float*)d_in[20]; const float* g2  = (const float*)d_in[21];
  const float* be2 = (const float*)d_in[22];
  const float* Wg  = (const float*)d_in[23]; const float* bg  = (const float*)d_in[24];
  float* out = (float*)d_out;

  const int N = in_sizes[0] / 64;        // 50000
  const int E = in_sizes[1] / 2;         // 800000
  const int EP = E + N;                  // with self-loops
  const int G = 256;
  const int* srcv = edge_idx;
  const int* dstv = edge_idx + E;

  // ---- workspace layout (element offsets, 64-elem aligned) ----
  float* ws = (float*)d_ws;
  size_t o = 0;
  auto alloc = [&](size_t elems){ size_t r = o; o += (elems + 63) & ~(size_t)63; return r; };
  size_t o_big1  = alloc((size_t)N*128);  // hb (bf16 N*128), later xlb2 (bf16 N*256)
  size_t o_union = alloc((size_t)N*256);  // [xr1 f32 | d1b bf16] , later d2 f32
  size_t o_xlb1  = alloc((size_t)N*64);   // xlb1 (bf16, N*128)
  size_t o_xr2   = alloc((size_t)N*256);
  size_t o_ea    = alloc((size_t)N*16);
  size_t o_gate  = alloc((size_t)N);
  size_t o_bn1   = alloc(2*128);          // bn1+bn2 contiguous -> one memset
  size_t o_bn2   = alloc(2*256);
  size_t o_sc1   = alloc(128);
  size_t o_sh1   = alloc(128);
  size_t o_deg   = alloc((size_t)N);      // deg+cur contiguous -> one memset
  size_t o_cur   = alloc((size_t)N);
  size_t o_rp    = alloc((size_t)N+1);
  size_t o_bsum  = alloc(64);
  size_t o_csr   = alloc((size_t)EP*2);   // int2 per CSR slot
  size_t o_wt1l  = alloc(128*128/2);      // bf16 128x128
  size_t o_wt1r  = alloc(128*128/2);
  size_t o_wt2l  = alloc(256*128/2);      // bf16 256x128
  size_t o_wt2r  = alloc(256*128/2);
  size_t o_gm    = alloc(G);              // gm+gden contiguous -> one memset
  size_t o_gden  = alloc(G);
  size_t o_gptr  = alloc(G+1);

  unsigned short* hb   = (unsigned short*)(ws + o_big1);
  unsigned short* xlb2 = (unsigned short*)(ws + o_big1);   // after hb is dead
  float* xr1  = ws + o_union;                              // N*128 f32
  unsigned short* d1b = (unsigned short*)(ws + o_union + (size_t)N*128);
  float* d2   = ws + o_union;                              // after xr1/d1b dead
  unsigned short* xlb1 = (unsigned short*)(ws + o_xlb1);
  float* xr2  = ws + o_xr2;
  float* eam  = ws + o_ea;
  float* gate = ws + o_gate;
  float* bn1  = ws + o_bn1;
  float* bn2  = ws + o_bn2;
  float* sc1  = ws + o_sc1;
  float* sh1  = ws + o_sh1;
  int*   deg  = (int*)(ws + o_deg);
  int*   cur  = (int*)(ws + o_cur);
  int*   rp   = (int*)(ws + o_rp);
  int*   bsum = (int*)(ws + o_bsum);
  int2*  csr2 = (int2*)(ws + o_csr);
  unsigned short* wt1l = (unsigned short*)(ws + o_wt1l);
  unsigned short* wt1r = (unsigned short*)(ws + o_wt1r);
  unsigned short* wt2l = (unsigned short*)(ws + o_wt2l);
  unsigned short* wt2r = (unsigned short*)(ws + o_wt2r);
  unsigned* gm = (unsigned*)(ws + o_gm);
  float* gden = ws + o_gden;
  int*   gptr = (int*)(ws + o_gptr);

  // ---- zero accumulators (graph replays must be deterministic) ----
  hipMemsetAsync(deg, 0, (o_cur - o_deg + (size_t)N)*4, stream);       // deg+cur
  hipMemsetAsync(bn1, 0, (o_bn2 - o_bn1 + 2*256)*4, stream);           // bn1+bn2
  hipMemsetAsync(gm,  0, (o_gden - o_gm + (size_t)G)*4, stream);       // gm+gden

  auto nblk = [](long long n, int b){ return (int)((n + b - 1) / b); };

  // ---- graph prep + weight prep ----
  k_embed<<<N, 64, 0, stream>>>(x, emb, hb, N);
  k_deg<<<nblk(E,256), 256, 0, stream>>>(dstv, deg, E);
  int nbs = nblk(N, 1024);
  k_scan1<<<nbs, 256, 0, stream>>>(deg, rp, bsum, N);
  k_scan2<<<1, 64, 0, stream>>>(bsum, nbs);
  k_scan3<<<nblk((long long)N+1,256), 256, 0, stream>>>(rp, bsum, N, EP);
  k_csrfill<<<nblk(EP,256), 256, 0, stream>>>(srcv, dstv, rp, cur, csr2, E, N);
  k_eamean<<<nblk(N,4), 256, 0, stream>>>(rp, csr2, edge_attr, eam, E, N);
  k_wprep<<<nblk(128*128,256), 256, 0, stream>>>(Wl1, wt1l, 128, 128);
  k_wprep<<<nblk(128*128,256), 256, 0, stream>>>(Wr1, wt1r, 128, 128);
  k_wprep<<<nblk(128*256,256), 256, 0, stream>>>(Wl2, wt2l, 128, 256);
  k_wprep<<<nblk(128*256,256), 256, 0, stream>>>(Wr2, wt2r, 128, 256);

  const int FGRID = 8192;   // persistent 1-wave blocks

  // ---- layer 1 (C=128) ----
  {
    dim3 grid(nblk(N,64), 2);            // y=0: xl, y=1: xr
    k_gemm_mfma<false><<<grid, 256, 0, stream>>>(hb, wt1l, bl1, wt1r, br1,
        nullptr, nullptr, xlb1, xr1, N, 128);
  }
  k_gat_fused<128,8,true><<<FGRID, 64, 0, stream>>>(rp, csr2, edge_attr, eam,
      xlb1, xr1, We1, att1, bias1, nullptr, d1b, E, N);
  k_bnstats_bf<<<512, 128, 0, stream>>>(d1b, bn1, N, 128);
  k_bnfin<<<1, 128, 0, stream>>>(bn1, g1, be1, sc1, sh1, N, 128);

  // ---- layer 2 (C=256); layer-1 BN+leaky fused into A-staging ----
  {
    dim3 grid(nblk(N,64), 4);            // y=0,1: xl halves; y=2,3: xr halves
    k_gemm_mfma<true><<<grid, 256, 0, stream>>>(d1b, wt2l, bl2, wt2r, br2,
        sc1, sh1, xlb2, xr2, N, 256);
  }
  k_gat_fused<256,6,false><<<FGRID, 64, 0, stream>>>(rp, csr2, edge_attr, eam,
      xlb2, xr2, We2, att2, bias2, d2, nullptr, E, N);
  k_bnstats<<<512, 256, 0, stream>>>(d2, bn2, N, 256);
  k_bnapply_gate<<<nblk(N,4), 256, 0, stream>>>(d2, bn2, g2, be2, Wg, bg, batch,
      gate, gm, N);

  // ---- attentional aggregation ----
  k_gexp<<<nblk(N,256), 256, 0, stream>>>(gate, batch, gm, gden, N);
  k_gptr<<<nblk((long long)N+1,256), 256, 0, stream>>>(batch, gptr, N, G);
  k_final<<<G, 256, 0, stream>>>(d2, gate, gden, gptr, out);
}

// Round 12
// 843.672 us; speedup vs baseline: 2.2819x; 1.2743x over previous
//
#include <hip/hip_runtime.h>
#include <cstddef>
#include <cstdint>

#define LEAKY_ATT 0.2f
#define LEAKY_ACT 0.01f
#define BN_EPS 1e-5f

typedef __attribute__((ext_vector_type(8))) short bf16x8;
typedef __attribute__((ext_vector_type(4))) float f32x4;
typedef __fp16 f16x2 __attribute__((ext_vector_type(2)));

// round-to-nearest-even f32 -> bf16
static __device__ __forceinline__ unsigned short f2bf(float f){
  unsigned u = __float_as_uint(f);
  unsigned r = u + 0x7fffu + ((u >> 16) & 1u);
  return (unsigned short)(r >> 16);
}
static __device__ __forceinline__ float bf_lo(unsigned u){ return __uint_as_float(u << 16); }
static __device__ __forceinline__ float bf_hi(unsigned u){ return __uint_as_float(u & 0xffff0000u); }
static __device__ __forceinline__ float bf2f(unsigned short u){ return __uint_as_float((unsigned)u << 16); }

static __device__ __forceinline__ f16x2 cvtpk(float a, float b){
#if __has_builtin(__builtin_amdgcn_cvt_pkrtz)
  return __builtin_amdgcn_cvt_pkrtz(a, b);
#else
  f16x2 r; r.x = (__fp16)a; r.y = (__fp16)b; return r;
#endif
}
#if __has_builtin(__builtin_amdgcn_fdot2)
#define FDOT2(a,b,c) __builtin_amdgcn_fdot2((a),(b),(c),false)
#else
static __device__ __forceinline__ float fdot2_emu(f16x2 a, f16x2 b, float c){
  return (float)a.x*(float)b.x + ((float)a.y*(float)b.y + c);
}
#define FDOT2(a,b,c) fdot2_emu((a),(b),(c))
#endif

static __device__ __forceinline__ f16x2 bcast_pair(f16x2 v, int k){
  int iv; __builtin_memcpy(&iv, &v, 4);
  iv = __shfl(iv, k);
  f16x2 r; __builtin_memcpy(&r, &iv, 4);
  return r;
}

// full-wave (64-lane) f32 sum via DPP row ops — VALU pipe only, no LDS.
static __device__ __forceinline__ float wave_sum64(float x){
  float t;
  t = __int_as_float(__builtin_amdgcn_update_dpp(0, __float_as_int(x), 0x111, 0xf, 0xf, true)); x += t;
  t = __int_as_float(__builtin_amdgcn_update_dpp(0, __float_as_int(x), 0x112, 0xf, 0xf, true)); x += t;
  t = __int_as_float(__builtin_amdgcn_update_dpp(0, __float_as_int(x), 0x114, 0xf, 0xf, true)); x += t;
  t = __int_as_float(__builtin_amdgcn_update_dpp(0, __float_as_int(x), 0x118, 0xf, 0xf, true)); x += t;
  t = __int_as_float(__builtin_amdgcn_update_dpp(0, __float_as_int(x), 0x142, 0xf, 0xf, true)); x += t; // row_bcast:15
  t = __int_as_float(__builtin_amdgcn_update_dpp(0, __float_as_int(x), 0x143, 0xf, 0xf, true)); x += t; // row_bcast:31
  return __int_as_float(__builtin_amdgcn_readlane(__float_as_int(x), 63));
}

// ---------------- argmax + embedding lookup (grid-stride, 4 waves/block) ----
__global__ void k_embed(const float* __restrict__ x, const float* __restrict__ emb,
                        unsigned short* __restrict__ hb, int N){
  int wv = threadIdx.x >> 6, lane = threadIdx.x & 63;
  for (int n = blockIdx.x*4 + wv; n < N; n += gridDim.x*4){
    float v = x[(size_t)n*64 + lane];
    int idx = lane;
    #pragma unroll
    for (int off = 32; off; off >>= 1){
      float ov = __shfl_down(v, off);
      int   oi = __shfl_down(idx, off);
      if (ov > v || (ov == v && oi < idx)) { v = ov; idx = oi; }  // first max wins
    }
    idx = __shfl(idx, 0);
    hb[(size_t)n*128 + lane]      = f2bf(emb[(size_t)idx*128 + lane]);
    hb[(size_t)n*128 + 64 + lane] = f2bf(emb[(size_t)idx*128 + 64 + lane]);
  }
}

// ---------------- degree per dst --------------------------------------------
__global__ void k_deg(const int* __restrict__ dst, int* __restrict__ deg, int E){
  int e = blockIdx.x*blockDim.x + threadIdx.x;
  if (e >= E) return;
  atomicAdd(&deg[dst[e]], 1);
}

// ---------------- hierarchical exclusive scan of (deg[i]+1) -----------------
__global__ __launch_bounds__(256) void k_scan1(const int* __restrict__ deg,
                        int* __restrict__ rowptr, int* __restrict__ bsum, int N){
  __shared__ int sd[256];
  int tid = threadIdx.x;
  int base = blockIdx.x*1024 + tid*4;
  int v0=0,v1=0,v2=0,v3=0;
  if (base+0 < N) v0 = deg[base+0]+1;
  if (base+1 < N) v1 = deg[base+1]+1;
  if (base+2 < N) v2 = deg[base+2]+1;
  if (base+3 < N) v3 = deg[base+3]+1;
  int t = v0+v1+v2+v3;
  sd[tid] = t;
  __syncthreads();
  for (int off = 1; off < 256; off <<= 1){
    int x = (tid >= off) ? sd[tid-off] : 0;
    __syncthreads();
    sd[tid] += x;
    __syncthreads();
  }
  int excl = sd[tid] - t;
  if (tid == 255) bsum[blockIdx.x] = sd[255];
  if (base+0 < N) rowptr[base+0] = excl;
  if (base+1 < N) rowptr[base+1] = excl + v0;
  if (base+2 < N) rowptr[base+2] = excl + v0 + v1;
  if (base+3 < N) rowptr[base+3] = excl + v0 + v1 + v2;
}
__global__ void k_scan2(int* __restrict__ bsum, int nb){
  int lane = threadIdx.x & 63;
  int carry = 0;
  for (int base = 0; base < nb; base += 64){
    int idx = base + lane;
    int v = (idx < nb) ? bsum[idx] : 0;
    int orig = v;
    #pragma unroll
    for (int off = 1; off < 64; off <<= 1){
      int x = __shfl_up(v, off);
      if (lane >= off) v += x;
    }
    if (idx < nb) bsum[idx] = carry + v - orig;   // exclusive
    carry += __shfl(v, 63);
  }
}
__global__ void k_scan3(int* __restrict__ rowptr, const int* __restrict__ bsum,
                        int N, int EP){
  int i = blockIdx.x*blockDim.x + threadIdx.x;
  if (i < N) rowptr[i] += bsum[i >> 10];
  if (i == N) rowptr[N] = EP;
}

// ---------------- CSR fill: store {src, edge_id} per slot -------------------
__global__ void k_csrfill(const int* __restrict__ src, const int* __restrict__ dst,
                          const int* __restrict__ rowptr,
                          int* __restrict__ cur, int2* __restrict__ csr2, int E, int N){
  int i = blockIdx.x*blockDim.x + threadIdx.x;
  if (i >= E + N) return;
  int d, s;
  if (i < E){ d = dst[i]; s = src[i]; }
  else      { d = i - E;  s = i - E;  }
  int pos = atomicAdd(&cur[d], 1);
  csr2[rowptr[d] + pos] = make_int2(s, i);
}

// ---------------- weight prep: Wt[n][k] = bf16(W[k][n]) ---------------------
__global__ void k_wprep(const float* __restrict__ W, unsigned short* __restrict__ Wt,
                        int K, int C){
  int i = blockIdx.x*blockDim.x + threadIdx.x;
  if (i >= K*C) return;
  int n = i / K, k = i - n*K;
  Wt[i] = f2bf(W[(size_t)k*C + n]);
}

// ---------------- MFMA GEMM: [xl|xr] = A[N,128]bf16 @ Wt^T + bias -----------
template<bool APPLY_BN>
__global__ __launch_bounds__(256) void k_gemm_mfma(
    const unsigned short* __restrict__ A,
    const unsigned short* __restrict__ Wtl, const float* __restrict__ bl,
    const unsigned short* __restrict__ Wtr, const float* __restrict__ br,
    const float* __restrict__ bnsc, const float* __restrict__ bnsh,
    unsigned short* __restrict__ xlb, float* __restrict__ xr,
    int N, int C)
{
  constexpr int K = 128;
  __shared__ unsigned short As[64][40];    // +8 bf16 pad: bank-conflict-free b128
  int tid = threadIdx.x;
  int wv = tid >> 6, lane = tid & 63;
  int m0 = blockIdx.x*64;
  int half = gridDim.y >> 1;
  bool isL = ((int)blockIdx.y < half);
  int n0 = (isL ? blockIdx.y : blockIdx.y - half) * 128;
  const unsigned short* Wt = isL ? Wtl : Wtr;
  const float* bias = isL ? bl : br;

  f32x4 acc[8];
  #pragma unroll
  for (int t = 0; t < 8; ++t) acc[t] = (f32x4){0.f,0.f,0.f,0.f};

  int srow = tid >> 2;            // 0..63
  int sseg = (tid & 3) * 8;       // k-offset 0,8,16,24
  int grow = m0 + srow;
  int arow = wv*16 + (lane & 15);
  int koff = (lane >> 4) * 8;

  for (int k0 = 0; k0 < K; k0 += 32){
    __syncthreads();
    uint4 raw = make_uint4(0,0,0,0);
    if (grow < N){
      raw = *reinterpret_cast<const uint4*>(&A[(size_t)grow*K + k0 + sseg]);
      if constexpr (APPLY_BN){
        float4 sa = *reinterpret_cast<const float4*>(&bnsc[k0 + sseg]);
        float4 sb = *reinterpret_cast<const float4*>(&bnsc[k0 + sseg + 4]);
        float4 ha = *reinterpret_cast<const float4*>(&bnsh[k0 + sseg]);
        float4 hb = *reinterpret_cast<const float4*>(&bnsh[k0 + sseg + 4]);
        float f0 = bf_lo(raw.x)*sa.x + ha.x; f0 = (f0>=0.f)?f0:LEAKY_ACT*f0;
        float f1 = bf_hi(raw.x)*sa.y + ha.y; f1 = (f1>=0.f)?f1:LEAKY_ACT*f1;
        float f2 = bf_lo(raw.y)*sa.z + ha.z; f2 = (f2>=0.f)?f2:LEAKY_ACT*f2;
        float f3 = bf_hi(raw.y)*sa.w + ha.w; f3 = (f3>=0.f)?f3:LEAKY_ACT*f3;
        float f4 = bf_lo(raw.z)*sb.x + hb.x; f4 = (f4>=0.f)?f4:LEAKY_ACT*f4;
        float f5 = bf_hi(raw.z)*sb.y + hb.y; f5 = (f5>=0.f)?f5:LEAKY_ACT*f5;
        float f6 = bf_lo(raw.w)*sb.z + hb.z; f6 = (f6>=0.f)?f6:LEAKY_ACT*f6;
        float f7 = bf_hi(raw.w)*sb.w + hb.w; f7 = (f7>=0.f)?f7:LEAKY_ACT*f7;
        raw.x = (unsigned)f2bf(f0) | ((unsigned)f2bf(f1) << 16);
        raw.y = (unsigned)f2bf(f2) | ((unsigned)f2bf(f3) << 16);
        raw.z = (unsigned)f2bf(f4) | ((unsigned)f2bf(f5) << 16);
        raw.w = (unsigned)f2bf(f6) | ((unsigned)f2bf(f7) << 16);
      }
    }
    *reinterpret_cast<uint4*>(&As[srow][sseg]) = raw;
    __syncthreads();
    bf16x8 a = *reinterpret_cast<const bf16x8*>(&As[arow][koff]);
    #pragma unroll
    for (int nt = 0; nt < 8; ++nt){
      int ncol = n0 + nt*16 + (lane & 15);
      bf16x8 b = *reinterpret_cast<const bf16x8*>(&Wt[(size_t)ncol*K + k0 + koff]);
      acc[nt] = __builtin_amdgcn_mfma_f32_16x16x32_bf16(a, b, acc[nt], 0, 0, 0);
    }
  }
  int rbase = m0 + wv*16 + (lane >> 4)*4;
  #pragma unroll
  for (int nt = 0; nt < 8; ++nt){
    int col = n0 + nt*16 + (lane & 15);
    float bv = bias[col];
    #pragma unroll
    for (int r = 0; r < 4; ++r){
      int row = rbase + r;
      if (row < N){
        float v = acc[nt][r] + bv;
        if (isL) xlb[(size_t)row*C + col] = f2bf(v);
        else     xr [(size_t)row*C + col] = v;
      }
    }
  }
}

// ---------------- fused GATv2: logits + softmax + aggregation ---------------
// 1 wave/block persistent; double-buffered edge batches. Attention weights
// packed f16 (wpk: half the VGPR of f32) with v_dot2_f32_f16 matvec (half the
// issue count). Edge-attr staged as packed f16 pairs, broadcast by literal-
// lane shfl. Self-loop edge-attr mean computed IN-FLIGHT (easum accumulated
// during staging, self slot masked out of the main loop, processed last) —
// removes the separate eamean gather pass. Logit reduce via DPP. No
// max-subtraction (logits O(1) by construction, softmax shift-invariant).
template<int C, int UNR, bool OUTBF>
__global__ __launch_bounds__(64) void k_gat_fused(
    const int* __restrict__ rowptr, const int2* __restrict__ csr2,
    const float* __restrict__ edge_attr,
    const unsigned short* __restrict__ xlb, const float* __restrict__ xr,
    const float* __restrict__ We, const float* __restrict__ att,
    const float* __restrict__ bias, float* __restrict__ out_f,
    unsigned short* __restrict__ out_b, int E, int N)
{
  constexpr int CPL = C/64;          // 2 or 4 columns per lane
  constexpr int PK  = CPL/2;         // packed uints per edge per lane
  const int lane = threadIdx.x;
  const int c0 = lane*CPL;

  f16x2 wpk[8][CPL];                 // We pairs (k=2k8,2k8+1) packed f16
  #pragma unroll
  for (int k8 = 0; k8 < 8; ++k8)
    #pragma unroll
    for (int q = 0; q < CPL; ++q)
      wpk[k8][q] = cvtpk(We[(2*k8)*C + c0 + q], We[(2*k8+1)*C + c0 + q]);
  float attv[CPL], biasv[CPL];
  #pragma unroll
  for (int q = 0; q < CPL; ++q){ attv[q] = att[c0 + q]; biasv[q] = bias[c0 + q]; }

  for (int n = blockIdx.x; n < N; n += gridDim.x){
    float xrv[CPL];
    #pragma unroll
    for (int q = 0; q < CPL; ++q) xrv[q] = xr[(size_t)n*C + c0 + q];
    int start = __builtin_amdgcn_readfirstlane(rowptr[n]);
    int end   = __builtin_amdgcn_readfirstlane(rowptr[n+1]);

    float denom = 0.f;
    float acc[CPL] = {};
    float2 easum = make_float2(0.f, 0.f);   // per-lane pair (lane&7) sum

    unsigned xA[UNR][PK]; f16x2 eaA[UNR];
    unsigned xB[UNR][PK]; f16x2 eaB[UNR];

    auto stage = [&](int base, unsigned (&xp)[UNR][PK], f16x2 (&eal)[UNR])->int{
      int mask = 0;
      #pragma unroll
      for (int u = 0; u < UNR; ++u){
        bool zero = true;
        if (base + u < end){
          int2 v = csr2[base + u];
          int e = __builtin_amdgcn_readfirstlane(v.y);
          if (e < E){                        // real edge (self slot deferred)
            int s = __builtin_amdgcn_readfirstlane(v.x);
            float2 ep = *reinterpret_cast<const float2*>(
                &edge_attr[(size_t)e*16 + 2*(lane & 7)]);
            easum.x += ep.x; easum.y += ep.y;
            eal[u] = cvtpk(ep.x, ep.y);
            const unsigned short* prow = xlb + (size_t)s*C + c0;
            if constexpr (PK == 2){
              uint2 w = *reinterpret_cast<const uint2*>(prow);
              xp[u][0] = w.x; xp[u][1] = w.y;
            } else {
              xp[u][0] = *reinterpret_cast<const unsigned*>(prow);
            }
            mask |= 1 << u;
            zero = false;
          }
        }
        if (zero){
          eal[u] = cvtpk(0.f, 0.f);
          #pragma unroll
          for (int p = 0; p < PK; ++p) xp[u][p] = 0;
        }
      }
      return mask;
    };
    auto compute = [&](unsigned (&xp)[UNR][PK], f16x2 (&eal)[UNR], int mask){
      float pe[UNR];
      #pragma unroll
      for (int u = 0; u < UNR; ++u){
        if ((mask >> u) & 1){
          float w[CPL] = {};
          #pragma unroll
          for (int k8 = 0; k8 < 8; ++k8){
            f16x2 pr = bcast_pair(eal[u], k8);   // v_readlane broadcast
            #pragma unroll
            for (int q = 0; q < CPL; ++q) w[q] = FDOT2(pr, wpk[k8][q], w[q]);
          }
          float p = 0.f;
          #pragma unroll
          for (int p2 = 0; p2 < PK; ++p2){
            float x0 = bf_lo(xp[u][p2]), x1 = bf_hi(xp[u][p2]);
            float v0 = x0 + xrv[2*p2]   + w[2*p2];
            float v1 = x1 + xrv[2*p2+1] + w[2*p2+1];
            v0 = (v0 >= 0.f) ? v0 : LEAKY_ATT*v0;
            v1 = (v1 >= 0.f) ? v1 : LEAKY_ATT*v1;
            p += attv[2*p2]*v0 + attv[2*p2+1]*v1;
          }
          p = wave_sum64(p);                     // DPP reduce (VALU only)
          pe[u] = __expf(p);
        } else pe[u] = 0.f;
      }
      #pragma unroll
      for (int u = 0; u < UNR; ++u) denom += pe[u];
      #pragma unroll
      for (int u = 0; u < UNR; ++u)
        #pragma unroll
        for (int p2 = 0; p2 < PK; ++p2){
          acc[2*p2]   += pe[u]*bf_lo(xp[u][p2]);
          acc[2*p2+1] += pe[u]*bf_hi(xp[u][p2]);
        }
    };

    int i = start;
    int mA = stage(i, xA, eaA);
    int mB = 0;
    for (;;){
      int j = i + UNR;
      if (j < end) mB = stage(j, xB, eaB);
      compute(xA, eaA, mA);
      i = j;
      if (i >= end) break;
      j = i + UNR;
      if (j < end) mA = stage(j, xA, eaA);
      compute(xB, eaB, mB);
      i = j;
      if (i >= end) break;
    }

    // self-loop: ea = mean of real in-edge attrs (0 if none), xl row of n
    {
      int deg = end - start - 1;
      float invd = 1.0f / (float)max(deg, 1);
      eaA[0] = cvtpk(easum.x*invd, easum.y*invd);
      const unsigned short* prow = xlb + (size_t)n*C + c0;
      if constexpr (PK == 2){
        uint2 w = *reinterpret_cast<const uint2*>(prow);
        xA[0][0] = w.x; xA[0][1] = w.y;
      } else {
        xA[0][0] = *reinterpret_cast<const unsigned*>(prow);
      }
      compute(xA, eaA, 1);
    }

    float inv = 1.0f / denom;     // self-loop guarantees denom > 0
    if constexpr (OUTBF){
      #pragma unroll
      for (int p2 = 0; p2 < PK; ++p2){
        unsigned po = (unsigned)f2bf(acc[2*p2]*inv + biasv[2*p2])
                    | ((unsigned)f2bf(acc[2*p2+1]*inv + biasv[2*p2+1]) << 16);
        *reinterpret_cast<unsigned*>(&out_b[(size_t)n*C + c0 + 2*p2]) = po;
      }
    } else {
      if constexpr (CPL == 4){
        float4 o = make_float4(acc[0]*inv + biasv[0], acc[1]*inv + biasv[1],
                               acc[2]*inv + biasv[2], acc[3]*inv + biasv[3]);
        *reinterpret_cast<float4*>(&out_f[(size_t)n*C + c0]) = o;
      } else {
        float2 o = make_float2(acc[0]*inv + biasv[0], acc[1]*inv + biasv[1]);
        *reinterpret_cast<float2*>(&out_f[(size_t)n*C + c0]) = o;
      }
    }
  }
}

// ---------------- batchnorm -------------------------------------------------
__global__ void k_bnstats(const float* __restrict__ x, float* __restrict__ sums,
                          int N, int C){
  int c = threadIdx.x;           // blockDim = C
  float s = 0.f, s2 = 0.f;
  for (int r = blockIdx.x; r < N; r += gridDim.x){
    float v = x[(size_t)r*C + c];
    s += v; s2 += v*v;
  }
  atomicAdd(&sums[c], s);
  atomicAdd(&sums[C + c], s2);
}

__global__ void k_bnstats_bf(const unsigned short* __restrict__ x,
                             float* __restrict__ sums, int N, int C){
  int c = threadIdx.x;
  float s = 0.f, s2 = 0.f;
  for (int r = blockIdx.x; r < N; r += gridDim.x){
    float v = bf2f(x[(size_t)r*C + c]);
    s += v; s2 += v*v;
  }
  atomicAdd(&sums[c], s);
  atomicAdd(&sums[C + c], s2);
}

// sums -> per-channel affine (scale, shift)
__global__ void k_bnfin(const float* __restrict__ sums, const float* __restrict__ gam,
                        const float* __restrict__ bet, float* __restrict__ sc,
                        float* __restrict__ sh, int N, int C){
  int c = threadIdx.x; if (c >= C) return;
  float invN = 1.0f / (float)N;
  float mu  = sums[c] * invN;
  float var = sums[C + c] * invN - mu*mu;
  float r = rsqrtf(var + BN_EPS) * gam[c];
  sc[c] = r;
  sh[c] = bet[c] - mu*r;
}

// ------- fused BN-apply + leaky + gate + graph softmax + pooled output ------
// One block per graph (batch is sorted). Applies the layer-2 BN affine on
// read (d2 stays raw), computes the gate dot per node via DPP+LDS block
// reduce, and accumulates the softmax-weighted pool in one pass (unshifted
// softmax: gate logits are O(1) by construction). Replaces bnapply_gate +
// gexp + final (saves a full 51 MB d2 rewrite + 2 dispatches).
__global__ __launch_bounds__(256) void k_bngate_final(
    const float* __restrict__ d2, const float* __restrict__ sc2,
    const float* __restrict__ sh2, const float* __restrict__ Wg,
    const float* __restrict__ bg, const int* __restrict__ gptr,
    float* __restrict__ out)
{
  int g = blockIdx.x;
  int s = gptr[g], e = gptr[g+1];
  int tid = threadIdx.x, wv = tid >> 6, lane = tid & 63;
  __shared__ float red[4];
  float scv = sc2[tid], shv = sh2[tid], wgv = Wg[tid], bgv = bg[0];
  float den = 0.f, acc = 0.f;
  float xv = (s < e) ? d2[(size_t)s*256 + tid] : 0.f;     // prefetch row s
  for (int n = s; n < e; ++n){
    float xn = (n+1 < e) ? d2[(size_t)(n+1)*256 + tid] : 0.f;  // prefetch next
    float v = xv*scv + shv;
    v = (v >= 0.f) ? v : LEAKY_ACT*v;
    float p = wave_sum64(v * wgv);
    if (lane == 0) red[wv] = p;
    __syncthreads();
    float gt = (red[0] + red[1]) + (red[2] + red[3]) + bgv;
    __syncthreads();
    float ex = __expf(gt);
    den += ex;
    acc += ex * v;
    xv = xn;
  }
  out[(size_t)g*256 + tid] = (e > s) ? acc/den : 0.f;
}

// ---------------- graph boundary pointers -----------------------------------
__global__ void k_gptr(const int* __restrict__ batch, int* __restrict__ gptr, int N, int G){
  int n = blockIdx.x*blockDim.x + threadIdx.x;
  if (n > N) return;
  if (n == N){
    int last = batch[N-1];
    for (int g = last+1; g <= G; ++g) gptr[g] = N;
    return;
  }
  int bc = batch[n];
  int bp = (n == 0) ? -1 : batch[n-1];
  for (int g = bp+1; g <= bc; ++g) gptr[g] = n;
}

// ============================================================================
extern "C" void kernel_launch(void* const* d_in, const int* in_sizes, int n_in,
                              void* d_out, int out_size, void* d_ws, size_t ws_size,
                              hipStream_t stream){
  const float* x         = (const float*)d_in[0];
  const int*   edge_idx  = (const int*)  d_in[1];
  const float* edge_attr = (const float*)d_in[2];
  const int*   batch     = (const int*)  d_in[3];
  const float* emb       = (const float*)d_in[4];
  const float* Wl1 = (const float*)d_in[5];  const float* bl1 = (const float*)d_in[6];
  const float* Wr1 = (const float*)d_in[7];  const float* br1 = (const float*)d_in[8];
  const float* We1 = (const float*)d_in[9];  const float* att1= (const float*)d_in[10];
  const float* bias1=(const float*)d_in[11]; const float* g1  = (const float*)d_in[12];
  const float* be1 = (const float*)d_in[13];
  const float* Wl2 = (const float*)d_in[14]; const float* bl2 = (const float*)d_in[15];
  const float* Wr2 = (const float*)d_in[16]; const float* br2 = (const float*)d_in[17];
  const float* We2 = (const float*)d_in[18]; const float* att2= (const float*)d_in[19];
  const float* bias2=(const float*)d_in[20]; const float* g2  = (const float*)d_in[21];
  const float* be2 = (const float*)d_in[22];
  const float* Wg  = (const float*)d_in[23]; const float* bg  = (const float*)d_in[24];
  float* out = (float*)d_out;

  const int N = in_sizes[0] / 64;        // 50000
  const int E = in_sizes[1] / 2;         // 800000
  const int EP = E + N;                  // with self-loops
  const int G = 256;
  const int* srcv = edge_idx;
  const int* dstv = edge_idx + E;

  // ---- workspace layout (element offsets, 64-elem aligned) ----
  float* ws = (float*)d_ws;
  size_t o = 0;
  auto alloc = [&](size_t elems){ size_t r = o; o += (elems + 63) & ~(size_t)63; return r; };
  size_t o_big1  = alloc((size_t)N*128);  // hb (bf16 N*128), later xlb2 (bf16 N*256)
  size_t o_union = alloc((size_t)N*256);  // [xr1 f32 | d1b bf16], later d2 f32
  size_t o_xlb1  = alloc((size_t)N*64);   // xlb1 (bf16, N*128)
  size_t o_xr2   = alloc((size_t)N*256);
  size_t o_bn1   = alloc(2*128);          // bn1+bn2 contiguous -> one memset
  size_t o_bn2   = alloc(2*256);
  size_t o_sc1   = alloc(128);
  size_t o_sh1   = alloc(128);
  size_t o_sc2   = alloc(256);
  size_t o_sh2   = alloc(256);
  size_t o_deg   = alloc((size_t)N);      // deg+cur contiguous -> one memset
  size_t o_cur   = alloc((size_t)N);
  size_t o_rp    = alloc((size_t)N+1);
  size_t o_bsum  = alloc(64);
  size_t o_csr   = alloc((size_t)EP*2);   // int2 per CSR slot
  size_t o_wt1l  = alloc(128*128/2);      // bf16 128x128
  size_t o_wt1r  = alloc(128*128/2);
  size_t o_wt2l  = alloc(256*128/2);      // bf16 256x128
  size_t o_wt2r  = alloc(256*128/2);
  size_t o_gptr  = alloc(G+1);

  unsigned short* hb   = (unsigned short*)(ws + o_big1);
  unsigned short* xlb2 = (unsigned short*)(ws + o_big1);   // after hb is dead
  float* xr1  = ws + o_union;                              // N*128 f32
  unsigned short* d1b = (unsigned short*)(ws + o_union + (size_t)N*128);
  float* d2   = ws + o_union;                              // after xr1/d1b dead
  unsigned short* xlb1 = (unsigned short*)(ws + o_xlb1);
  float* xr2  = ws + o_xr2;
  float* bn1  = ws + o_bn1;
  float* bn2  = ws + o_bn2;
  float* sc1  = ws + o_sc1;
  float* sh1  = ws + o_sh1;
  float* sc2  = ws + o_sc2;
  float* sh2  = ws + o_sh2;
  int*   deg  = (int*)(ws + o_deg);
  int*   cur  = (int*)(ws + o_cur);
  int*   rp   = (int*)(ws + o_rp);
  int*   bsum = (int*)(ws + o_bsum);
  int2*  csr2 = (int2*)(ws + o_csr);
  unsigned short* wt1l = (unsigned short*)(ws + o_wt1l);
  unsigned short* wt1r = (unsigned short*)(ws + o_wt1r);
  unsigned short* wt2l = (unsigned short*)(ws + o_wt2l);
  unsigned short* wt2r = (unsigned short*)(ws + o_wt2r);
  int*   gptr = (int*)(ws + o_gptr);

  // ---- zero accumulators (graph replays must be deterministic) ----
  hipMemsetAsync(deg, 0, (o_cur - o_deg + (size_t)N)*4, stream);       // deg+cur
  hipMemsetAsync(bn1, 0, (o_bn2 - o_bn1 + 2*256)*4, stream);           // bn1+bn2

  auto nblk = [](long long n, int b){ return (int)((n + b - 1) / b); };

  // ---- graph prep + weight prep ----
  k_embed<<<1024, 256, 0, stream>>>(x, emb, hb, N);
  k_deg<<<nblk(E,256), 256, 0, stream>>>(dstv, deg, E);
  int nbs = nblk(N, 1024);
  k_scan1<<<nbs, 256, 0, stream>>>(deg, rp, bsum, N);
  k_scan2<<<1, 64, 0, stream>>>(bsum, nbs);
  k_scan3<<<nblk((long long)N+1,256), 256, 0, stream>>>(rp, bsum, N, EP);
  k_csrfill<<<nblk(EP,256), 256, 0, stream>>>(srcv, dstv, rp, cur, csr2, E, N);
  k_wprep<<<nblk(128*128,256), 256, 0, stream>>>(Wl1, wt1l, 128, 128);
  k_wprep<<<nblk(128*128,256), 256, 0, stream>>>(Wr1, wt1r, 128, 128);
  k_wprep<<<nblk(128*256,256), 256, 0, stream>>>(Wl2, wt2l, 128, 256);
  k_wprep<<<nblk(128*256,256), 256, 0, stream>>>(Wr2, wt2r, 128, 256);

  const int FGRID = 8192;   // persistent 1-wave blocks

  // ---- layer 1 (C=128) ----
  {
    dim3 grid(nblk(N,64), 2);            // y=0: xl, y=1: xr
    k_gemm_mfma<false><<<grid, 256, 0, stream>>>(hb, wt1l, bl1, wt1r, br1,
        nullptr, nullptr, xlb1, xr1, N, 128);
  }
  k_gat_fused<128,8,true><<<FGRID, 64, 0, stream>>>(rp, csr2, edge_attr,
      xlb1, xr1, We1, att1, bias1, nullptr, d1b, E, N);
  k_bnstats_bf<<<512, 128, 0, stream>>>(d1b, bn1, N, 128);
  k_bnfin<<<1, 128, 0, stream>>>(bn1, g1, be1, sc1, sh1, N, 128);

  // ---- layer 2 (C=256); layer-1 BN+leaky fused into A-staging ----
  {
    dim3 grid(nblk(N,64), 4);            // y=0,1: xl halves; y=2,3: xr halves
    k_gemm_mfma<true><<<grid, 256, 0, stream>>>(d1b, wt2l, bl2, wt2r, br2,
        sc1, sh1, xlb2, xr2, N, 256);
  }
  k_gat_fused<256,6,false><<<FGRID, 64, 0, stream>>>(rp, csr2, edge_attr,
      xlb2, xr2, We2, att2, bias2, d2, nullptr, E, N);
  k_bnstats<<<512, 256, 0, stream>>>(d2, bn2, N, 256);
  k_bnfin<<<1, 256, 0, stream>>>(bn2, g2, be2, sc2, sh2, N, 256);

  // ---- attentional aggregation (BN-apply fused on read) ----
  k_gptr<<<nblk((long long)N+1,256), 256, 0, stream>>>(batch, gptr, N, G);
  k_bngate_final<<<G, 256, 0, stream>>>(d2, sc2, sh2, Wg, bg, gptr, out);
}